// Round 3
// baseline (4793.019 us; speedup 1.0000x reference)
//
#include <hip/hip_runtime.h>
#include <hip/hip_bf16.h>
#include <cstdint>
#include <cstddef>

typedef __hip_bfloat16 bf16;

#define N_NODES  50000
#define N_EDGES  150000
#define E_TOT    (N_EDGES + N_NODES)   /* 200000: edges then self-loops */
#define N_GRAPHS 1024
#define IN_DIM   78
#define OUT_DIM  64
#define HEADS    10
#define HID      640
#define NEG_SLOPE 0.2f

#define NCHUNK 2
#define CH (N_NODES / NCHUNK)          /* 25000 rows per accumulator chunk */

static __device__ __forceinline__ float b2f(bf16 v){ return __bfloat162float(v); }
static __device__ __forceinline__ bf16  f2b(float v){ return __float2bfloat16(v); }
__device__ __forceinline__ float ldf(float v){ return v; }
__device__ __forceinline__ float ldf(bf16 v){ return b2f(v); }

__device__ __forceinline__ int clampi(int v, int hi){ return v < 0 ? 0 : (v >= hi ? hi - 1 : v); }

// Order-preserving float<->uint encoding for atomicMax on floats of any sign.
__device__ __forceinline__ unsigned enc_f(float f){
  unsigned u = __float_as_uint(f);
  return (u & 0x80000000u) ? ~u : (u | 0x80000000u);
}
__device__ __forceinline__ float dec_f(unsigned u){
  return (u & 0x80000000u) ? __uint_as_float(u ^ 0x80000000u) : __uint_as_float(~u);
}
#define ENC_NEG_INF 0x007FFFFFu   /* enc_f(-inf) */

// ---------------------------------------------------------------- fills
__global__ __launch_bounds__(256) void fill_u32(unsigned* __restrict__ p, unsigned v, int n){
  int i = blockIdx.x * 256 + threadIdx.x;
  if (i < n) p[i] = v;
}

// ---------------------------------------------------------------- GEMM (A: f32|bf16, B: f32, C: bf16)
// C[M,N] = A[M,K] @ B[K,N]; 64x64 tile, 256 threads, 4x4 microtile, f32 accumulate.
#define GT_M 64
#define GT_N 64
#define GT_K 16
template<typename TA>
__global__ __launch_bounds__(256) void gemm_tile(const TA* __restrict__ A,
                                                 const float* __restrict__ B,
                                                 bf16* __restrict__ C,
                                                 int M, int K, int N){
  __shared__ float As[GT_K][GT_M + 4];
  __shared__ float Bs[GT_K][GT_N + 4];
  int tid = threadIdx.x;
  int tx = tid & 15, ty = tid >> 4;
  int row0 = blockIdx.y * GT_M;
  int col0 = blockIdx.x * GT_N;
  float acc[4][4] = {};
  for (int k0 = 0; k0 < K; k0 += GT_K){
    {
      int r  = tid >> 2;
      int kc = (tid & 3) * 4;
      int gr = row0 + r;
#pragma unroll
      for (int j = 0; j < 4; ++j){
        int gk = k0 + kc + j;
        float v = 0.f;
        if (gr < M && gk < K) v = ldf(A[(size_t)gr * K + gk]);
        As[kc + j][r] = v;
      }
    }
    {
      int kr = tid >> 4;
      int c  = (tid & 15) * 4;
      int gk = k0 + kr;
#pragma unroll
      for (int j = 0; j < 4; ++j){
        int gc = col0 + c + j;
        float v = 0.f;
        if (gk < K && gc < N) v = B[(size_t)gk * N + gc];
        Bs[kr][c + j] = v;
      }
    }
    __syncthreads();
#pragma unroll
    for (int kk = 0; kk < GT_K; ++kk){
      float a[4], b[4];
#pragma unroll
      for (int i = 0; i < 4; ++i) a[i] = As[kk][ty * 4 + i];
#pragma unroll
      for (int j = 0; j < 4; ++j) b[j] = Bs[kk][tx * 4 + j];
#pragma unroll
      for (int i = 0; i < 4; ++i)
#pragma unroll
        for (int j = 0; j < 4; ++j) acc[i][j] += a[i] * b[j];
    }
    __syncthreads();
  }
#pragma unroll
  for (int i = 0; i < 4; ++i){
    int gr = row0 + ty * 4 + i;
    if (gr >= M) continue;
#pragma unroll
    for (int j = 0; j < 4; ++j){
      int gc = col0 + tx * 4 + j;
      if (gc < N) C[(size_t)gr * N + gc] = f2b(acc[i][j]);
    }
  }
}

// ---------------------------------------------------------------- edge index fetch (with clamp)
__device__ __forceinline__ void edge_sd(const int* esrc, const int* edst, int e, int& s, int& d){
  if (e < N_EDGES){ s = clampi(esrc[e], N_NODES); d = clampi(edst[e], N_NODES); }
  else            { s = d = e - N_EDGES; }
}

// ---------------------------------------------------------------- GAT layer 1 (10 heads x 64)
__global__ __launch_bounds__(256) void edge1_logits(const bf16* __restrict__ xl,
                                                    const bf16* __restrict__ xr,
                                                    const int* __restrict__ esrc,
                                                    const int* __restrict__ edst,
                                                    const float* __restrict__ att,
                                                    float* __restrict__ log1,
                                                    unsigned* __restrict__ m1){
  int wid  = (blockIdx.x * 256 + threadIdx.x) >> 6;
  int lane = threadIdx.x & 63;
  if (wid >= E_TOT) return;
  int s, d; edge_sd(esrc, edst, wid, s, d);
  const bf16* xls = xl + (size_t)s * HID;
  const bf16* xrd = xr + (size_t)d * HID;
  float mine = 0.f;
#pragma unroll
  for (int h = 0; h < HEADS; ++h){
    int idx = h * 64 + lane;
    float v = b2f(xls[idx]) + b2f(xrd[idx]);
    v = v > 0.f ? v : NEG_SLOPE * v;
    v *= att[idx];
#pragma unroll
    for (int off = 32; off > 0; off >>= 1) v += __shfl_xor(v, off);
    if (lane == h) mine = v;
  }
  if (lane < HEADS){
    log1[(size_t)wid * HEADS + lane] = mine;
    atomicMax(&m1[d * HEADS + lane], enc_f(mine));
  }
}

__global__ __launch_bounds__(256) void edge1_exp(const int* __restrict__ esrc,
                                                 const int* __restrict__ edst,
                                                 float* __restrict__ log1,
                                                 const unsigned* __restrict__ m1,
                                                 float* __restrict__ den1){
  int t = blockIdx.x * 256 + threadIdx.x;
  if (t >= E_TOT * HEADS) return;
  int e = t / HEADS, h = t - e * HEADS;
  int s, d; edge_sd(esrc, edst, e, s, d);
  float m  = dec_f(m1[d * HEADS + h]);
  float ex = expf(log1[t] - m);
  log1[t] = ex;
  atomicAdd(&den1[d * HEADS + h], ex);
}

__global__ __launch_bounds__(256) void edge1_scatter(const bf16* __restrict__ xl,
                                                     const int* __restrict__ esrc,
                                                     const int* __restrict__ edst,
                                                     const float* __restrict__ log1,
                                                     const float* __restrict__ den1,
                                                     float* __restrict__ accc,
                                                     int base){
  int wid  = (blockIdx.x * 256 + threadIdx.x) >> 6;
  int lane = threadIdx.x & 63;
  if (wid >= E_TOT) return;
  int s, d; edge_sd(esrc, edst, wid, s, d);
  if (d < base || d >= base + CH) return;
  float alpha = 0.f;
  if (lane < HEADS) alpha = log1[(size_t)wid * HEADS + lane] / den1[d * HEADS + lane];
  const bf16* xls = xl + (size_t)s * HID;
  float* accd = accc + (size_t)(d - base) * HID;
#pragma unroll
  for (int h = 0; h < HEADS; ++h){
    float a = __shfl(alpha, h);
    int idx = h * 64 + lane;
    atomicAdd(&accd[idx], a * b2f(xls[idx]));
  }
}

// ---------------------------------------------------------------- GAT layer 2 (1 head x 640)
__global__ __launch_bounds__(256) void edge2_logits(const bf16* __restrict__ xl,
                                                    const bf16* __restrict__ xr,
                                                    const int* __restrict__ esrc,
                                                    const int* __restrict__ edst,
                                                    const float* __restrict__ att,
                                                    float* __restrict__ log2,
                                                    unsigned* __restrict__ m2){
  int wid  = (blockIdx.x * 256 + threadIdx.x) >> 6;
  int lane = threadIdx.x & 63;
  if (wid >= E_TOT) return;
  int s, d; edge_sd(esrc, edst, wid, s, d);
  const bf16* xls = xl + (size_t)s * HID;
  const bf16* xrd = xr + (size_t)d * HID;
  float sum = 0.f;
#pragma unroll
  for (int i = lane; i < HID; i += 64){
    float v = b2f(xls[i]) + b2f(xrd[i]);
    v = v > 0.f ? v : NEG_SLOPE * v;
    sum += v * att[i];
  }
#pragma unroll
  for (int off = 32; off > 0; off >>= 1) sum += __shfl_xor(sum, off);
  if (lane == 0){
    log2[wid] = sum;
    atomicMax(&m2[d], enc_f(sum));
  }
}

__global__ __launch_bounds__(256) void edge2_exp(const int* __restrict__ esrc,
                                                 const int* __restrict__ edst,
                                                 float* __restrict__ log2,
                                                 const unsigned* __restrict__ m2,
                                                 float* __restrict__ den2){
  int e = blockIdx.x * 256 + threadIdx.x;
  if (e >= E_TOT) return;
  int s, d; edge_sd(esrc, edst, e, s, d);
  float ex = expf(log2[e] - dec_f(m2[d]));
  log2[e] = ex;
  atomicAdd(&den2[d], ex);
}

__global__ __launch_bounds__(256) void edge2_scatter(const bf16* __restrict__ xl,
                                                     const int* __restrict__ esrc,
                                                     const int* __restrict__ edst,
                                                     const float* __restrict__ log2,
                                                     const float* __restrict__ den2,
                                                     float* __restrict__ accc,
                                                     int base){
  int wid  = (blockIdx.x * 256 + threadIdx.x) >> 6;
  int lane = threadIdx.x & 63;
  if (wid >= E_TOT) return;
  int s, d; edge_sd(esrc, edst, wid, s, d);
  if (d < base || d >= base + CH) return;
  float alpha = log2[wid] / den2[d];
  const bf16* xls = xl + (size_t)s * HID;
  float* accd = accc + (size_t)(d - base) * HID;
#pragma unroll
  for (int i = lane; i < HID; i += 64)
    atomicAdd(&accd[i], alpha * b2f(xls[i]));
}

// ---------------------------------------------------------------- bias (+activation) chunk -> bf16 H
template<int MODE>  // 0 = none, 1 = ELU
__global__ __launch_bounds__(256) void bias_act(const float* __restrict__ accc,
                                                const float* __restrict__ bias,
                                                bf16* __restrict__ out, int base){
  int i = blockIdx.x * 256 + threadIdx.x;
  if (i >= CH * HID) return;
  int col = i % HID;
  float v = accc[i] + bias[col];
  if (MODE == 1) v = v > 0.f ? v : (expf(v) - 1.f);
  out[(size_t)base * HID + i] = f2b(v);
}

// ---------------------------------------------------------------- GCN
__global__ __launch_bounds__(256) void deg_kernel(const int* __restrict__ esrc,
                                                  const int* __restrict__ edst,
                                                  float* __restrict__ deg){
  int e = blockIdx.x * 256 + threadIdx.x;
  if (e >= E_TOT) return;
  int s, d; edge_sd(esrc, edst, e, s, d);
  atomicAdd(&deg[d], 1.0f);
}

__global__ __launch_bounds__(256) void dinv_kernel(const float* __restrict__ deg,
                                                   float* __restrict__ dinv){
  int n = blockIdx.x * 256 + threadIdx.x;
  if (n < N_NODES) dinv[n] = rsqrtf(fmaxf(deg[n], 1.0f));
}

__global__ __launch_bounds__(256) void gcn_scatter(const bf16* __restrict__ xw,
                                                   const int* __restrict__ esrc,
                                                   const int* __restrict__ edst,
                                                   const float* __restrict__ dinv,
                                                   float* __restrict__ accc,
                                                   int base){
  int wid  = (blockIdx.x * 256 + threadIdx.x) >> 6;
  int lane = threadIdx.x & 63;
  if (wid >= E_TOT) return;
  int s, d; edge_sd(esrc, edst, wid, s, d);
  if (d < base || d >= base + CH) return;
  float w = dinv[s] * dinv[d];
  const bf16* xs = xw + (size_t)s * HID;
  float* accd = accc + (size_t)(d - base) * HID;
#pragma unroll
  for (int i = lane; i < HID; i += 64)
    atomicAdd(&accd[i], w * b2f(xs[i]));
}

// ---------------------------------------------------------------- pooling
__global__ __launch_bounds__(256) void pool_cnt(const int* __restrict__ batch,
                                                float* __restrict__ cnt){
  int n = blockIdx.x * 256 + threadIdx.x;
  if (n < N_NODES) atomicAdd(&cnt[clampi(batch[n], N_GRAPHS)], 1.0f);
}

__global__ __launch_bounds__(256) void relu_pool(const float* __restrict__ accc,
                                                 const float* __restrict__ bg,
                                                 const int* __restrict__ batch,
                                                 float* __restrict__ pmax,
                                                 float* __restrict__ psum,
                                                 int base){
  int i = blockIdx.x * 256 + threadIdx.x;
  if (i >= CH * HID) return;
  int n = base + i / HID, c = i % HID;
  float v = fmaxf(accc[i] + bg[c], 0.f);
  int g = clampi(batch[n], N_GRAPHS);
  // v >= 0: float bits order as unsigned; pmax zero-initialized.
  atomicMax((unsigned*)&pmax[(size_t)g * HID + c], __float_as_uint(v));
  atomicAdd(&psum[(size_t)g * HID + c], v);
}

__global__ __launch_bounds__(256) void final_out(const float* __restrict__ pmax,
                                                 const float* __restrict__ psum,
                                                 const float* __restrict__ cnt,
                                                 float* __restrict__ out){
  int i = blockIdx.x * 256 + threadIdx.x;
  if (i >= N_GRAPHS * 2 * HID) return;
  int g = i / (2 * HID), c = i - g * (2 * HID);
  float v;
  if (c < HID) v = pmax[(size_t)g * HID + c];
  else         v = psum[(size_t)g * HID + (c - HID)] / fmaxf(cnt[g], 1.0f);
  out[i] = v;
}

// ---------------------------------------------------------------- launch
extern "C" void kernel_launch(void* const* d_in, const int* in_sizes, int n_in,
                              void* d_out, int out_size, void* d_ws, size_t ws_size,
                              hipStream_t stream){
  const float* x     = (const float*)d_in[0];
  const int*   ei    = (const int*)d_in[1];
  const int*   batch = (const int*)d_in[2];
  const float* Wl1 = (const float*)d_in[3];
  const float* Wr1 = (const float*)d_in[4];
  const float* a1  = (const float*)d_in[5];
  const float* b1  = (const float*)d_in[6];
  const float* Wl2 = (const float*)d_in[7];
  const float* Wr2 = (const float*)d_in[8];
  const float* a2  = (const float*)d_in[9];
  const float* b2  = (const float*)d_in[10];
  const float* Wg  = (const float*)d_in[11];
  const float* bg  = (const float*)d_in[12];
  const int* esrc = ei;
  const int* edst = ei + N_EDGES;

  // ---- workspace layout (~211 MB total) ----
  char* ws = (char*)d_ws;
  size_t off = 0;
  auto take = [&](size_t bytes)->char*{
    char* p = ws + off; off = (off + bytes + 255) & ~(size_t)255; return p;
  };
  bf16*     X1   = (bf16*)    take((size_t)N_NODES * HID * 2);   // xl / xw (64 MB)
  char*     X2R  =            take((size_t)N_NODES * HID * 2);   // xr  UNION  f32 acc chunk (64 MB)
  bf16*     X2   = (bf16*)X2R;
  float*    ACCC = (float*)X2R;                                  // CH*HID*4 == 64 MB exactly
  bf16*     H    = (bf16*)    take((size_t)N_NODES * HID * 2);   // h1 then h2 (64 MB)
  float*    LOG1 = (float*)   take((size_t)E_TOT * HEADS * 4);   // 8 MB
  unsigned* M1   = (unsigned*)take((size_t)N_NODES * HEADS * 4);
  float*    DEN1 = (float*)   take((size_t)N_NODES * HEADS * 4);
  float*    LOG2 = (float*)   take((size_t)E_TOT * 4);
  unsigned* M2   = (unsigned*)take((size_t)N_NODES * 4);
  float*    DEN2 = (float*)   take((size_t)N_NODES * 4);
  float*    DEG  = (float*)   take((size_t)N_NODES * 4);
  float*    DINV = (float*)   take((size_t)N_NODES * 4);
  float*    PMAX = (float*)   take((size_t)N_GRAPHS * HID * 4);
  float*    PSUM = (float*)   take((size_t)N_GRAPHS * HID * 4);
  float*    CNT  = (float*)   take((size_t)N_GRAPHS * 4);

  dim3 blk(256);
  auto fill = [&](void* p, unsigned v, int n){
    fill_u32<<<dim3((n + 255) / 256), blk, 0, stream>>>((unsigned*)p, v, n);
  };
  dim3 ggrid(HID / GT_N, (N_NODES + GT_M - 1) / GT_M);
  const int eblocks  = (E_TOT * 64 + 255) / 256;          // wave-per-edge kernels
  const int ehblocks = (E_TOT * HEADS + 255) / 256;
  const int chblocks = (CH * HID + 255) / 256;

  // ---- GATv2 layer 1 ----
  fill(M1, ENC_NEG_INF, N_NODES * HEADS);
  fill(DEN1, 0u, N_NODES * HEADS);
  gemm_tile<float><<<ggrid, blk, 0, stream>>>(x, Wl1, X1, N_NODES, IN_DIM, HID);
  gemm_tile<float><<<ggrid, blk, 0, stream>>>(x, Wr1, X2, N_NODES, IN_DIM, HID);
  edge1_logits<<<eblocks, blk, 0, stream>>>(X1, X2, esrc, edst, a1, LOG1, M1);
  edge1_exp<<<ehblocks, blk, 0, stream>>>(esrc, edst, LOG1, M1, DEN1);
  for (int c = 0; c < NCHUNK; ++c){
    int base = c * CH;
    fill(ACCC, 0u, CH * HID);
    edge1_scatter<<<eblocks, blk, 0, stream>>>(X1, esrc, edst, LOG1, DEN1, ACCC, base);
    bias_act<1><<<chblocks, blk, 0, stream>>>(ACCC, b1, H, base);
  }

  // ---- GATv2 layer 2 ----
  fill(M2, ENC_NEG_INF, N_NODES);
  fill(DEN2, 0u, N_NODES);
  gemm_tile<bf16><<<ggrid, blk, 0, stream>>>(H, Wl2, X1, N_NODES, HID, HID);
  gemm_tile<bf16><<<ggrid, blk, 0, stream>>>(H, Wr2, X2, N_NODES, HID, HID);
  edge2_logits<<<eblocks, blk, 0, stream>>>(X1, X2, esrc, edst, a2, LOG2, M2);
  edge2_exp<<<(E_TOT + 255) / 256, blk, 0, stream>>>(esrc, edst, LOG2, M2, DEN2);
  for (int c = 0; c < NCHUNK; ++c){
    int base = c * CH;
    fill(ACCC, 0u, CH * HID);
    edge2_scatter<<<eblocks, blk, 0, stream>>>(X1, esrc, edst, LOG2, DEN2, ACCC, base);
    bias_act<0><<<chblocks, blk, 0, stream>>>(ACCC, b2, H, base);
  }

  // ---- GCN + pooling ----
  fill(DEG, 0u, N_NODES);
  deg_kernel<<<(E_TOT + 255) / 256, blk, 0, stream>>>(esrc, edst, DEG);
  dinv_kernel<<<(N_NODES + 255) / 256, blk, 0, stream>>>(DEG, DINV);
  gemm_tile<bf16><<<ggrid, blk, 0, stream>>>(H, Wg, X1, N_NODES, HID, HID);
  fill(PMAX, 0u, N_GRAPHS * HID);
  fill(PSUM, 0u, N_GRAPHS * HID);
  fill(CNT, 0u, N_GRAPHS);
  pool_cnt<<<(N_NODES + 255) / 256, blk, 0, stream>>>(batch, CNT);
  for (int c = 0; c < NCHUNK; ++c){
    int base = c * CH;
    fill(ACCC, 0u, CH * HID);
    gcn_scatter<<<eblocks, blk, 0, stream>>>(X1, esrc, edst, DINV, ACCC, base);
    relu_pool<<<chblocks, blk, 0, stream>>>(ACCC, bg, batch, PMAX, PSUM, base);
  }
  final_out<<<(N_GRAPHS * 2 * HID + 255) / 256, blk, 0, stream>>>(PMAX, PSUM, CNT, (float*)d_out);
}

// Round 4
// 2324.351 us; speedup vs baseline: 2.0621x; 2.0621x over previous
//
#include <hip/hip_runtime.h>
#include <hip/hip_bf16.h>
#include <cstdint>
#include <cstddef>

typedef __hip_bfloat16 bf16;

#define N_NODES  50000
#define N_EDGES  150000
#define E_TOT    (N_EDGES + N_NODES)   /* 200000: edges then self-loops */
#define N_GRAPHS 1024
#define IN_DIM   78
#define K1P      96                    /* IN_DIM padded to mult of 32 */
#define OUT_DIM  64
#define HEADS    10
#define HID      640
#define NEG_SLOPE 0.2f

#define NCHUNK 2
#define CH (N_NODES / NCHUNK)          /* 25000 rows per accumulator chunk */

static __device__ __forceinline__ float b2f(bf16 v){ return __bfloat162float(v); }
static __device__ __forceinline__ bf16  f2b(float v){ return __float2bfloat16(v); }

__device__ __forceinline__ int clampi(int v, int hi){ return v < 0 ? 0 : (v >= hi ? hi - 1 : v); }

// Order-preserving float<->uint encoding for atomicMax on floats of any sign.
__device__ __forceinline__ unsigned enc_f(float f){
  unsigned u = __float_as_uint(f);
  return (u & 0x80000000u) ? ~u : (u | 0x80000000u);
}
__device__ __forceinline__ float dec_f(unsigned u){
  return (u & 0x80000000u) ? __uint_as_float(u ^ 0x80000000u) : __uint_as_float(~u);
}
#define ENC_NEG_INF 0x007FFFFFu   /* enc_f(-inf) */

// ---------------------------------------------------------------- fills
__global__ __launch_bounds__(256) void fill_u32(unsigned* __restrict__ p, unsigned v, int n){
  int i = blockIdx.x * 256 + threadIdx.x;
  if (i < n) p[i] = v;
}

// ---------------------------------------------------------------- dtype prep
// x (N_NODES x IN_DIM f32) -> XB (N_NODES x K1P bf16, zero-padded)
__global__ __launch_bounds__(256) void conv_x(const float* __restrict__ x, bf16* __restrict__ XB){
  int i = blockIdx.x * 256 + threadIdx.x;
  if (i >= N_NODES * K1P) return;
  int n = i / K1P, k = i - n * K1P;
  XB[i] = f2b(k < IN_DIM ? x[(size_t)n * IN_DIM + k] : 0.f);
}

// W (K x N f32, row-major) -> WT (N x Kp bf16, row-major, zero-padded in k)
__global__ __launch_bounds__(256) void conv_wT(const float* __restrict__ W, bf16* __restrict__ WT,
                                               int K, int N, int Kp){
  int i = blockIdx.x * 256 + threadIdx.x;
  if (i >= N * Kp) return;
  int n = i / Kp, k = i - n * Kp;
  WT[i] = f2b(k < K ? W[(size_t)k * N + n] : 0.f);
}

// ---------------------------------------------------------------- MFMA GEMM
// C[M,N] = A[M,Kp] @ BT[N,Kp]^T.  A,BT bf16 row-major; C bf16; f32 accumulate.
// 128x128 block tile, 4 waves in 2x2, each wave 64x64 via 4x4 of 16x16x32 MFMA.
#define BM 128
#define BN 128
#define BK 32
#define LDT 40   /* BK + 8 shorts: pad breaks power-of-2 bank stride */

typedef __attribute__((ext_vector_type(8))) short bf16x8;
typedef __attribute__((ext_vector_type(4))) float f32x4;

__global__ __launch_bounds__(256) void mfma_gemm(const bf16* __restrict__ A,
                                                 const bf16* __restrict__ BT,
                                                 bf16* __restrict__ C,
                                                 int M, int Kp, int N){
  __shared__ short As[BM * LDT];
  __shared__ short Bs[BN * LDT];
  const int tid  = threadIdx.x;
  const int lane = tid & 63;
  const int wave = tid >> 6;
  const int wr   = (wave >> 1) * 64;
  const int wc   = (wave & 1) * 64;
  const int l15  = lane & 15;
  const int quad = lane >> 4;
  const int row0 = blockIdx.y * BM;
  const int col0 = blockIdx.x * BN;

  f32x4 acc[4][4];
#pragma unroll
  for (int i = 0; i < 4; ++i)
#pragma unroll
    for (int j = 0; j < 4; ++j) acc[i][j] = (f32x4){0.f, 0.f, 0.f, 0.f};

  for (int k0 = 0; k0 < Kp; k0 += BK){
    // stage A-tile (128x32) and BT-tile (128x32), 16B chunks, 2 of each per thread
#pragma unroll
    for (int c = 0; c < 2; ++c){
      int ch = tid * 2 + c;              // 0..511
      int r  = ch >> 2;                  // 0..127
      int ko = (ch & 3) * 8;             // 0,8,16,24
      int gr = row0 + r; if (gr >= M) gr = M - 1;
      uint4 va = *(const uint4*)(A  + (size_t)gr * Kp + k0 + ko);
      *(uint4*)(&As[r * LDT + ko]) = va;
      uint4 vb = *(const uint4*)(BT + (size_t)(col0 + r) * Kp + k0 + ko);
      *(uint4*)(&Bs[r * LDT + ko]) = vb;
    }
    __syncthreads();

    bf16x8 af[4], bf[4];
#pragma unroll
    for (int i = 0; i < 4; ++i)
      af[i] = *(bf16x8*)(&As[(wr + i * 16 + l15) * LDT + quad * 8]);
#pragma unroll
    for (int j = 0; j < 4; ++j)
      bf[j] = *(bf16x8*)(&Bs[(wc + j * 16 + l15) * LDT + quad * 8]);
#pragma unroll
    for (int i = 0; i < 4; ++i)
#pragma unroll
      for (int j = 0; j < 4; ++j)
        acc[i][j] = __builtin_amdgcn_mfma_f32_16x16x32_bf16(af[i], bf[j], acc[i][j], 0, 0, 0);
    __syncthreads();
  }

  // epilogue: C/D layout col=lane&15, row=quad*4+reg
#pragma unroll
  for (int i = 0; i < 4; ++i){
#pragma unroll
    for (int j = 0; j < 4; ++j){
      int gc = col0 + wc + j * 16 + l15;
#pragma unroll
      for (int r = 0; r < 4; ++r){
        int gr = row0 + wr + i * 16 + quad * 4 + r;
        if (gr < M && gc < N) C[(size_t)gr * N + gc] = f2b(acc[i][j][r]);
      }
    }
  }
}

// ---------------------------------------------------------------- edge index fetch (with clamp)
__device__ __forceinline__ void edge_sd(const int* esrc, const int* edst, int e, int& s, int& d){
  if (e < N_EDGES){ s = clampi(esrc[e], N_NODES); d = clampi(edst[e], N_NODES); }
  else            { s = d = e - N_EDGES; }
}

// ---------------------------------------------------------------- GAT layer 1 (10 heads x 64)
__global__ __launch_bounds__(256) void edge1_logits(const bf16* __restrict__ xl,
                                                    const bf16* __restrict__ xr,
                                                    const int* __restrict__ esrc,
                                                    const int* __restrict__ edst,
                                                    const float* __restrict__ att,
                                                    float* __restrict__ log1,
                                                    unsigned* __restrict__ m1){
  int wid  = (blockIdx.x * 256 + threadIdx.x) >> 6;
  int lane = threadIdx.x & 63;
  if (wid >= E_TOT) return;
  int s, d; edge_sd(esrc, edst, wid, s, d);
  const bf16* xls = xl + (size_t)s * HID;
  const bf16* xrd = xr + (size_t)d * HID;
  float mine = 0.f;
#pragma unroll
  for (int h = 0; h < HEADS; ++h){
    int idx = h * 64 + lane;
    float v = b2f(xls[idx]) + b2f(xrd[idx]);
    v = v > 0.f ? v : NEG_SLOPE * v;
    v *= att[idx];
#pragma unroll
    for (int off = 32; off > 0; off >>= 1) v += __shfl_xor(v, off);
    if (lane == h) mine = v;
  }
  if (lane < HEADS){
    log1[(size_t)wid * HEADS + lane] = mine;
    atomicMax(&m1[d * HEADS + lane], enc_f(mine));
  }
}

__global__ __launch_bounds__(256) void edge1_exp(const int* __restrict__ esrc,
                                                 const int* __restrict__ edst,
                                                 float* __restrict__ log1,
                                                 const unsigned* __restrict__ m1,
                                                 float* __restrict__ den1){
  int t = blockIdx.x * 256 + threadIdx.x;
  if (t >= E_TOT * HEADS) return;
  int e = t / HEADS, h = t - e * HEADS;
  int s, d; edge_sd(esrc, edst, e, s, d);
  float m  = dec_f(m1[d * HEADS + h]);
  float ex = expf(log1[t] - m);
  log1[t] = ex;
  atomicAdd(&den1[d * HEADS + h], ex);
}

__global__ __launch_bounds__(256) void edge1_scatter(const bf16* __restrict__ xl,
                                                     const int* __restrict__ esrc,
                                                     const int* __restrict__ edst,
                                                     const float* __restrict__ log1,
                                                     const float* __restrict__ den1,
                                                     float* __restrict__ accc,
                                                     int base){
  int wid  = (blockIdx.x * 256 + threadIdx.x) >> 6;
  int lane = threadIdx.x & 63;
  if (wid >= E_TOT) return;
  int s, d; edge_sd(esrc, edst, wid, s, d);
  if (d < base || d >= base + CH) return;
  float alpha = 0.f;
  if (lane < HEADS) alpha = log1[(size_t)wid * HEADS + lane] / den1[d * HEADS + lane];
  const bf16* xls = xl + (size_t)s * HID;
  float* accd = accc + (size_t)(d - base) * HID;
#pragma unroll
  for (int h = 0; h < HEADS; ++h){
    float a = __shfl(alpha, h);
    int idx = h * 64 + lane;
    atomicAdd(&accd[idx], a * b2f(xls[idx]));
  }
}

// ---------------------------------------------------------------- GAT layer 2 (1 head x 640)
__global__ __launch_bounds__(256) void edge2_logits(const bf16* __restrict__ xl,
                                                    const bf16* __restrict__ xr,
                                                    const int* __restrict__ esrc,
                                                    const int* __restrict__ edst,
                                                    const float* __restrict__ att,
                                                    float* __restrict__ log2,
                                                    unsigned* __restrict__ m2){
  int wid  = (blockIdx.x * 256 + threadIdx.x) >> 6;
  int lane = threadIdx.x & 63;
  if (wid >= E_TOT) return;
  int s, d; edge_sd(esrc, edst, wid, s, d);
  const bf16* xls = xl + (size_t)s * HID;
  const bf16* xrd = xr + (size_t)d * HID;
  float sum = 0.f;
#pragma unroll
  for (int i = lane; i < HID; i += 64){
    float v = b2f(xls[i]) + b2f(xrd[i]);
    v = v > 0.f ? v : NEG_SLOPE * v;
    sum += v * att[i];
  }
#pragma unroll
  for (int off = 32; off > 0; off >>= 1) sum += __shfl_xor(sum, off);
  if (lane == 0){
    log2[wid] = sum;
    atomicMax(&m2[d], enc_f(sum));
  }
}

__global__ __launch_bounds__(256) void edge2_exp(const int* __restrict__ esrc,
                                                 const int* __restrict__ edst,
                                                 float* __restrict__ log2,
                                                 const unsigned* __restrict__ m2,
                                                 float* __restrict__ den2){
  int e = blockIdx.x * 256 + threadIdx.x;
  if (e >= E_TOT) return;
  int s, d; edge_sd(esrc, edst, e, s, d);
  float ex = expf(log2[e] - dec_f(m2[d]));
  log2[e] = ex;
  atomicAdd(&den2[d], ex);
}

__global__ __launch_bounds__(256) void edge2_scatter(const bf16* __restrict__ xl,
                                                     const int* __restrict__ esrc,
                                                     const int* __restrict__ edst,
                                                     const float* __restrict__ log2,
                                                     const float* __restrict__ den2,
                                                     float* __restrict__ accc,
                                                     int base){
  int wid  = (blockIdx.x * 256 + threadIdx.x) >> 6;
  int lane = threadIdx.x & 63;
  if (wid >= E_TOT) return;
  int s, d; edge_sd(esrc, edst, wid, s, d);
  if (d < base || d >= base + CH) return;
  float alpha = log2[wid] / den2[d];
  const bf16* xls = xl + (size_t)s * HID;
  float* accd = accc + (size_t)(d - base) * HID;
#pragma unroll
  for (int i = lane; i < HID; i += 64)
    atomicAdd(&accd[i], alpha * b2f(xls[i]));
}

// ---------------------------------------------------------------- bias (+activation) chunk -> bf16 H
template<int MODE>  // 0 = none, 1 = ELU
__global__ __launch_bounds__(256) void bias_act(const float* __restrict__ accc,
                                                const float* __restrict__ bias,
                                                bf16* __restrict__ out, int base){
  int i = blockIdx.x * 256 + threadIdx.x;
  if (i >= CH * HID) return;
  int col = i % HID;
  float v = accc[i] + bias[col];
  if (MODE == 1) v = v > 0.f ? v : (expf(v) - 1.f);
  out[(size_t)base * HID + i] = f2b(v);
}

// ---------------------------------------------------------------- GCN
__global__ __launch_bounds__(256) void deg_kernel(const int* __restrict__ esrc,
                                                  const int* __restrict__ edst,
                                                  float* __restrict__ deg){
  int e = blockIdx.x * 256 + threadIdx.x;
  if (e >= E_TOT) return;
  int s, d; edge_sd(esrc, edst, e, s, d);
  atomicAdd(&deg[d], 1.0f);
}

__global__ __launch_bounds__(256) void dinv_kernel(const float* __restrict__ deg,
                                                   float* __restrict__ dinv){
  int n = blockIdx.x * 256 + threadIdx.x;
  if (n < N_NODES) dinv[n] = rsqrtf(fmaxf(deg[n], 1.0f));
}

__global__ __launch_bounds__(256) void gcn_scatter(const bf16* __restrict__ xw,
                                                   const int* __restrict__ esrc,
                                                   const int* __restrict__ edst,
                                                   const float* __restrict__ dinv,
                                                   float* __restrict__ accc,
                                                   int base){
  int wid  = (blockIdx.x * 256 + threadIdx.x) >> 6;
  int lane = threadIdx.x & 63;
  if (wid >= E_TOT) return;
  int s, d; edge_sd(esrc, edst, wid, s, d);
  if (d < base || d >= base + CH) return;
  float w = dinv[s] * dinv[d];
  const bf16* xs = xw + (size_t)s * HID;
  float* accd = accc + (size_t)(d - base) * HID;
#pragma unroll
  for (int i = lane; i < HID; i += 64)
    atomicAdd(&accd[i], w * b2f(xs[i]));
}

// ---------------------------------------------------------------- pooling
__global__ __launch_bounds__(256) void pool_cnt(const int* __restrict__ batch,
                                                float* __restrict__ cnt){
  int n = blockIdx.x * 256 + threadIdx.x;
  if (n < N_NODES) atomicAdd(&cnt[clampi(batch[n], N_GRAPHS)], 1.0f);
}

__global__ __launch_bounds__(256) void relu_pool(const float* __restrict__ accc,
                                                 const float* __restrict__ bg,
                                                 const int* __restrict__ batch,
                                                 float* __restrict__ pmax,
                                                 float* __restrict__ psum,
                                                 int base){
  int i = blockIdx.x * 256 + threadIdx.x;
  if (i >= CH * HID) return;
  int n = base + i / HID, c = i % HID;
  float v = fmaxf(accc[i] + bg[c], 0.f);
  int g = clampi(batch[n], N_GRAPHS);
  // v >= 0: float bits order as unsigned; pmax zero-initialized.
  atomicMax((unsigned*)&pmax[(size_t)g * HID + c], __float_as_uint(v));
  atomicAdd(&psum[(size_t)g * HID + c], v);
}

__global__ __launch_bounds__(256) void final_out(const float* __restrict__ pmax,
                                                 const float* __restrict__ psum,
                                                 const float* __restrict__ cnt,
                                                 float* __restrict__ out){
  int i = blockIdx.x * 256 + threadIdx.x;
  if (i >= N_GRAPHS * 2 * HID) return;
  int g = i / (2 * HID), c = i - g * (2 * HID);
  float v;
  if (c < HID) v = pmax[(size_t)g * HID + c];
  else         v = psum[(size_t)g * HID + (c - HID)] / fmaxf(cnt[g], 1.0f);
  out[i] = v;
}

// ---------------------------------------------------------------- launch
extern "C" void kernel_launch(void* const* d_in, const int* in_sizes, int n_in,
                              void* d_out, int out_size, void* d_ws, size_t ws_size,
                              hipStream_t stream){
  const float* x     = (const float*)d_in[0];
  const int*   ei    = (const int*)d_in[1];
  const int*   batch = (const int*)d_in[2];
  const float* Wl1 = (const float*)d_in[3];
  const float* Wr1 = (const float*)d_in[4];
  const float* a1  = (const float*)d_in[5];
  const float* b1  = (const float*)d_in[6];
  const float* Wl2 = (const float*)d_in[7];
  const float* Wr2 = (const float*)d_in[8];
  const float* a2  = (const float*)d_in[9];
  const float* b2  = (const float*)d_in[10];
  const float* Wg  = (const float*)d_in[11];
  const float* bg  = (const float*)d_in[12];
  const int* esrc = ei;
  const int* edst = ei + N_EDGES;

  // ---- workspace layout (~224 MB total) ----
  char* ws = (char*)d_ws;
  size_t off = 0;
  auto take = [&](size_t bytes)->char*{
    char* p = ws + off; off = (off + bytes + 255) & ~(size_t)255; return p;
  };
  bf16*     X1   = (bf16*)    take((size_t)N_NODES * HID * 2);   // xl / xw (64 MB)
  char*     X2R  =            take((size_t)N_NODES * HID * 2);   // xr  UNION  f32 acc chunk (64 MB)
  bf16*     X2   = (bf16*)X2R;
  float*    ACCC = (float*)X2R;                                  // CH*HID*4 == 64 MB exactly
  bf16*     H    = (bf16*)    take((size_t)N_NODES * HID * 2);   // h1 then h2 (64 MB)
  bf16*     XB   = (bf16*)    take((size_t)N_NODES * K1P * 2);   // bf16 x, K-padded (9.6 MB)
  bf16*     WT1l = (bf16*)    take((size_t)HID * K1P * 2);
  bf16*     WT1r = (bf16*)    take((size_t)HID * K1P * 2);
  bf16*     WT2l = (bf16*)    take((size_t)HID * HID * 2);
  bf16*     WT2r = (bf16*)    take((size_t)HID * HID * 2);
  bf16*     WTg  = (bf16*)    take((size_t)HID * HID * 2);
  float*    LOG1 = (float*)   take((size_t)E_TOT * HEADS * 4);   // 8 MB
  unsigned* M1   = (unsigned*)take((size_t)N_NODES * HEADS * 4);
  float*    DEN1 = (float*)   take((size_t)N_NODES * HEADS * 4);
  float*    LOG2 = (float*)   take((size_t)E_TOT * 4);
  unsigned* M2   = (unsigned*)take((size_t)N_NODES * 4);
  float*    DEN2 = (float*)   take((size_t)N_NODES * 4);
  float*    DEG  = (float*)   take((size_t)N_NODES * 4);
  float*    DINV = (float*)   take((size_t)N_NODES * 4);
  float*    PMAX = (float*)   take((size_t)N_GRAPHS * HID * 4);
  float*    PSUM = (float*)   take((size_t)N_GRAPHS * HID * 4);
  float*    CNT  = (float*)   take((size_t)N_GRAPHS * 4);

  dim3 blk(256);
  auto fill = [&](void* p, unsigned v, int n){
    fill_u32<<<dim3((n + 255) / 256), blk, 0, stream>>>((unsigned*)p, v, n);
  };
  dim3 ggrid(HID / BN, (N_NODES + BM - 1) / BM);   // (5, 391)
  const int eblocks  = (E_TOT * 64 + 255) / 256;          // wave-per-edge kernels
  const int ehblocks = (E_TOT * HEADS + 255) / 256;
  const int chblocks = (CH * HID + 255) / 256;

  // ---- dtype prep ----
  conv_x<<<(N_NODES * K1P + 255) / 256, blk, 0, stream>>>(x, XB);
  conv_wT<<<(HID * K1P + 255) / 256, blk, 0, stream>>>(Wl1, WT1l, IN_DIM, HID, K1P);
  conv_wT<<<(HID * K1P + 255) / 256, blk, 0, stream>>>(Wr1, WT1r, IN_DIM, HID, K1P);
  conv_wT<<<(HID * HID + 255) / 256, blk, 0, stream>>>(Wl2, WT2l, HID, HID, HID);
  conv_wT<<<(HID * HID + 255) / 256, blk, 0, stream>>>(Wr2, WT2r, HID, HID, HID);
  conv_wT<<<(HID * HID + 255) / 256, blk, 0, stream>>>(Wg,  WTg,  HID, HID, HID);

  // ---- GATv2 layer 1 ----
  fill(M1, ENC_NEG_INF, N_NODES * HEADS);
  fill(DEN1, 0u, N_NODES * HEADS);
  mfma_gemm<<<ggrid, blk, 0, stream>>>(XB, WT1l, X1, N_NODES, K1P, HID);
  mfma_gemm<<<ggrid, blk, 0, stream>>>(XB, WT1r, X2, N_NODES, K1P, HID);
  edge1_logits<<<eblocks, blk, 0, stream>>>(X1, X2, esrc, edst, a1, LOG1, M1);
  edge1_exp<<<ehblocks, blk, 0, stream>>>(esrc, edst, LOG1, M1, DEN1);
  for (int c = 0; c < NCHUNK; ++c){
    int base = c * CH;
    fill(ACCC, 0u, CH * HID);
    edge1_scatter<<<eblocks, blk, 0, stream>>>(X1, esrc, edst, LOG1, DEN1, ACCC, base);
    bias_act<1><<<chblocks, blk, 0, stream>>>(ACCC, b1, H, base);
  }

  // ---- GATv2 layer 2 ----
  fill(M2, ENC_NEG_INF, N_NODES);
  fill(DEN2, 0u, N_NODES);
  mfma_gemm<<<ggrid, blk, 0, stream>>>(H, WT2l, X1, N_NODES, HID, HID);
  mfma_gemm<<<ggrid, blk, 0, stream>>>(H, WT2r, X2, N_NODES, HID, HID);
  edge2_logits<<<eblocks, blk, 0, stream>>>(X1, X2, esrc, edst, a2, LOG2, M2);
  edge2_exp<<<(E_TOT + 255) / 256, blk, 0, stream>>>(esrc, edst, LOG2, M2, DEN2);
  for (int c = 0; c < NCHUNK; ++c){
    int base = c * CH;
    fill(ACCC, 0u, CH * HID);
    edge2_scatter<<<eblocks, blk, 0, stream>>>(X1, esrc, edst, LOG2, DEN2, ACCC, base);
    bias_act<0><<<chblocks, blk, 0, stream>>>(ACCC, b2, H, base);
  }

  // ---- GCN + pooling ----
  fill(DEG, 0u, N_NODES);
  deg_kernel<<<(E_TOT + 255) / 256, blk, 0, stream>>>(esrc, edst, DEG);
  dinv_kernel<<<(N_NODES + 255) / 256, blk, 0, stream>>>(DEG, DINV);
  mfma_gemm<<<ggrid, blk, 0, stream>>>(H, WTg, X1, N_NODES, HID, HID);
  fill(PMAX, 0u, N_GRAPHS * HID);
  fill(PSUM, 0u, N_GRAPHS * HID);
  fill(CNT, 0u, N_GRAPHS);
  pool_cnt<<<(N_NODES + 255) / 256, blk, 0, stream>>>(batch, CNT);
  for (int c = 0; c < NCHUNK; ++c){
    int base = c * CH;
    fill(ACCC, 0u, CH * HID);
    gcn_scatter<<<eblocks, blk, 0, stream>>>(X1, esrc, edst, DINV, ACCC, base);
    relu_pool<<<chblocks, blk, 0, stream>>>(ACCC, bg, batch, PMAX, PSUM, base);
  }
  final_out<<<(N_GRAPHS * 2 * HID + 255) / 256, blk, 0, stream>>>(PMAX, PSUM, CNT, (float*)d_out);
}

// Round 5
// 1069.323 us; speedup vs baseline: 4.4823x; 2.1737x over previous
//
#include <hip/hip_runtime.h>
#include <hip/hip_bf16.h>
#include <cstdint>
#include <cstddef>

typedef __hip_bfloat16 bf16;

#define N_NODES  50000
#define N_EDGES  150000
#define E_TOT    (N_EDGES + N_NODES)   /* 200000: edges then self-loops */
#define N_GRAPHS 1024
#define IN_DIM   78
#define K1P      96                    /* IN_DIM padded to mult of 32 */
#define OUT_DIM  64
#define HEADS    10
#define HID      640
#define NEG_SLOPE 0.2f

static __device__ __forceinline__ float b2f(bf16 v){ return __bfloat162float(v); }
static __device__ __forceinline__ bf16  f2b(float v){ return __float2bfloat16(v); }

__device__ __forceinline__ int clampi(int v, int hi){ return v < 0 ? 0 : (v >= hi ? hi - 1 : v); }

// Order-preserving float<->uint encoding for atomicMax on floats of any sign.
__device__ __forceinline__ unsigned enc_f(float f){
  unsigned u = __float_as_uint(f);
  return (u & 0x80000000u) ? ~u : (u | 0x80000000u);
}
__device__ __forceinline__ float dec_f(unsigned u){
  return (u & 0x80000000u) ? __uint_as_float(u ^ 0x80000000u) : __uint_as_float(~u);
}
#define ENC_NEG_INF 0x007FFFFFu   /* enc_f(-inf) */

// ---------------------------------------------------------------- fills
__global__ __launch_bounds__(256) void fill_u32(unsigned* __restrict__ p, unsigned v, int n){
  int i = blockIdx.x * 256 + threadIdx.x;
  if (i < n) p[i] = v;
}

// ---------------------------------------------------------------- dtype prep
__global__ __launch_bounds__(256) void conv_x(const float* __restrict__ x, bf16* __restrict__ XB){
  int i = blockIdx.x * 256 + threadIdx.x;
  if (i >= N_NODES * K1P) return;
  int n = i / K1P, k = i - n * K1P;
  XB[i] = f2b(k < IN_DIM ? x[(size_t)n * IN_DIM + k] : 0.f);
}

// W (K x N f32, row-major) -> WT (N x Kp bf16, row-major, zero-padded in k)
__global__ __launch_bounds__(256) void conv_wT(const float* __restrict__ W, bf16* __restrict__ WT,
                                               int K, int N, int Kp){
  int i = blockIdx.x * 256 + threadIdx.x;
  if (i >= N * Kp) return;
  int n = i / Kp, k = i - n * Kp;
  WT[i] = f2b(k < K ? W[(size_t)k * N + n] : 0.f);
}

// ---------------------------------------------------------------- MFMA GEMM
// C[M,N] = A[M,Kp] @ BT[N,Kp]^T.  A,BT bf16 row-major; C bf16; f32 accumulate.
// 128x128 block tile, 4 waves in 2x2, each wave 64x64 via 4x4 of 16x16x32 MFMA.
#define BM 128
#define BN 128
#define BK 32
#define LDT 40   /* BK + 8 shorts: pad breaks power-of-2 bank stride */

typedef __attribute__((ext_vector_type(8))) short bf16x8;
typedef __attribute__((ext_vector_type(4))) float f32x4;

__global__ __launch_bounds__(256) void mfma_gemm(const bf16* __restrict__ A,
                                                 const bf16* __restrict__ BT,
                                                 bf16* __restrict__ C,
                                                 int M, int Kp, int N){
  __shared__ short As[BM * LDT];
  __shared__ short Bs[BN * LDT];
  const int tid  = threadIdx.x;
  const int lane = tid & 63;
  const int wave = tid >> 6;
  const int wr   = (wave >> 1) * 64;
  const int wc   = (wave & 1) * 64;
  const int l15  = lane & 15;
  const int quad = lane >> 4;
  const int row0 = blockIdx.y * BM;
  const int col0 = blockIdx.x * BN;

  f32x4 acc[4][4];
#pragma unroll
  for (int i = 0; i < 4; ++i)
#pragma unroll
    for (int j = 0; j < 4; ++j) acc[i][j] = (f32x4){0.f, 0.f, 0.f, 0.f};

  for (int k0 = 0; k0 < Kp; k0 += BK){
#pragma unroll
    for (int c = 0; c < 2; ++c){
      int ch = tid * 2 + c;              // 0..511
      int r  = ch >> 2;                  // 0..127
      int ko = (ch & 3) * 8;             // 0,8,16,24
      int gr = row0 + r; if (gr >= M) gr = M - 1;
      uint4 va = *(const uint4*)(A  + (size_t)gr * Kp + k0 + ko);
      *(uint4*)(&As[r * LDT + ko]) = va;
      uint4 vb = *(const uint4*)(BT + (size_t)(col0 + r) * Kp + k0 + ko);
      *(uint4*)(&Bs[r * LDT + ko]) = vb;
    }
    __syncthreads();

    bf16x8 af[4], bfr[4];
#pragma unroll
    for (int i = 0; i < 4; ++i)
      af[i] = *(bf16x8*)(&As[(wr + i * 16 + l15) * LDT + quad * 8]);
#pragma unroll
    for (int j = 0; j < 4; ++j)
      bfr[j] = *(bf16x8*)(&Bs[(wc + j * 16 + l15) * LDT + quad * 8]);
#pragma unroll
    for (int i = 0; i < 4; ++i)
#pragma unroll
      for (int j = 0; j < 4; ++j)
        acc[i][j] = __builtin_amdgcn_mfma_f32_16x16x32_bf16(af[i], bfr[j], acc[i][j], 0, 0, 0);
    __syncthreads();
  }

  // epilogue: C/D layout col=lane&15, row=quad*4+reg
#pragma unroll
  for (int i = 0; i < 4; ++i){
#pragma unroll
    for (int j = 0; j < 4; ++j){
      int gc = col0 + wc + j * 16 + l15;
#pragma unroll
      for (int r = 0; r < 4; ++r){
        int gr = row0 + wr + i * 16 + quad * 4 + r;
        if (gr < M && gc < N) C[(size_t)gr * N + gc] = f2b(acc[i][j][r]);
      }
    }
  }
}

// ---------------------------------------------------------------- CSR build (in-edges, real edges only)
__global__ __launch_bounds__(256) void count_deg(const int* __restrict__ edst, int* __restrict__ degi){
  int e = blockIdx.x * 256 + threadIdx.x;
  if (e >= N_EDGES) return;
  atomicAdd(&degi[clampi(edst[e], N_NODES)], 1);
}

// single-block hierarchical exclusive scan of DEGI -> ROWP/CURS; also DINV = rsqrt(deg+1)
__global__ __launch_bounds__(1024) void scan_rowp(const int* __restrict__ degi,
                                                  int* __restrict__ rowp,
                                                  int* __restrict__ curs,
                                                  float* __restrict__ dinv){
  __shared__ int wsum[16];
  __shared__ int carry_s;
  const int tid = threadIdx.x, lane = tid & 63, wv = tid >> 6;
  if (tid == 0) carry_s = 0;
  __syncthreads();
  for (int base = 0; base < N_NODES; base += 1024){
    int i = base + tid;
    int v = (i < N_NODES) ? degi[i] : 0;
    int incl = v;
#pragma unroll
    for (int ofs = 1; ofs < 64; ofs <<= 1){
      int t = __shfl_up(incl, ofs);
      if (lane >= ofs) incl += t;
    }
    if (lane == 63) wsum[wv] = incl;
    __syncthreads();
    int woff = 0;
    for (int w = 0; w < 16; ++w) if (w < wv) woff += wsum[w];
    int carry = carry_s;
    if (i < N_NODES){
      int excl = carry + woff + incl - v;
      rowp[i] = excl; curs[i] = excl;
      dinv[i] = rsqrtf((float)(v + 1));
    }
    __syncthreads();
    if (tid == 1023) carry_s = carry + woff + incl;
    __syncthreads();
  }
  if (tid == 0) rowp[N_NODES] = carry_s;
}

__global__ __launch_bounds__(256) void bucket_edges(const int* __restrict__ edst,
                                                    int* __restrict__ curs,
                                                    int* __restrict__ eidx){
  int e = blockIdx.x * 256 + threadIdx.x;
  if (e >= N_EDGES) return;
  int d = clampi(edst[e], N_NODES);
  int pos = atomicAdd(&curs[d], 1);
  eidx[pos] = e;
}

// ---------------------------------------------------------------- GAT logits (scatter-max, unchanged)
__global__ __launch_bounds__(256) void edge1_logits(const bf16* __restrict__ xl,
                                                    const bf16* __restrict__ xr,
                                                    const int* __restrict__ esrc,
                                                    const int* __restrict__ edst,
                                                    const float* __restrict__ att,
                                                    float* __restrict__ log1,
                                                    unsigned* __restrict__ m1){
  int wid  = (blockIdx.x * 256 + threadIdx.x) >> 6;
  int lane = threadIdx.x & 63;
  if (wid >= E_TOT) return;
  int s, d;
  if (wid < N_EDGES){ s = clampi(esrc[wid], N_NODES); d = clampi(edst[wid], N_NODES); }
  else              { s = d = wid - N_EDGES; }
  const bf16* xls = xl + (size_t)s * HID;
  const bf16* xrd = xr + (size_t)d * HID;
  float mine = 0.f;
#pragma unroll
  for (int h = 0; h < HEADS; ++h){
    int idx = h * 64 + lane;
    float v = b2f(xls[idx]) + b2f(xrd[idx]);
    v = v > 0.f ? v : NEG_SLOPE * v;
    v *= att[idx];
#pragma unroll
    for (int off = 32; off > 0; off >>= 1) v += __shfl_xor(v, off);
    if (lane == h) mine = v;
  }
  if (lane < HEADS){
    log1[(size_t)wid * HEADS + lane] = mine;
    atomicMax(&m1[d * HEADS + lane], enc_f(mine));
  }
}

__global__ __launch_bounds__(256) void edge2_logits(const bf16* __restrict__ xl,
                                                    const bf16* __restrict__ xr,
                                                    const int* __restrict__ esrc,
                                                    const int* __restrict__ edst,
                                                    const float* __restrict__ att,
                                                    float* __restrict__ log2,
                                                    unsigned* __restrict__ m2){
  int wid  = (blockIdx.x * 256 + threadIdx.x) >> 6;
  int lane = threadIdx.x & 63;
  if (wid >= E_TOT) return;
  int s, d;
  if (wid < N_EDGES){ s = clampi(esrc[wid], N_NODES); d = clampi(edst[wid], N_NODES); }
  else              { s = d = wid - N_EDGES; }
  const bf16* xls = xl + (size_t)s * HID;
  const bf16* xrd = xr + (size_t)d * HID;
  float sum = 0.f;
#pragma unroll
  for (int i = lane; i < HID; i += 64){
    float v = b2f(xls[i]) + b2f(xrd[i]);
    v = v > 0.f ? v : NEG_SLOPE * v;
    sum += v * att[i];
  }
#pragma unroll
  for (int off = 32; off > 0; off >>= 1) sum += __shfl_xor(sum, off);
  if (lane == 0){
    log2[wid] = sum;
    atomicMax(&m2[d], enc_f(sum));
  }
}

// ---------------------------------------------------------------- gather aggregations (wave per node)
// GAT1: softmax over in-edges per head (den computed in-wave), alpha-weighted sum of xl[src],
//       + bias + ELU, write bf16 H. channel of lane l, head h is h*64+l.
__global__ __launch_bounds__(256) void gat1_gather(const bf16* __restrict__ xl,
                                                   const int* __restrict__ esrc,
                                                   const int* __restrict__ rowp,
                                                   const int* __restrict__ eidx,
                                                   const float* __restrict__ log1,
                                                   const unsigned* __restrict__ m1,
                                                   const float* __restrict__ bias,
                                                   bf16* __restrict__ H){
  int n    = (blockIdx.x * 256 + threadIdx.x) >> 6;
  int lane = threadIdx.x & 63;
  if (n >= N_NODES) return;
  int r0 = rowp[n], r1 = rowp[n + 1];

  float mh = 0.f, a_self = 0.f, den = 0.f;
  if (lane < HEADS){
    mh = dec_f(m1[n * HEADS + lane]);
    a_self = __expf(log1[(size_t)(N_EDGES + n) * HEADS + lane] - mh);
    den = a_self;
  }
  for (int e = r0; e < r1; ++e){
    int eid = eidx[e];
    if (lane < HEADS) den += __expf(log1[(size_t)eid * HEADS + lane] - mh);
  }
  float inv_den = (lane < HEADS) ? 1.f / den : 0.f;

  float acc[HEADS];
  {
    float a = a_self * inv_den;
    const bf16* xn = xl + (size_t)n * HID;
#pragma unroll
    for (int h = 0; h < HEADS; ++h)
      acc[h] = __shfl(a, h) * b2f(xn[h * 64 + lane]);
  }
  for (int e = r0; e < r1; ++e){
    int eid = eidx[e];
    int s = clampi(esrc[eid], N_NODES);
    float a = 0.f;
    if (lane < HEADS) a = __expf(log1[(size_t)eid * HEADS + lane] - mh) * inv_den;
    const bf16* xs = xl + (size_t)s * HID;
#pragma unroll
    for (int h = 0; h < HEADS; ++h)
      acc[h] += __shfl(a, h) * b2f(xs[h * 64 + lane]);
  }
#pragma unroll
  for (int h = 0; h < HEADS; ++h){
    int c = h * 64 + lane;
    float v = acc[h] + bias[c];
    v = v > 0.f ? v : (__expf(v) - 1.f);          // ELU
    H[(size_t)n * HID + c] = f2b(v);
  }
}

// GAT2: single head over 640 channels; channel of lane l, slot j is j*64+l.
__global__ __launch_bounds__(256) void gat2_gather(const bf16* __restrict__ xl,
                                                   const int* __restrict__ esrc,
                                                   const int* __restrict__ rowp,
                                                   const int* __restrict__ eidx,
                                                   const float* __restrict__ log2,
                                                   const unsigned* __restrict__ m2,
                                                   const float* __restrict__ bias,
                                                   bf16* __restrict__ H){
  int n    = (blockIdx.x * 256 + threadIdx.x) >> 6;
  int lane = threadIdx.x & 63;
  if (n >= N_NODES) return;
  int r0 = rowp[n], r1 = rowp[n + 1];

  float m = dec_f(m2[n]);
  float a_self = __expf(log2[N_EDGES + n] - m);
  float den = a_self;
  for (int e = r0; e < r1; ++e) den += __expf(log2[eidx[e]] - m);
  float inv_den = 1.f / den;

  float acc[HEADS];
  {
    float a = a_self * inv_den;
    const bf16* xn = xl + (size_t)n * HID;
#pragma unroll
    for (int j = 0; j < HEADS; ++j) acc[j] = a * b2f(xn[j * 64 + lane]);
  }
  for (int e = r0; e < r1; ++e){
    int eid = eidx[e];
    int s = clampi(esrc[eid], N_NODES);
    float a = __expf(log2[eid] - m) * inv_den;
    const bf16* xs = xl + (size_t)s * HID;
#pragma unroll
    for (int j = 0; j < HEADS; ++j) acc[j] += a * b2f(xs[j * 64 + lane]);
  }
#pragma unroll
  for (int j = 0; j < HEADS; ++j){
    int c = j * 64 + lane;
    H[(size_t)n * HID + c] = f2b(acc[j] + bias[c]);
  }
}

// GCN: normalized sum + bias + ReLU, fused max/mean pooling.
__global__ __launch_bounds__(256) void gcn_gather(const bf16* __restrict__ xw,
                                                  const int* __restrict__ esrc,
                                                  const int* __restrict__ rowp,
                                                  const int* __restrict__ eidx,
                                                  const float* __restrict__ dinv,
                                                  const float* __restrict__ bg,
                                                  const int* __restrict__ batch,
                                                  float* __restrict__ pmax,
                                                  float* __restrict__ psum){
  int n    = (blockIdx.x * 256 + threadIdx.x) >> 6;
  int lane = threadIdx.x & 63;
  if (n >= N_NODES) return;
  int r0 = rowp[n], r1 = rowp[n + 1];

  float dn = dinv[n];
  float acc[HEADS];
  {
    float w = dn * dn;
    const bf16* xn = xw + (size_t)n * HID;
#pragma unroll
    for (int j = 0; j < HEADS; ++j) acc[j] = w * b2f(xn[j * 64 + lane]);
  }
  for (int e = r0; e < r1; ++e){
    int eid = eidx[e];
    int s = clampi(esrc[eid], N_NODES);
    float w = dinv[s] * dn;
    const bf16* xs = xw + (size_t)s * HID;
#pragma unroll
    for (int j = 0; j < HEADS; ++j) acc[j] += w * b2f(xs[j * 64 + lane]);
  }
  int g = clampi(batch[n], N_GRAPHS);
#pragma unroll
  for (int j = 0; j < HEADS; ++j){
    int c = j * 64 + lane;
    float v = fmaxf(acc[j] + bg[c], 0.f);
    atomicMax((unsigned*)&pmax[(size_t)g * HID + c], __float_as_uint(v));
    atomicAdd(&psum[(size_t)g * HID + c], v);
  }
}

// ---------------------------------------------------------------- pooling tail
__global__ __launch_bounds__(256) void pool_cnt(const int* __restrict__ batch,
                                                float* __restrict__ cnt){
  int n = blockIdx.x * 256 + threadIdx.x;
  if (n < N_NODES) atomicAdd(&cnt[clampi(batch[n], N_GRAPHS)], 1.0f);
}

__global__ __launch_bounds__(256) void final_out(const float* __restrict__ pmax,
                                                 const float* __restrict__ psum,
                                                 const float* __restrict__ cnt,
                                                 float* __restrict__ out){
  int i = blockIdx.x * 256 + threadIdx.x;
  if (i >= N_GRAPHS * 2 * HID) return;
  int g = i / (2 * HID), c = i - g * (2 * HID);
  float v;
  if (c < HID) v = pmax[(size_t)g * HID + c];
  else         v = psum[(size_t)g * HID + (c - HID)] / fmaxf(cnt[g], 1.0f);
  out[i] = v;
}

// ---------------------------------------------------------------- launch
extern "C" void kernel_launch(void* const* d_in, const int* in_sizes, int n_in,
                              void* d_out, int out_size, void* d_ws, size_t ws_size,
                              hipStream_t stream){
  const float* x     = (const float*)d_in[0];
  const int*   ei    = (const int*)d_in[1];
  const int*   batch = (const int*)d_in[2];
  const float* Wl1 = (const float*)d_in[3];
  const float* Wr1 = (const float*)d_in[4];
  const float* a1  = (const float*)d_in[5];
  const float* b1  = (const float*)d_in[6];
  const float* Wl2 = (const float*)d_in[7];
  const float* Wr2 = (const float*)d_in[8];
  const float* a2  = (const float*)d_in[9];
  const float* b2  = (const float*)d_in[10];
  const float* Wg  = (const float*)d_in[11];
  const float* bg  = (const float*)d_in[12];
  const int* esrc = ei;
  const int* edst = ei + N_EDGES;

  // ---- workspace layout (~210 MB total) ----
  char* ws = (char*)d_ws;
  size_t off = 0;
  auto take = [&](size_t bytes)->char*{
    char* p = ws + off; off = (off + bytes + 255) & ~(size_t)255; return p;
  };
  bf16*     X1   = (bf16*)    take((size_t)N_NODES * HID * 2);   // xl / xw (64 MB)
  bf16*     X2   = (bf16*)    take((size_t)N_NODES * HID * 2);   // xr (64 MB)
  bf16*     H    = (bf16*)    take((size_t)N_NODES * HID * 2);   // h1 then h2 (64 MB)
  bf16*     XB   = (bf16*)    take((size_t)N_NODES * K1P * 2);   // bf16 x, K-padded (9.6 MB)
  bf16*     WT1l = (bf16*)    take((size_t)HID * K1P * 2);
  bf16*     WT1r = (bf16*)    take((size_t)HID * K1P * 2);
  bf16*     WT2l = (bf16*)    take((size_t)HID * HID * 2);
  bf16*     WT2r = (bf16*)    take((size_t)HID * HID * 2);
  bf16*     WTg  = (bf16*)    take((size_t)HID * HID * 2);
  float*    LOG1 = (float*)   take((size_t)E_TOT * HEADS * 4);   // 8 MB
  unsigned* M1   = (unsigned*)take((size_t)N_NODES * HEADS * 4);
  float*    LOG2 = (float*)   take((size_t)E_TOT * 4);
  unsigned* M2   = (unsigned*)take((size_t)N_NODES * 4);
  int*      DEGI = (int*)     take((size_t)N_NODES * 4);
  int*      ROWP = (int*)     take((size_t)(N_NODES + 1) * 4);
  int*      CURS = (int*)     take((size_t)N_NODES * 4);
  int*      EIDX = (int*)     take((size_t)N_EDGES * 4);
  float*    DINV = (float*)   take((size_t)N_NODES * 4);
  float*    PMAX = (float*)   take((size_t)N_GRAPHS * HID * 4);
  float*    PSUM = (float*)   take((size_t)N_GRAPHS * HID * 4);
  float*    CNT  = (float*)   take((size_t)N_GRAPHS * 4);

  dim3 blk(256);
  auto fill = [&](void* p, unsigned v, int n){
    fill_u32<<<dim3((n + 255) / 256), blk, 0, stream>>>((unsigned*)p, v, n);
  };
  dim3 ggrid(HID / BN, (N_NODES + BM - 1) / BM);   // (5, 391)
  const int eblocks = (E_TOT * 64 + 255) / 256;    // wave-per-edge kernels
  const int nblocks = (N_NODES * 64 + 255) / 256;  // wave-per-node kernels
  const int reblk   = (N_EDGES + 255) / 256;

  // ---- dtype prep + CSR build ----
  conv_x<<<(N_NODES * K1P + 255) / 256, blk, 0, stream>>>(x, XB);
  conv_wT<<<(HID * K1P + 255) / 256, blk, 0, stream>>>(Wl1, WT1l, IN_DIM, HID, K1P);
  conv_wT<<<(HID * K1P + 255) / 256, blk, 0, stream>>>(Wr1, WT1r, IN_DIM, HID, K1P);
  conv_wT<<<(HID * HID + 255) / 256, blk, 0, stream>>>(Wl2, WT2l, HID, HID, HID);
  conv_wT<<<(HID * HID + 255) / 256, blk, 0, stream>>>(Wr2, WT2r, HID, HID, HID);
  conv_wT<<<(HID * HID + 255) / 256, blk, 0, stream>>>(Wg,  WTg,  HID, HID, HID);
  fill(DEGI, 0u, N_NODES);
  count_deg<<<reblk, blk, 0, stream>>>(edst, DEGI);
  scan_rowp<<<1, 1024, 0, stream>>>(DEGI, ROWP, CURS, DINV);
  bucket_edges<<<reblk, blk, 0, stream>>>(edst, CURS, EIDX);

  // ---- GATv2 layer 1 ----
  fill(M1, ENC_NEG_INF, N_NODES * HEADS);
  mfma_gemm<<<ggrid, blk, 0, stream>>>(XB, WT1l, X1, N_NODES, K1P, HID);
  mfma_gemm<<<ggrid, blk, 0, stream>>>(XB, WT1r, X2, N_NODES, K1P, HID);
  edge1_logits<<<eblocks, blk, 0, stream>>>(X1, X2, esrc, edst, a1, LOG1, M1);
  gat1_gather<<<nblocks, blk, 0, stream>>>(X1, esrc, ROWP, EIDX, LOG1, M1, b1, H);

  // ---- GATv2 layer 2 ----
  fill(M2, ENC_NEG_INF, N_NODES);
  mfma_gemm<<<ggrid, blk, 0, stream>>>(H, WT2l, X1, N_NODES, HID, HID);
  mfma_gemm<<<ggrid, blk, 0, stream>>>(H, WT2r, X2, N_NODES, HID, HID);
  edge2_logits<<<eblocks, blk, 0, stream>>>(X1, X2, esrc, edst, a2, LOG2, M2);
  gat2_gather<<<nblocks, blk, 0, stream>>>(X1, esrc, ROWP, EIDX, LOG2, M2, b2, H);

  // ---- GCN + pooling ----
  mfma_gemm<<<ggrid, blk, 0, stream>>>(H, WTg, X1, N_NODES, HID, HID);
  fill(PMAX, 0u, N_GRAPHS * HID);
  fill(PSUM, 0u, N_GRAPHS * HID);
  fill(CNT, 0u, N_GRAPHS);
  pool_cnt<<<(N_NODES + 255) / 256, blk, 0, stream>>>(batch, CNT);
  gcn_gather<<<nblocks, blk, 0, stream>>>(X1, esrc, ROWP, EIDX, DINV, bg, batch, PMAX, PSUM);
  final_out<<<(N_GRAPHS * 2 * HID + 255) / 256, blk, 0, stream>>>(PMAX, PSUM, CNT, (float*)d_out);
}

// Round 6
// 842.230 us; speedup vs baseline: 5.6909x; 1.2696x over previous
//
#include <hip/hip_runtime.h>
#include <hip/hip_bf16.h>
#include <cstdint>
#include <cstddef>

typedef __hip_bfloat16 bf16;

#define N_NODES  50000
#define N_EDGES  150000
#define E_TOT    (N_EDGES + N_NODES)
#define N_GRAPHS 1024
#define IN_DIM   78
#define K1P      96                    /* IN_DIM padded to mult of 32 */
#define OUT_DIM  64
#define HEADS    10
#define HID      640
#define NEG_SLOPE 0.2f

static __device__ __forceinline__ float b2f(bf16 v){ return __bfloat162float(v); }
static __device__ __forceinline__ bf16  f2b(float v){ return __float2bfloat16(v); }

__device__ __forceinline__ int clampi(int v, int hi){ return v < 0 ? 0 : (v >= hi ? hi - 1 : v); }

// ---------------------------------------------------------------- fills
__global__ __launch_bounds__(256) void fill_u32(unsigned* __restrict__ p, unsigned v, int n){
  int i = blockIdx.x * 256 + threadIdx.x;
  if (i < n) p[i] = v;
}

// ---------------------------------------------------------------- dtype prep
__global__ __launch_bounds__(256) void conv_x(const float* __restrict__ x, bf16* __restrict__ XB){
  int i = blockIdx.x * 256 + threadIdx.x;
  if (i >= N_NODES * K1P) return;
  int n = i / K1P, k = i - n * K1P;
  XB[i] = f2b(k < IN_DIM ? x[(size_t)n * IN_DIM + k] : 0.f);
}

// W (K x N f32, row-major) -> WT (N x Kp bf16, row-major, zero-padded in k)
__global__ __launch_bounds__(256) void conv_wT(const float* __restrict__ W, bf16* __restrict__ WT,
                                               int K, int N, int Kp){
  int i = blockIdx.x * 256 + threadIdx.x;
  if (i >= N * Kp) return;
  int n = i / Kp, k = i - n * Kp;
  WT[i] = f2b(k < K ? W[(size_t)k * N + n] : 0.f);
}

// ---------------------------------------------------------------- MFMA GEMM
#define BM 128
#define BN 128
#define BK 32
#define LDT 40   /* BK + 8 shorts: pad breaks power-of-2 bank stride */

typedef __attribute__((ext_vector_type(8))) short bf16x8;
typedef __attribute__((ext_vector_type(4))) float f32x4;

__global__ __launch_bounds__(256) void mfma_gemm(const bf16* __restrict__ A,
                                                 const bf16* __restrict__ BT,
                                                 bf16* __restrict__ C,
                                                 int M, int Kp, int N){
  __shared__ short As[BM * LDT];
  __shared__ short Bs[BN * LDT];
  const int tid  = threadIdx.x;
  const int lane = tid & 63;
  const int wave = tid >> 6;
  const int wr   = (wave >> 1) * 64;
  const int wc   = (wave & 1) * 64;
  const int l15  = lane & 15;
  const int quad = lane >> 4;
  const int row0 = blockIdx.y * BM;
  const int col0 = blockIdx.x * BN;

  f32x4 acc[4][4];
#pragma unroll
  for (int i = 0; i < 4; ++i)
#pragma unroll
    for (int j = 0; j < 4; ++j) acc[i][j] = (f32x4){0.f, 0.f, 0.f, 0.f};

  for (int k0 = 0; k0 < Kp; k0 += BK){
#pragma unroll
    for (int c = 0; c < 2; ++c){
      int ch = tid * 2 + c;
      int r  = ch >> 2;
      int ko = (ch & 3) * 8;
      int gr = row0 + r; if (gr >= M) gr = M - 1;
      uint4 va = *(const uint4*)(A  + (size_t)gr * Kp + k0 + ko);
      *(uint4*)(&As[r * LDT + ko]) = va;
      uint4 vb = *(const uint4*)(BT + (size_t)(col0 + r) * Kp + k0 + ko);
      *(uint4*)(&Bs[r * LDT + ko]) = vb;
    }
    __syncthreads();

    bf16x8 af[4], bfr[4];
#pragma unroll
    for (int i = 0; i < 4; ++i)
      af[i] = *(bf16x8*)(&As[(wr + i * 16 + l15) * LDT + quad * 8]);
#pragma unroll
    for (int j = 0; j < 4; ++j)
      bfr[j] = *(bf16x8*)(&Bs[(wc + j * 16 + l15) * LDT + quad * 8]);
#pragma unroll
    for (int i = 0; i < 4; ++i)
#pragma unroll
      for (int j = 0; j < 4; ++j)
        acc[i][j] = __builtin_amdgcn_mfma_f32_16x16x32_bf16(af[i], bfr[j], acc[i][j], 0, 0, 0);
    __syncthreads();
  }

#pragma unroll
  for (int i = 0; i < 4; ++i){
#pragma unroll
    for (int j = 0; j < 4; ++j){
      int gc = col0 + wc + j * 16 + l15;
#pragma unroll
      for (int r = 0; r < 4; ++r){
        int gr = row0 + wr + i * 16 + quad * 4 + r;
        if (gr < M && gc < N) C[(size_t)gr * N + gc] = f2b(acc[i][j][r]);
      }
    }
  }
}

// ---------------------------------------------------------------- CSR build (in-edges, real edges only)
__global__ __launch_bounds__(256) void count_deg(const int* __restrict__ edst, int* __restrict__ degi){
  int e = blockIdx.x * 256 + threadIdx.x;
  if (e >= N_EDGES) return;
  atomicAdd(&degi[clampi(edst[e], N_NODES)], 1);
}

// single-block hierarchical exclusive scan of DEGI -> ROWP/CURS; also DINV = rsqrt(deg+1)
__global__ __launch_bounds__(1024) void scan_rowp(const int* __restrict__ degi,
                                                  int* __restrict__ rowp,
                                                  int* __restrict__ curs,
                                                  float* __restrict__ dinv){
  __shared__ int wsum[16];
  __shared__ int carry_s;
  const int tid = threadIdx.x, lane = tid & 63, wv = tid >> 6;
  if (tid == 0) carry_s = 0;
  __syncthreads();
  for (int base = 0; base < N_NODES; base += 1024){
    int i = base + tid;
    int v = (i < N_NODES) ? degi[i] : 0;
    int incl = v;
#pragma unroll
    for (int ofs = 1; ofs < 64; ofs <<= 1){
      int t = __shfl_up(incl, ofs);
      if (lane >= ofs) incl += t;
    }
    if (lane == 63) wsum[wv] = incl;
    __syncthreads();
    int woff = 0;
    for (int w = 0; w < 16; ++w) if (w < wv) woff += wsum[w];
    int carry = carry_s;
    if (i < N_NODES){
      int excl = carry + woff + incl - v;
      rowp[i] = excl; curs[i] = excl;
      dinv[i] = rsqrtf((float)(v + 1));
    }
    __syncthreads();
    if (tid == 1023) carry_s = carry + woff + incl;
    __syncthreads();
  }
  if (tid == 0) rowp[N_NODES] = carry_s;
}

__global__ __launch_bounds__(256) void bucket_edges(const int* __restrict__ edst,
                                                    int* __restrict__ curs,
                                                    int* __restrict__ eidx){
  int e = blockIdx.x * 256 + threadIdx.x;
  if (e >= N_EDGES) return;
  int d = clampi(edst[e], N_NODES);
  int pos = atomicAdd(&curs[d], 1);
  eidx[pos] = e;
}

// ---------------------------------------------------------------- fused GATv2 layer 1
// wave per dst node; lane l holds channel h*64+l of each head h.
// online softmax over {self} ∪ in-edges; each xl[src] row read exactly once.
__global__ __launch_bounds__(256) void gat1_fused(const bf16* __restrict__ xl,
                                                  const bf16* __restrict__ xr,
                                                  const int* __restrict__ esrc,
                                                  const int* __restrict__ rowp,
                                                  const int* __restrict__ eidx,
                                                  const float* __restrict__ att,
                                                  const float* __restrict__ bias,
                                                  bf16* __restrict__ H){
  int n    = (blockIdx.x * 256 + threadIdx.x) >> 6;
  int lane = threadIdx.x & 63;
  if (n >= N_NODES) return;
  int r0 = rowp[n], r1 = rowp[n + 1];

  float xrd[HEADS], attv[HEADS], acc[HEADS], m[HEADS], den[HEADS];
  const bf16* xrn = xr + (size_t)n * HID;
  const bf16* xln = xl + (size_t)n * HID;
#pragma unroll
  for (int h = 0; h < HEADS; ++h){
    xrd[h]  = b2f(xrn[h * 64 + lane]);
    attv[h] = att[h * 64 + lane];
  }
  // self-loop initializes the online state
#pragma unroll
  for (int h = 0; h < HEADS; ++h){
    float xv = b2f(xln[h * 64 + lane]);
    float v = xv + xrd[h];
    v = v > 0.f ? v : NEG_SLOPE * v;
    v *= attv[h];
#pragma unroll
    for (int o = 32; o > 0; o >>= 1) v += __shfl_xor(v, o);   // all lanes get head-h logit
    m[h] = v; den[h] = 1.f; acc[h] = xv;
  }
  for (int e = r0; e < r1; ++e){
    int s = clampi(esrc[eidx[e]], N_NODES);
    const bf16* xs = xl + (size_t)s * HID;
#pragma unroll
    for (int h = 0; h < HEADS; ++h){
      float xv = b2f(xs[h * 64 + lane]);
      float v = xv + xrd[h];
      v = v > 0.f ? v : NEG_SLOPE * v;
      v *= attv[h];
#pragma unroll
      for (int o = 32; o > 0; o >>= 1) v += __shfl_xor(v, o);
      float mn = fmaxf(m[h], v);
      float sc = __expf(m[h] - mn);
      float p  = __expf(v - mn);
      den[h] = den[h] * sc + p;
      acc[h] = acc[h] * sc + p * xv;
      m[h] = mn;
    }
  }
#pragma unroll
  for (int h = 0; h < HEADS; ++h){
    int c = h * 64 + lane;
    float v = acc[h] / den[h] + bias[c];
    v = v > 0.f ? v : (__expf(v) - 1.f);          // ELU
    H[(size_t)n * HID + c] = f2b(v);
  }
}

// ---------------------------------------------------------------- fused GATv2 layer 2 (1 head x 640)
__global__ __launch_bounds__(256) void gat2_fused(const bf16* __restrict__ xl,
                                                  const bf16* __restrict__ xr,
                                                  const int* __restrict__ esrc,
                                                  const int* __restrict__ rowp,
                                                  const int* __restrict__ eidx,
                                                  const float* __restrict__ att,
                                                  const float* __restrict__ bias,
                                                  bf16* __restrict__ H){
  int n    = (blockIdx.x * 256 + threadIdx.x) >> 6;
  int lane = threadIdx.x & 63;
  if (n >= N_NODES) return;
  int r0 = rowp[n], r1 = rowp[n + 1];

  float xrd[HEADS], attv[HEADS], acc[HEADS];
  const bf16* xrn = xr + (size_t)n * HID;
  const bf16* xln = xl + (size_t)n * HID;
#pragma unroll
  for (int j = 0; j < HEADS; ++j){
    xrd[j]  = b2f(xrn[j * 64 + lane]);
    attv[j] = att[j * 64 + lane];
  }
  float m, den;
  {
    float xv[HEADS], ps = 0.f;
#pragma unroll
    for (int j = 0; j < HEADS; ++j){
      xv[j] = b2f(xln[j * 64 + lane]);
      float v = xv[j] + xrd[j];
      v = v > 0.f ? v : NEG_SLOPE * v;
      ps += v * attv[j];
    }
#pragma unroll
    for (int o = 32; o > 0; o >>= 1) ps += __shfl_xor(ps, o);
    m = ps; den = 1.f;
#pragma unroll
    for (int j = 0; j < HEADS; ++j) acc[j] = xv[j];
  }
  for (int e = r0; e < r1; ++e){
    int s = clampi(esrc[eidx[e]], N_NODES);
    const bf16* xs = xl + (size_t)s * HID;
    float xv[HEADS], ps = 0.f;
#pragma unroll
    for (int j = 0; j < HEADS; ++j){
      xv[j] = b2f(xs[j * 64 + lane]);
      float v = xv[j] + xrd[j];
      v = v > 0.f ? v : NEG_SLOPE * v;
      ps += v * attv[j];
    }
#pragma unroll
    for (int o = 32; o > 0; o >>= 1) ps += __shfl_xor(ps, o);
    float mn = fmaxf(m, ps);
    float sc = __expf(m - mn);
    float p  = __expf(ps - mn);
    den = den * sc + p;
#pragma unroll
    for (int j = 0; j < HEADS; ++j) acc[j] = acc[j] * sc + p * xv[j];
    m = mn;
  }
  float inv = 1.f / den;
#pragma unroll
  for (int j = 0; j < HEADS; ++j){
    int c = j * 64 + lane;
    H[(size_t)n * HID + c] = f2b(acc[j] * inv + bias[c]);
  }
}

// ---------------------------------------------------------------- GCN gather: bias+ReLU -> bf16 h3
__global__ __launch_bounds__(256) void gcn_gather(const bf16* __restrict__ xw,
                                                  const int* __restrict__ esrc,
                                                  const int* __restrict__ rowp,
                                                  const int* __restrict__ eidx,
                                                  const float* __restrict__ dinv,
                                                  const float* __restrict__ bg,
                                                  bf16* __restrict__ h3){
  int n    = (blockIdx.x * 256 + threadIdx.x) >> 6;
  int lane = threadIdx.x & 63;
  if (n >= N_NODES) return;
  int r0 = rowp[n], r1 = rowp[n + 1];

  float dn = dinv[n];
  float acc[HEADS];
  {
    float w = dn * dn;
    const bf16* xn = xw + (size_t)n * HID;
#pragma unroll
    for (int j = 0; j < HEADS; ++j) acc[j] = w * b2f(xn[j * 64 + lane]);
  }
  for (int e = r0; e < r1; ++e){
    int s = clampi(esrc[eidx[e]], N_NODES);
    float w = dinv[s] * dn;
    const bf16* xs = xw + (size_t)s * HID;
#pragma unroll
    for (int j = 0; j < HEADS; ++j) acc[j] += w * b2f(xs[j * 64 + lane]);
  }
#pragma unroll
  for (int j = 0; j < HEADS; ++j){
    int c = j * 64 + lane;
    h3[(size_t)n * HID + c] = f2b(fmaxf(acc[j] + bg[c], 0.f));
  }
}

// ---------------------------------------------------------------- per-graph pooling (batch is sorted)
__global__ __launch_bounds__(256) void graph_bounds(const int* __restrict__ batch,
                                                    int* __restrict__ gstart){
  int n = blockIdx.x * 256 + threadIdx.x;
  if (n >= N_NODES) return;
  int b = clampi(batch[n], N_GRAPHS);
  if (n == 0){
    for (int g = 0; g <= b; ++g) gstart[g] = 0;
  } else {
    int bp = clampi(batch[n - 1], N_GRAPHS);
    for (int g = bp + 1; g <= b; ++g) gstart[g] = n;
  }
  if (n == N_NODES - 1){
    for (int g = b + 1; g <= N_GRAPHS; ++g) gstart[g] = N_NODES;
  }
}

__global__ __launch_bounds__(640) void pool_graph(const bf16* __restrict__ h3,
                                                  const int* __restrict__ gstart,
                                                  float* __restrict__ out){
  int g = blockIdx.x;
  int c = threadIdx.x;          // 0..639, one channel per thread
  int n0 = gstart[g], n1 = gstart[g + 1];
  float mx = 0.f, sm = 0.f;     // h3 >= 0 post-ReLU, so max init 0 is exact
  for (int n = n0; n < n1; ++n){
    float v = b2f(h3[(size_t)n * HID + c]);
    mx = fmaxf(mx, v); sm += v;
  }
  float mean = (n1 > n0) ? sm / (float)(n1 - n0) : 0.f;
  out[(size_t)g * 2 * HID + c]       = mx;
  out[(size_t)g * 2 * HID + HID + c] = mean;
}

// ---------------------------------------------------------------- launch
extern "C" void kernel_launch(void* const* d_in, const int* in_sizes, int n_in,
                              void* d_out, int out_size, void* d_ws, size_t ws_size,
                              hipStream_t stream){
  const float* x     = (const float*)d_in[0];
  const int*   ei    = (const int*)d_in[1];
  const int*   batch = (const int*)d_in[2];
  const float* Wl1 = (const float*)d_in[3];
  const float* Wr1 = (const float*)d_in[4];
  const float* a1  = (const float*)d_in[5];
  const float* b1  = (const float*)d_in[6];
  const float* Wl2 = (const float*)d_in[7];
  const float* Wr2 = (const float*)d_in[8];
  const float* a2  = (const float*)d_in[9];
  const float* b2  = (const float*)d_in[10];
  const float* Wg  = (const float*)d_in[11];
  const float* bg  = (const float*)d_in[12];
  const int* esrc = ei;
  const int* edst = ei + N_EDGES;

  // ---- workspace layout (~205 MB total) ----
  char* ws = (char*)d_ws;
  size_t off = 0;
  auto take = [&](size_t bytes)->char*{
    char* p = ws + off; off = (off + bytes + 255) & ~(size_t)255; return p;
  };
  bf16*     X1   = (bf16*)    take((size_t)N_NODES * HID * 2);   // xl / xw (64 MB)
  bf16*     X2   = (bf16*)    take((size_t)N_NODES * HID * 2);   // xr / h3 (64 MB)
  bf16*     H    = (bf16*)    take((size_t)N_NODES * HID * 2);   // h1 then h2 (64 MB)
  bf16*     XB   = (bf16*)    take((size_t)N_NODES * K1P * 2);   // bf16 x, K-padded (9.6 MB)
  bf16*     WT1l = (bf16*)    take((size_t)HID * K1P * 2);
  bf16*     WT1r = (bf16*)    take((size_t)HID * K1P * 2);
  bf16*     WT2l = (bf16*)    take((size_t)HID * HID * 2);
  bf16*     WT2r = (bf16*)    take((size_t)HID * HID * 2);
  bf16*     WTg  = (bf16*)    take((size_t)HID * HID * 2);
  int*      DEGI = (int*)     take((size_t)N_NODES * 4);
  int*      ROWP = (int*)     take((size_t)(N_NODES + 1) * 4);
  int*      CURS = (int*)     take((size_t)N_NODES * 4);
  int*      EIDX = (int*)     take((size_t)N_EDGES * 4);
  float*    DINV = (float*)   take((size_t)N_NODES * 4);
  int*      GST  = (int*)     take((size_t)(N_GRAPHS + 1) * 4);

  dim3 blk(256);
  auto fill = [&](void* p, unsigned v, int n){
    fill_u32<<<dim3((n + 255) / 256), blk, 0, stream>>>((unsigned*)p, v, n);
  };
  dim3 ggrid(HID / BN, (N_NODES + BM - 1) / BM);   // (5, 391)
  const int nblocks = (N_NODES * 64 + 255) / 256;  // wave-per-node kernels
  const int reblk   = (N_EDGES + 255) / 256;

  // ---- dtype prep + CSR build ----
  conv_x<<<(N_NODES * K1P + 255) / 256, blk, 0, stream>>>(x, XB);
  conv_wT<<<(HID * K1P + 255) / 256, blk, 0, stream>>>(Wl1, WT1l, IN_DIM, HID, K1P);
  conv_wT<<<(HID * K1P + 255) / 256, blk, 0, stream>>>(Wr1, WT1r, IN_DIM, HID, K1P);
  conv_wT<<<(HID * HID + 255) / 256, blk, 0, stream>>>(Wl2, WT2l, HID, HID, HID);
  conv_wT<<<(HID * HID + 255) / 256, blk, 0, stream>>>(Wr2, WT2r, HID, HID, HID);
  conv_wT<<<(HID * HID + 255) / 256, blk, 0, stream>>>(Wg,  WTg,  HID, HID, HID);
  fill(DEGI, 0u, N_NODES);
  count_deg<<<reblk, blk, 0, stream>>>(edst, DEGI);
  scan_rowp<<<1, 1024, 0, stream>>>(DEGI, ROWP, CURS, DINV);
  bucket_edges<<<reblk, blk, 0, stream>>>(edst, CURS, EIDX);
  graph_bounds<<<(N_NODES + 255) / 256, blk, 0, stream>>>(batch, GST);

  // ---- GATv2 layer 1 ----
  mfma_gemm<<<ggrid, blk, 0, stream>>>(XB, WT1l, X1, N_NODES, K1P, HID);
  mfma_gemm<<<ggrid, blk, 0, stream>>>(XB, WT1r, X2, N_NODES, K1P, HID);
  gat1_fused<<<nblocks, blk, 0, stream>>>(X1, X2, esrc, ROWP, EIDX, a1, b1, H);

  // ---- GATv2 layer 2 ----
  mfma_gemm<<<ggrid, blk, 0, stream>>>(H, WT2l, X1, N_NODES, HID, HID);
  mfma_gemm<<<ggrid, blk, 0, stream>>>(H, WT2r, X2, N_NODES, HID, HID);
  gat2_fused<<<nblocks, blk, 0, stream>>>(X1, X2, esrc, ROWP, EIDX, a2, b2, H);

  // ---- GCN + pooling ----
  mfma_gemm<<<ggrid, blk, 0, stream>>>(H, WTg, X1, N_NODES, HID, HID);
  gcn_gather<<<nblocks, blk, 0, stream>>>(X1, esrc, ROWP, EIDX, DINV, bg, X2);
  pool_graph<<<dim3(N_GRAPHS), dim3(640), 0, stream>>>(X2, GST, (float*)d_out);
}

// Round 7
// 823.599 us; speedup vs baseline: 5.8196x; 1.0226x over previous
//
#include <hip/hip_runtime.h>
#include <hip/hip_bf16.h>
#include <cstdint>
#include <cstddef>

typedef __hip_bfloat16 bf16;

#define N_NODES  50000
#define N_EDGES  150000
#define E_TOT    (N_EDGES + N_NODES)   /* edges then self-loops */
#define N_TILES  ((E_TOT + 15) / 16)
#define N_GRAPHS 1024
#define IN_DIM   78
#define K1P      96                    /* IN_DIM padded to mult of 32 */
#define OUT_DIM  64
#define HEADS    10
#define HID      640
#define NEG_SLOPE 0.2f

static __device__ __forceinline__ float b2f(bf16 v){ return __bfloat162float(v); }
static __device__ __forceinline__ bf16  f2b(float v){ return __float2bfloat16(v); }

__device__ __forceinline__ int clampi(int v, int hi){ return v < 0 ? 0 : (v >= hi ? hi - 1 : v); }

// bf16 bit helpers (no API dependence)
__device__ __forceinline__ float bf2f_bits(short s){
  return __uint_as_float(((unsigned)(unsigned short)s) << 16);
}
__device__ __forceinline__ short f2bf_bits(float v){
  unsigned u = __float_as_uint(v);
  return (short)((u + 0x7fffu + ((u >> 16) & 1u)) >> 16);   // RNE
}

// ---------------------------------------------------------------- fills
__global__ __launch_bounds__(256) void fill_u32(unsigned* __restrict__ p, unsigned v, int n){
  int i = blockIdx.x * 256 + threadIdx.x;
  if (i < n) p[i] = v;
}

// ---------------------------------------------------------------- dtype prep
__global__ __launch_bounds__(256) void conv_x(const float* __restrict__ x, bf16* __restrict__ XB){
  int i = blockIdx.x * 256 + threadIdx.x;
  if (i >= N_NODES * K1P) return;
  int n = i / K1P, k = i - n * K1P;
  XB[i] = f2b(k < IN_DIM ? x[(size_t)n * IN_DIM + k] : 0.f);
}

// W (K x N f32, row-major) -> WT (N x Kp bf16, row-major, zero-padded in k)
__global__ __launch_bounds__(256) void conv_wT(const float* __restrict__ W, bf16* __restrict__ WT,
                                               int K, int N, int Kp){
  int i = blockIdx.x * 256 + threadIdx.x;
  if (i >= N * Kp) return;
  int n = i / Kp, k = i - n * Kp;
  WT[i] = f2b(k < K ? W[(size_t)k * N + n] : 0.f);
}

// att -> B-fragment-ordered matrix for 16x16x32 MFMA.
// element i: chunk=i>>9, lane=(i>>3)&63, j=i&7; h=lane&15, k=(lane>>4)*8+j, c=chunk*32+k.
// layer1 (heads=10): B[c][h] = (h<10 && c>>6==h) ? a1_flat[c] : 0  (block-diagonal)
// layer2 (heads=1):  B[c][0] = a2[c]
__global__ __launch_bounds__(256) void conv_attP(const float* __restrict__ a, bf16* __restrict__ P,
                                                 int heads){
  int i = blockIdx.x * 256 + threadIdx.x;
  if (i >= (HID / 32) * 512) return;
  int chunk = i >> 9;
  int lane  = (i >> 3) & 63;
  int j     = i & 7;
  int h = lane & 15;
  int k = (lane >> 4) * 8 + j;
  int c = chunk * 32 + k;
  float v = 0.f;
  if (heads == HEADS){ if (h < HEADS && (c >> 6) == h) v = a[c]; }
  else               { if (h == 0) v = a[c]; }
  P[i] = f2b(v);
}

// ---------------------------------------------------------------- MFMA GEMM (global_load_lds staging)
#define BM 128
#define BN 128
#define BK 32

typedef __attribute__((ext_vector_type(8))) short bf16x8;
typedef __attribute__((ext_vector_type(4))) float f32x4;

typedef const __attribute__((address_space(1))) unsigned gu32;
typedef __attribute__((address_space(3))) unsigned lu32;

__global__ __launch_bounds__(256) void mfma_gemm(const bf16* __restrict__ A,
                                                 const bf16* __restrict__ BT,
                                                 bf16* __restrict__ C,
                                                 int M, int Kp, int N){
  __shared__ short As[BM * BK];   // 8 KB, row-major [r][k], no pad (m97 pattern)
  __shared__ short Bs[BN * BK];
  const int tid  = threadIdx.x;
  const int lane = tid & 63;
  const int wave = tid >> 6;
  const int wr   = (wave >> 1) * 64;
  const int wc   = (wave & 1) * 64;
  const int l15  = lane & 15;
  const int quad = lane >> 4;
  const int row0 = blockIdx.y * BM;
  const int col0 = blockIdx.x * BN;

  f32x4 acc[4][4];
#pragma unroll
  for (int i = 0; i < 4; ++i)
#pragma unroll
    for (int j = 0; j < 4; ++j) acc[i][j] = (f32x4){0.f, 0.f, 0.f, 0.f};

  for (int k0 = 0; k0 < Kp; k0 += BK){
    // stage A and B tiles: 512 16B-chunks each; ci=(t*4+wave)*64+lane; r=ci>>2, ko=(ci&3)*8
#pragma unroll
    for (int t = 0; t < 2; ++t){
      int ci = (t * 4 + wave) * 64 + lane;
      int r  = ci >> 2;
      int ko = (ci & 3) * 8;
      int gr = row0 + r; if (gr >= M) gr = M - 1;
      __builtin_amdgcn_global_load_lds((gu32*)(A + (size_t)gr * Kp + k0 + ko),
                                       (lu32*)(&As[(t * 4 + wave) * 512]), 16, 0, 0);
      __builtin_amdgcn_global_load_lds((gu32*)(BT + (size_t)(col0 + r) * Kp + k0 + ko),
                                       (lu32*)(&Bs[(t * 4 + wave) * 512]), 16, 0, 0);
    }
    __syncthreads();

    bf16x8 af[4], bfr[4];
#pragma unroll
    for (int i = 0; i < 4; ++i)
      af[i] = *(bf16x8*)(&As[(wr + i * 16 + l15) * BK + quad * 8]);
#pragma unroll
    for (int j = 0; j < 4; ++j)
      bfr[j] = *(bf16x8*)(&Bs[(wc + j * 16 + l15) * BK + quad * 8]);
#pragma unroll
    for (int i = 0; i < 4; ++i)
#pragma unroll
      for (int j = 0; j < 4; ++j)
        acc[i][j] = __builtin_amdgcn_mfma_f32_16x16x32_bf16(af[i], bfr[j], acc[i][j], 0, 0, 0);
    __syncthreads();
  }

  // epilogue: C/D layout col=lane&15, row=quad*4+reg
#pragma unroll
  for (int i = 0; i < 4; ++i){
#pragma unroll
    for (int j = 0; j < 4; ++j){
      int gc = col0 + wc + j * 16 + l15;
#pragma unroll
      for (int r = 0; r < 4; ++r){
        int gr = row0 + wr + i * 16 + quad * 4 + r;
        if (gr < M && gc < N) C[(size_t)gr * N + gc] = f2b(acc[i][j][r]);
      }
    }
  }
}

// ---------------------------------------------------------------- CSR build (in-edges, real edges only)
__global__ __launch_bounds__(256) void count_deg(const int* __restrict__ edst, int* __restrict__ degi){
  int e = blockIdx.x * 256 + threadIdx.x;
  if (e >= N_EDGES) return;
  atomicAdd(&degi[clampi(edst[e], N_NODES)], 1);
}

__global__ __launch_bounds__(1024) void scan_rowp(const int* __restrict__ degi,
                                                  int* __restrict__ rowp,
                                                  int* __restrict__ curs,
                                                  float* __restrict__ dinv){
  __shared__ int wsum[16];
  __shared__ int carry_s;
  const int tid = threadIdx.x, lane = tid & 63, wv = tid >> 6;
  if (tid == 0) carry_s = 0;
  __syncthreads();
  for (int base = 0; base < N_NODES; base += 1024){
    int i = base + tid;
    int v = (i < N_NODES) ? degi[i] : 0;
    int incl = v;
#pragma unroll
    for (int ofs = 1; ofs < 64; ofs <<= 1){
      int t = __shfl_up(incl, ofs);
      if (lane >= ofs) incl += t;
    }
    if (lane == 63) wsum[wv] = incl;
    __syncthreads();
    int woff = 0;
    for (int w = 0; w < 16; ++w) if (w < wv) woff += wsum[w];
    int carry = carry_s;
    if (i < N_NODES){
      int excl = carry + woff + incl - v;
      rowp[i] = excl; curs[i] = excl;
      dinv[i] = rsqrtf((float)(v + 1));
    }
    __syncthreads();
    if (tid == 1023) carry_s = carry + woff + incl;
    __syncthreads();
  }
  if (tid == 0) rowp[N_NODES] = carry_s;
}

__global__ __launch_bounds__(256) void bucket_edges(const int* __restrict__ edst,
                                                    int* __restrict__ curs,
                                                    int* __restrict__ eidx){
  int e = blockIdx.x * 256 + threadIdx.x;
  if (e >= N_EDGES) return;
  int d = clampi(edst[e], N_NODES);
  int pos = atomicAdd(&curs[d], 1);
  eidx[pos] = e;
}

// ---------------------------------------------------------------- MFMA logits
// LOG[e][h16] = att_h · leaky(xl[src_e] + xr[dst_e]); one wave per 16 edges.
__global__ __launch_bounds__(256) void logits_mfma(const bf16* __restrict__ xl,
                                                   const bf16* __restrict__ xr,
                                                   const int* __restrict__ esrc,
                                                   const int* __restrict__ edst,
                                                   const bf16* __restrict__ attP,
                                                   float* __restrict__ LOG){
  int wid  = (blockIdx.x * 256 + threadIdx.x) >> 6;
  int lane = threadIdx.x & 63;
  if (wid >= N_TILES) return;
  const int l15 = lane & 15, quad = lane >> 4;
  int e = wid * 16 + l15; if (e >= E_TOT) e = E_TOT - 1;
  int s, d;
  if (e < N_EDGES){ s = clampi(esrc[e], N_NODES); d = clampi(edst[e], N_NODES); }
  else            { s = d = e - N_EDGES; }
  const bf16* ps = xl + (size_t)s * HID + quad * 8;
  const bf16* pd = xr + (size_t)d * HID + quad * 8;

  f32x4 acc = (f32x4){0.f, 0.f, 0.f, 0.f};
  for (int k0 = 0; k0 < HID; k0 += 32){
    bf16x8 va = *(const bf16x8*)(ps + k0);
    bf16x8 vb = *(const bf16x8*)(pd + k0);
    bf16x8 t;
#pragma unroll
    for (int j = 0; j < 8; ++j){
      float v = bf2f_bits(va[j]) + bf2f_bits(vb[j]);
      v = fmaxf(v, 0.f) + NEG_SLOPE * fminf(v, 0.f);   // leaky relu
      t[j] = f2bf_bits(v);
    }
    bf16x8 wb = *(const bf16x8*)(attP + (k0 >> 5) * 512 + lane * 8);
    acc = __builtin_amdgcn_mfma_f32_16x16x32_bf16(t, wb, acc, 0, 0, 0);
  }
  // C layout: row(edge)=quad*4+r, col(head)=l15
  int er = wid * 16 + quad * 4;
#pragma unroll
  for (int r = 0; r < 4; ++r){
    int ee = er + r;
    if (ee < E_TOT) LOG[(size_t)ee * 16 + l15] = acc[r];
  }
}

// ---------------------------------------------------------------- GAT1 aggregation (10 heads x 64)
__global__ __launch_bounds__(256) void gat1_agg(const bf16* __restrict__ xl,
                                                const int* __restrict__ esrc,
                                                const int* __restrict__ rowp,
                                                const int* __restrict__ eidx,
                                                const float* __restrict__ LOG,
                                                const float* __restrict__ bias,
                                                bf16* __restrict__ H){
  int n    = (blockIdx.x * 256 + threadIdx.x) >> 6;
  int lane = threadIdx.x & 63;
  if (n >= N_NODES) return;
  const int l15 = lane & 15;
  int r0 = rowp[n], r1 = rowp[n + 1];

  // pass 1: exact max per head (lane tracks head l15; lanes 16-63 redundant)
  float lself = LOG[(size_t)(N_EDGES + n) * 16 + l15];
  float m = lself;
  for (int e = r0; e < r1; ++e)
    m = fmaxf(m, LOG[(size_t)eidx[e] * 16 + l15]);

  // pass 2: unnormalized accumulate + den
  float p0  = __expf(lself - m);
  float den = p0;
  float acc[HEADS];
  const bf16* xn = xl + (size_t)n * HID;
#pragma unroll
  for (int h = 0; h < HEADS; ++h)
    acc[h] = __shfl(p0, h) * b2f(xn[h * 64 + lane]);
  for (int e = r0; e < r1; ++e){
    int eid = eidx[e];
    int s = clampi(esrc[eid], N_NODES);
    float p = __expf(LOG[(size_t)eid * 16 + l15] - m);
    den += p;
    const bf16* xs = xl + (size_t)s * HID;
#pragma unroll
    for (int h = 0; h < HEADS; ++h)
      acc[h] += __shfl(p, h) * b2f(xs[h * 64 + lane]);
  }
#pragma unroll
  for (int h = 0; h < HEADS; ++h){
    float dh = __shfl(den, h);
    int c = h * 64 + lane;
    float v = acc[h] / dh + bias[c];
    v = v > 0.f ? v : (__expf(v) - 1.f);             // ELU
    H[(size_t)n * HID + c] = f2b(v);
  }
}

// ---------------------------------------------------------------- GAT2 aggregation (1 head x 640)
__global__ __launch_bounds__(256) void gat2_agg(const bf16* __restrict__ xl,
                                                const int* __restrict__ esrc,
                                                const int* __restrict__ rowp,
                                                const int* __restrict__ eidx,
                                                const float* __restrict__ LOG,
                                                const float* __restrict__ bias,
                                                bf16* __restrict__ H){
  int n    = (blockIdx.x * 256 + threadIdx.x) >> 6;
  int lane = threadIdx.x & 63;
  if (n >= N_NODES) return;
  int r0 = rowp[n], r1 = rowp[n + 1];

  float lself = LOG[(size_t)(N_EDGES + n) * 16];
  float m = lself;
  for (int e = r0; e < r1; ++e)
    m = fmaxf(m, LOG[(size_t)eidx[e] * 16]);

  float p0  = __expf(lself - m);
  float den = p0;
  float acc[HEADS];
  const bf16* xn = xl + (size_t)n * HID;
#pragma unroll
  for (int j = 0; j < HEADS; ++j)
    acc[j] = p0 * b2f(xn[j * 64 + lane]);
  for (int e = r0; e < r1; ++e){
    int eid = eidx[e];
    int s = clampi(esrc[eid], N_NODES);
    float p = __expf(LOG[(size_t)eid * 16] - m);
    den += p;
    const bf16* xs = xl + (size_t)s * HID;
#pragma unroll
    for (int j = 0; j < HEADS; ++j)
      acc[j] += p * b2f(xs[j * 64 + lane]);
  }
  float inv = 1.f / den;
#pragma unroll
  for (int j = 0; j < HEADS; ++j){
    int c = j * 64 + lane;
    H[(size_t)n * HID + c] = f2b(acc[j] * inv + bias[c]);
  }
}

// ---------------------------------------------------------------- GCN gather: bias+ReLU -> bf16 h3
__global__ __launch_bounds__(256) void gcn_gather(const bf16* __restrict__ xw,
                                                  const int* __restrict__ esrc,
                                                  const int* __restrict__ rowp,
                                                  const int* __restrict__ eidx,
                                                  const float* __restrict__ dinv,
                                                  const float* __restrict__ bg,
                                                  bf16* __restrict__ h3){
  int n    = (blockIdx.x * 256 + threadIdx.x) >> 6;
  int lane = threadIdx.x & 63;
  if (n >= N_NODES) return;
  int r0 = rowp[n], r1 = rowp[n + 1];

  float dn = dinv[n];
  float acc[HEADS];
  {
    float w = dn * dn;
    const bf16* xn = xw + (size_t)n * HID;
#pragma unroll
    for (int j = 0; j < HEADS; ++j) acc[j] = w * b2f(xn[j * 64 + lane]);
  }
  for (int e = r0; e < r1; ++e){
    int s = clampi(esrc[eidx[e]], N_NODES);
    float w = dinv[s] * dn;
    const bf16* xs = xw + (size_t)s * HID;
#pragma unroll
    for (int j = 0; j < HEADS; ++j) acc[j] += w * b2f(xs[j * 64 + lane]);
  }
#pragma unroll
  for (int j = 0; j < HEADS; ++j){
    int c = j * 64 + lane;
    h3[(size_t)n * HID + c] = f2b(fmaxf(acc[j] + bg[c], 0.f));
  }
}

// ---------------------------------------------------------------- per-graph pooling (batch is sorted)
__global__ __launch_bounds__(256) void graph_bounds(const int* __restrict__ batch,
                                                    int* __restrict__ gstart){
  int n = blockIdx.x * 256 + threadIdx.x;
  if (n >= N_NODES) return;
  int b = clampi(batch[n], N_GRAPHS);
  if (n == 0){
    for (int g = 0; g <= b; ++g) gstart[g] = 0;
  } else {
    int bp = clampi(batch[n - 1], N_GRAPHS);
    for (int g = bp + 1; g <= b; ++g) gstart[g] = n;
  }
  if (n == N_NODES - 1){
    for (int g = b + 1; g <= N_GRAPHS; ++g) gstart[g] = N_NODES;
  }
}

__global__ __launch_bounds__(640) void pool_graph(const bf16* __restrict__ h3,
                                                  const int* __restrict__ gstart,
                                                  float* __restrict__ out){
  int g = blockIdx.x;
  int c = threadIdx.x;
  int n0 = gstart[g], n1 = gstart[g + 1];
  float mx = 0.f, sm = 0.f;     // h3 >= 0 post-ReLU
  for (int n = n0; n < n1; ++n){
    float v = b2f(h3[(size_t)n * HID + c]);
    mx = fmaxf(mx, v); sm += v;
  }
  float mean = (n1 > n0) ? sm / (float)(n1 - n0) : 0.f;
  out[(size_t)g * 2 * HID + c]       = mx;
  out[(size_t)g * 2 * HID + HID + c] = mean;
}

// ---------------------------------------------------------------- launch
extern "C" void kernel_launch(void* const* d_in, const int* in_sizes, int n_in,
                              void* d_out, int out_size, void* d_ws, size_t ws_size,
                              hipStream_t stream){
  const float* x     = (const float*)d_in[0];
  const int*   ei    = (const int*)d_in[1];
  const int*   batch = (const int*)d_in[2];
  const float* Wl1 = (const float*)d_in[3];
  const float* Wr1 = (const float*)d_in[4];
  const float* a1  = (const float*)d_in[5];
  const float* b1  = (const float*)d_in[6];
  const float* Wl2 = (const float*)d_in[7];
  const float* Wr2 = (const float*)d_in[8];
  const float* a2  = (const float*)d_in[9];
  const float* b2  = (const float*)d_in[10];
  const float* Wg  = (const float*)d_in[11];
  const float* bg  = (const float*)d_in[12];
  const int* esrc = ei;
  const int* edst = ei + N_EDGES;

  // ---- workspace layout (~218 MB total) ----
  char* ws = (char*)d_ws;
  size_t off = 0;
  auto take = [&](size_t bytes)->char*{
    char* p = ws + off; off = (off + bytes + 255) & ~(size_t)255; return p;
  };
  bf16*     X1   = (bf16*)    take((size_t)N_NODES * HID * 2);   // xl / xw (64 MB)
  bf16*     X2   = (bf16*)    take((size_t)N_NODES * HID * 2);   // xr / h3 (64 MB)
  bf16*     H    = (bf16*)    take((size_t)N_NODES * HID * 2);   // h1 then h2 (64 MB)
  bf16*     XB   = (bf16*)    take((size_t)N_NODES * K1P * 2);   // bf16 x, K-padded (9.6 MB)
  bf16*     WT1l = (bf16*)    take((size_t)HID * K1P * 2);
  bf16*     WT1r = (bf16*)    take((size_t)HID * K1P * 2);
  bf16*     WT2l = (bf16*)    take((size_t)HID * HID * 2);
  bf16*     WT2r = (bf16*)    take((size_t)HID * HID * 2);
  bf16*     WTg  = (bf16*)    take((size_t)HID * HID * 2);
  bf16*     AT1P = (bf16*)    take((size_t)(HID / 32) * 512 * 2);
  bf16*     AT2P = (bf16*)    take((size_t)(HID / 32) * 512 * 2);
  float*    LOG  = (float*)   take((size_t)E_TOT * 16 * 4);      // 12.8 MB
  int*      DEGI = (int*)     take((size_t)N_NODES * 4);
  int*      ROWP = (int*)     take((size_t)(N_NODES + 1) * 4);
  int*      CURS = (int*)     take((size_t)N_NODES * 4);
  int*      EIDX = (int*)     take((size_t)N_EDGES * 4);
  float*    DINV = (float*)   take((size_t)N_NODES * 4);
  int*      GST  = (int*)     take((size_t)(N_GRAPHS + 1) * 4);

  dim3 blk(256);
  auto fill = [&](void* p, unsigned v, int n){
    fill_u32<<<dim3((n + 255) / 256), blk, 0, stream>>>((unsigned*)p, v, n);
  };
  dim3 ggrid(HID / BN, (N_NODES + BM - 1) / BM);       // (5, 391)
  const int nblocks = (N_NODES * 64 + 255) / 256;      // wave-per-node kernels
  const int lblocks = (N_TILES * 64 + 255) / 256;      // wave-per-16-edges logits
  const int reblk   = (N_EDGES + 255) / 256;
  const int apn     = (HID / 32) * 512;

  // ---- prep + CSR ----
  conv_x<<<(N_NODES * K1P + 255) / 256, blk, 0, stream>>>(x, XB);
  conv_wT<<<(HID * K1P + 255) / 256, blk, 0, stream>>>(Wl1, WT1l, IN_DIM, HID, K1P);
  conv_wT<<<(HID * K1P + 255) / 256, blk, 0, stream>>>(Wr1, WT1r, IN_DIM, HID, K1P);
  conv_wT<<<(HID * HID + 255) / 256, blk, 0, stream>>>(Wl2, WT2l, HID, HID, HID);
  conv_wT<<<(HID * HID + 255) / 256, blk, 0, stream>>>(Wr2, WT2r, HID, HID, HID);
  conv_wT<<<(HID * HID + 255) / 256, blk, 0, stream>>>(Wg,  WTg,  HID, HID, HID);
  conv_attP<<<(apn + 255) / 256, blk, 0, stream>>>(a1, AT1P, HEADS);
  conv_attP<<<(apn + 255) / 256, blk, 0, stream>>>(a2, AT2P, 1);
  fill(DEGI, 0u, N_NODES);
  count_deg<<<reblk, blk, 0, stream>>>(edst, DEGI);
  scan_rowp<<<1, 1024, 0, stream>>>(DEGI, ROWP, CURS, DINV);
  bucket_edges<<<reblk, blk, 0, stream>>>(edst, CURS, EIDX);
  graph_bounds<<<(N_NODES + 255) / 256, blk, 0, stream>>>(batch, GST);

  // ---- GATv2 layer 1 ----
  mfma_gemm<<<ggrid, blk, 0, stream>>>(XB, WT1l, X1, N_NODES, K1P, HID);
  mfma_gemm<<<ggrid, blk, 0, stream>>>(XB, WT1r, X2, N_NODES, K1P, HID);
  logits_mfma<<<lblocks, blk, 0, stream>>>(X1, X2, esrc, edst, AT1P, LOG);
  gat1_agg<<<nblocks, blk, 0, stream>>>(X1, esrc, ROWP, EIDX, LOG, b1, H);

  // ---- GATv2 layer 2 ----
  mfma_gemm<<<ggrid, blk, 0, stream>>>(H, WT2l, X1, N_NODES, HID, HID);
  mfma_gemm<<<ggrid, blk, 0, stream>>>(H, WT2r, X2, N_NODES, HID, HID);
  logits_mfma<<<lblocks, blk, 0, stream>>>(X1, X2, esrc, edst, AT2P, LOG);
  gat2_agg<<<nblocks, blk, 0, stream>>>(X1, esrc, ROWP, EIDX, LOG, b2, H);

  // ---- GCN + pooling ----
  mfma_gemm<<<ggrid, blk, 0, stream>>>(H, WTg, X1, N_NODES, HID, HID);
  gcn_gather<<<nblocks, blk, 0, stream>>>(X1, esrc, ROWP, EIDX, DINV, bg, X2);
  pool_graph<<<dim3(N_GRAPHS), dim3(640), 0, stream>>>(X2, GST, (float*)d_out);
}

// Round 8
// 759.680 us; speedup vs baseline: 6.3093x; 1.0841x over previous
//
#include <hip/hip_runtime.h>
#include <hip/hip_bf16.h>
#include <cstdint>
#include <cstddef>

typedef __hip_bfloat16 bf16;

#define N_NODES  50000
#define N_EDGES  150000
#define E_TOT    (N_EDGES + N_NODES)   /* CSR positions: edges (dst-sorted), then self-loops */
#define N_TILES  ((E_TOT + 15) / 16)
#define N_GRAPHS 1024
#define IN_DIM   78
#define K1P      96
#define OUT_DIM  64
#define HEADS    10
#define HID      640
#define NEG_SLOPE 0.2f

static __device__ __forceinline__ float b2f(bf16 v){ return __bfloat162float(v); }
static __device__ __forceinline__ bf16  f2b(float v){ return __float2bfloat16(v); }

__device__ __forceinline__ int clampi(int v, int hi){ return v < 0 ? 0 : (v >= hi ? hi - 1 : v); }

__device__ __forceinline__ float bf2f_bits(short s){
  return __uint_as_float(((unsigned)(unsigned short)s) << 16);
}
__device__ __forceinline__ short f2bf_bits(float v){
  unsigned u = __float_as_uint(v);
  return (short)((u + 0x7fffu + ((u >> 16) & 1u)) >> 16);   // RNE
}

// ---------------------------------------------------------------- fills
__global__ __launch_bounds__(256) void fill_u32(unsigned* __restrict__ p, unsigned v, int n){
  int i = blockIdx.x * 256 + threadIdx.x;
  if (i < n) p[i] = v;
}

// ---------------------------------------------------------------- dtype prep
__global__ __launch_bounds__(256) void conv_x(const float* __restrict__ x, bf16* __restrict__ XB){
  int i = blockIdx.x * 256 + threadIdx.x;
  if (i >= N_NODES * K1P) return;
  int n = i / K1P, k = i - n * K1P;
  XB[i] = f2b(k < IN_DIM ? x[(size_t)n * IN_DIM + k] : 0.f);
}

__global__ __launch_bounds__(256) void conv_wT(const float* __restrict__ W, bf16* __restrict__ WT,
                                               int K, int N, int Kp){
  int i = blockIdx.x * 256 + threadIdx.x;
  if (i >= N * Kp) return;
  int n = i / Kp, k = i - n * Kp;
  WT[i] = f2b(k < K ? W[(size_t)k * N + n] : 0.f);
}

// att -> B-fragment-ordered matrix for 16x16x32 MFMA (see round 7)
__global__ __launch_bounds__(256) void conv_attP(const float* __restrict__ a, bf16* __restrict__ P,
                                                 int heads){
  int i = blockIdx.x * 256 + threadIdx.x;
  if (i >= (HID / 32) * 512) return;
  int chunk = i >> 9;
  int lane  = (i >> 3) & 63;
  int j     = i & 7;
  int h = lane & 15;
  int k = (lane >> 4) * 8 + j;
  int c = chunk * 32 + k;
  float v = 0.f;
  if (heads == HEADS){ if (h < HEADS && (c >> 6) == h) v = a[c]; }
  else               { if (h == 0) v = a[c]; }
  P[i] = f2b(v);
}

// ---------------------------------------------------------------- MFMA GEMM (global_load_lds + XOR swizzle)
#define BM 128
#define BN 128
#define BK 32

typedef __attribute__((ext_vector_type(8))) short bf16x8;
typedef __attribute__((ext_vector_type(4))) float f32x4;

typedef const __attribute__((address_space(1))) unsigned gu32;
typedef __attribute__((address_space(3))) unsigned lu32;

__global__ __launch_bounds__(256) void mfma_gemm(const bf16* __restrict__ A,
                                                 const bf16* __restrict__ BT,
                                                 bf16* __restrict__ C,
                                                 int M, int Kp, int N){
  __shared__ short As[BM * BK];   // slot (r, c) holds k-chunk c ^ ((r>>1)&3)  -> 2-way banks (free)
  __shared__ short Bs[BN * BK];
  const int tid  = threadIdx.x;
  const int lane = tid & 63;
  const int wave = tid >> 6;
  const int wr   = (wave >> 1) * 64;
  const int wc   = (wave & 1) * 64;
  const int l15  = lane & 15;
  const int quad = lane >> 4;
  const int row0 = blockIdx.y * BM;
  const int col0 = blockIdx.x * BN;
  const int swA  = ((wr + l15) >> 1) & 3;
  const int swB  = ((wc + l15) >> 1) & 3;

  f32x4 acc[4][4];
#pragma unroll
  for (int i = 0; i < 4; ++i)
#pragma unroll
    for (int j = 0; j < 4; ++j) acc[i][j] = (f32x4){0.f, 0.f, 0.f, 0.f};

  for (int k0 = 0; k0 < Kp; k0 += BK){
#pragma unroll
    for (int t = 0; t < 2; ++t){
      int ci = (t * 4 + wave) * 64 + lane;
      int r  = ci >> 2;
      int ko = ((ci & 3) ^ ((r >> 1) & 3)) * 8;       // swizzled source k-chunk
      int gr = row0 + r; if (gr >= M) gr = M - 1;
      __builtin_amdgcn_global_load_lds((gu32*)(A + (size_t)gr * Kp + k0 + ko),
                                       (lu32*)(&As[(t * 4 + wave) * 512]), 16, 0, 0);
      __builtin_amdgcn_global_load_lds((gu32*)(BT + (size_t)(col0 + r) * Kp + k0 + ko),
                                       (lu32*)(&Bs[(t * 4 + wave) * 512]), 16, 0, 0);
    }
    __syncthreads();

    bf16x8 af[4], bfr[4];
#pragma unroll
    for (int i = 0; i < 4; ++i)
      af[i] = *(bf16x8*)(&As[(wr + i * 16 + l15) * BK + ((quad ^ swA) * 8)]);
#pragma unroll
    for (int j = 0; j < 4; ++j)
      bfr[j] = *(bf16x8*)(&Bs[(wc + j * 16 + l15) * BK + ((quad ^ swB) * 8)]);
#pragma unroll
    for (int i = 0; i < 4; ++i)
#pragma unroll
      for (int j = 0; j < 4; ++j)
        acc[i][j] = __builtin_amdgcn_mfma_f32_16x16x32_bf16(af[i], bfr[j], acc[i][j], 0, 0, 0);
    __syncthreads();
  }

#pragma unroll
  for (int i = 0; i < 4; ++i){
#pragma unroll
    for (int j = 0; j < 4; ++j){
      int gc = col0 + wc + j * 16 + l15;
#pragma unroll
      for (int r = 0; r < 4; ++r){
        int gr = row0 + wr + i * 16 + quad * 4 + r;
        if (gr < M && gc < N) C[(size_t)gr * N + gc] = f2b(acc[i][j][r]);
      }
    }
  }
}

// ---------------------------------------------------------------- CSR build
__global__ __launch_bounds__(256) void count_deg(const int* __restrict__ edst, int* __restrict__ degi){
  int e = blockIdx.x * 256 + threadIdx.x;
  if (e >= N_EDGES) return;
  atomicAdd(&degi[clampi(edst[e], N_NODES)], 1);
}

__global__ __launch_bounds__(1024) void scan_rowp(const int* __restrict__ degi,
                                                  int* __restrict__ rowp,
                                                  int* __restrict__ curs,
                                                  float* __restrict__ dinv){
  __shared__ int wsum[16];
  __shared__ int carry_s;
  const int tid = threadIdx.x, lane = tid & 63, wv = tid >> 6;
  if (tid == 0) carry_s = 0;
  __syncthreads();
  for (int base = 0; base < N_NODES; base += 1024){
    int i = base + tid;
    int v = (i < N_NODES) ? degi[i] : 0;
    int incl = v;
#pragma unroll
    for (int ofs = 1; ofs < 64; ofs <<= 1){
      int t = __shfl_up(incl, ofs);
      if (lane >= ofs) incl += t;
    }
    if (lane == 63) wsum[wv] = incl;
    __syncthreads();
    int woff = 0;
    for (int w = 0; w < 16; ++w) if (w < wv) woff += wsum[w];
    int carry = carry_s;
    if (i < N_NODES){
      int excl = carry + woff + incl - v;
      rowp[i] = excl; curs[i] = excl;
      dinv[i] = rsqrtf((float)(v + 1));
    }
    __syncthreads();
    if (tid == 1023) carry_s = carry + woff + incl;
    __syncthreads();
  }
  if (tid == 0) rowp[N_NODES] = carry_s;
}

// scatter src/dst into CSR slots (removes eidx indirection downstream)
__global__ __launch_bounds__(256) void bucket_edges(const int* __restrict__ esrc,
                                                    const int* __restrict__ edst,
                                                    int* __restrict__ curs,
                                                    int* __restrict__ srcg,
                                                    int* __restrict__ dstg){
  int e = blockIdx.x * 256 + threadIdx.x;
  if (e >= N_EDGES) return;
  int d = clampi(edst[e], N_NODES);
  int pos = atomicAdd(&curs[d], 1);
  srcg[pos] = clampi(esrc[e], N_NODES);
  dstg[pos] = d;
}

// ---------------------------------------------------------------- MFMA logits (CSR order)
// LOG[p][h16] = att_h · leaky(xl[src_p] + xr[dst_p]); positions sorted by dst -> xr reuse.
__global__ __launch_bounds__(256) void logits_mfma(const bf16* __restrict__ xl,
                                                   const bf16* __restrict__ xr,
                                                   const int* __restrict__ srcg,
                                                   const int* __restrict__ dstg,
                                                   const bf16* __restrict__ attP,
                                                   float* __restrict__ LOG){
  int wid  = (blockIdx.x * 256 + threadIdx.x) >> 6;
  int lane = threadIdx.x & 63;
  if (wid >= N_TILES) return;
  const int l15 = lane & 15, quad = lane >> 4;
  int p = wid * 16 + l15; if (p >= E_TOT) p = E_TOT - 1;
  int s, d;
  if (p < N_EDGES){ s = srcg[p]; d = dstg[p]; }
  else            { s = d = p - N_EDGES; }
  const bf16* ps = xl + (size_t)s * HID + quad * 8;
  const bf16* pd = xr + (size_t)d * HID + quad * 8;

  f32x4 acc = (f32x4){0.f, 0.f, 0.f, 0.f};
  for (int k0 = 0; k0 < HID; k0 += 32){
    bf16x8 va = *(const bf16x8*)(ps + k0);
    bf16x8 vb = *(const bf16x8*)(pd + k0);
    bf16x8 t;
#pragma unroll
    for (int j = 0; j < 8; ++j){
      float v = bf2f_bits(va[j]) + bf2f_bits(vb[j]);
      v = fmaxf(v, 0.f) + NEG_SLOPE * fminf(v, 0.f);
      t[j] = f2bf_bits(v);
    }
    bf16x8 wb = *(const bf16x8*)(attP + (k0 >> 5) * 512 + lane * 8);
    acc = __builtin_amdgcn_mfma_f32_16x16x32_bf16(t, wb, acc, 0, 0, 0);
  }
  int er = wid * 16 + quad * 4;
#pragma unroll
  for (int r = 0; r < 4; ++r){
    int ee = er + r;
    if (ee < E_TOT) LOG[(size_t)ee * 16 + l15] = acc[r];
  }
}

// ---------------------------------------------------------------- GAT1 aggregation
// lane l owns ch [8l,8l+8) (head l>>3) and ch {512+2l,513+2l} (head 8+(l>>5)).
__global__ __launch_bounds__(256) void gat1_agg(const bf16* __restrict__ xl,
                                                const int* __restrict__ srcg,
                                                const int* __restrict__ rowp,
                                                const float* __restrict__ LOG,
                                                const float* __restrict__ bias,
                                                bf16* __restrict__ H){
  int n    = (blockIdx.x * 256 + threadIdx.x) >> 6;
  int lane = threadIdx.x & 63;
  if (n >= N_NODES) return;
  const int l15 = lane & 15;
  const int hA = lane >> 3;           // 0..7
  const int hB = 8 + (lane >> 5);     // 8..9
  int r0 = rowp[n], r1 = rowp[n + 1];

  // pass 1: exact per-head max (lanes 0..15 track head l15)
  float lself = LOG[(size_t)(N_EDGES + n) * 16 + l15];
  float m = lself;
  for (int p = r0; p < r1; ++p) m = fmaxf(m, LOG[(size_t)p * 16 + l15]);

  float p0  = __expf(lself - m);
  float den = p0;
  float accA[8], accB[2];
  {
    float pA = __shfl(p0, hA), pB = __shfl(p0, hB);
    const bf16* xn = xl + (size_t)n * HID;
    bf16x8 va = *(const bf16x8*)(xn + 8 * lane);
    unsigned vb = *(const unsigned*)(xn + 512 + 2 * lane);
#pragma unroll
    for (int j = 0; j < 8; ++j) accA[j] = pA * bf2f_bits(va[j]);
    accB[0] = pB * bf2f_bits((short)(vb & 0xffff));
    accB[1] = pB * bf2f_bits((short)(vb >> 16));
  }
  for (int p = r0; p < r1; ++p){
    int s = srcg[p];
    float pv = __expf(LOG[(size_t)p * 16 + l15] - m);
    den += pv;
    float pA = __shfl(pv, hA), pB = __shfl(pv, hB);
    const bf16* xs = xl + (size_t)s * HID;
    bf16x8 va = *(const bf16x8*)(xs + 8 * lane);
    unsigned vb = *(const unsigned*)(xs + 512 + 2 * lane);
#pragma unroll
    for (int j = 0; j < 8; ++j) accA[j] += pA * bf2f_bits(va[j]);
    accB[0] += pB * bf2f_bits((short)(vb & 0xffff));
    accB[1] += pB * bf2f_bits((short)(vb >> 16));
  }
  float dA = __shfl(den, hA), dB = __shfl(den, hB);
  float4 bA0 = *(const float4*)(bias + 8 * lane);
  float4 bA1 = *(const float4*)(bias + 8 * lane + 4);
  float2 bB  = *(const float2*)(bias + 512 + 2 * lane);
  bf16x8 oA;
  float bAa[8] = {bA0.x, bA0.y, bA0.z, bA0.w, bA1.x, bA1.y, bA1.z, bA1.w};
#pragma unroll
  for (int j = 0; j < 8; ++j){
    float v = accA[j] / dA + bAa[j];
    v = v > 0.f ? v : (__expf(v) - 1.f);              // ELU
    oA[j] = f2bf_bits(v);
  }
  float v0 = accB[0] / dB + bB.x; v0 = v0 > 0.f ? v0 : (__expf(v0) - 1.f);
  float v1 = accB[1] / dB + bB.y; v1 = v1 > 0.f ? v1 : (__expf(v1) - 1.f);
  bf16* hn = H + (size_t)n * HID;
  *(bf16x8*)(hn + 8 * lane) = oA;
  unsigned ob = (unsigned)(unsigned short)f2bf_bits(v0) |
                ((unsigned)(unsigned short)f2bf_bits(v1) << 16);
  *(unsigned*)(hn + 512 + 2 * lane) = ob;
}

// ---------------------------------------------------------------- GAT2 aggregation (1 head)
__global__ __launch_bounds__(256) void gat2_agg(const bf16* __restrict__ xl,
                                                const int* __restrict__ srcg,
                                                const int* __restrict__ rowp,
                                                const float* __restrict__ LOG,
                                                const float* __restrict__ bias,
                                                bf16* __restrict__ H){
  int n    = (blockIdx.x * 256 + threadIdx.x) >> 6;
  int lane = threadIdx.x & 63;
  if (n >= N_NODES) return;
  int r0 = rowp[n], r1 = rowp[n + 1];

  float lself = LOG[(size_t)(N_EDGES + n) * 16];
  float m = lself;
  for (int p = r0; p < r1; ++p) m = fmaxf(m, LOG[(size_t)p * 16]);

  float p0  = __expf(lself - m);
  float den = p0;
  float accA[8], accB[2];
  {
    const bf16* xn = xl + (size_t)n * HID;
    bf16x8 va = *(const bf16x8*)(xn + 8 * lane);
    unsigned vb = *(const unsigned*)(xn + 512 + 2 * lane);
#pragma unroll
    for (int j = 0; j < 8; ++j) accA[j] = p0 * bf2f_bits(va[j]);
    accB[0] = p0 * bf2f_bits((short)(vb & 0xffff));
    accB[1] = p0 * bf2f_bits((short)(vb >> 16));
  }
  for (int p = r0; p < r1; ++p){
    int s = srcg[p];
    float pv = __expf(LOG[(size_t)p * 16] - m);
    den += pv;
    const bf16* xs = xl + (size_t)s * HID;
    bf16x8 va = *(const bf16x8*)(xs + 8 * lane);
    unsigned vb = *(const unsigned*)(xs + 512 + 2 * lane);
#pragma unroll
    for (int j = 0; j < 8; ++j) accA[j] += pv * bf2f_bits(va[j]);
    accB[0] += pv * bf2f_bits((short)(vb & 0xffff));
    accB[1] += pv * bf2f_bits((short)(vb >> 16));
  }
  float inv = 1.f / den;
  float4 bA0 = *(const float4*)(bias + 8 * lane);
  float4 bA1 = *(const float4*)(bias + 8 * lane + 4);
  float2 bB  = *(const float2*)(bias + 512 + 2 * lane);
  float bAa[8] = {bA0.x, bA0.y, bA0.z, bA0.w, bA1.x, bA1.y, bA1.z, bA1.w};
  bf16x8 oA;
#pragma unroll
  for (int j = 0; j < 8; ++j) oA[j] = f2bf_bits(accA[j] * inv + bAa[j]);
  bf16* hn = H + (size_t)n * HID;
  *(bf16x8*)(hn + 8 * lane) = oA;
  unsigned ob = (unsigned)(unsigned short)f2bf_bits(accB[0] * inv + bB.x) |
                ((unsigned)(unsigned short)f2bf_bits(accB[1] * inv + bB.y) << 16);
  *(unsigned*)(hn + 512 + 2 * lane) = ob;
}

// ---------------------------------------------------------------- GCN gather: bias+ReLU -> bf16 h3
__global__ __launch_bounds__(256) void gcn_gather(const bf16* __restrict__ xw,
                                                  const int* __restrict__ srcg,
                                                  const int* __restrict__ rowp,
                                                  const float* __restrict__ dinv,
                                                  const float* __restrict__ bg,
                                                  bf16* __restrict__ h3){
  int n    = (blockIdx.x * 256 + threadIdx.x) >> 6;
  int lane = threadIdx.x & 63;
  if (n >= N_NODES) return;
  int r0 = rowp[n], r1 = rowp[n + 1];

  float dn = dinv[n];
  float accA[8], accB[2];
  {
    float w = dn * dn;
    const bf16* xn = xw + (size_t)n * HID;
    bf16x8 va = *(const bf16x8*)(xn + 8 * lane);
    unsigned vb = *(const unsigned*)(xn + 512 + 2 * lane);
#pragma unroll
    for (int j = 0; j < 8; ++j) accA[j] = w * bf2f_bits(va[j]);
    accB[0] = w * bf2f_bits((short)(vb & 0xffff));
    accB[1] = w * bf2f_bits((short)(vb >> 16));
  }
  for (int p = r0; p < r1; ++p){
    int s = srcg[p];
    float w = dinv[s] * dn;
    const bf16* xs = xw + (size_t)s * HID;
    bf16x8 va = *(const bf16x8*)(xs + 8 * lane);
    unsigned vb = *(const unsigned*)(xs + 512 + 2 * lane);
#pragma unroll
    for (int j = 0; j < 8; ++j) accA[j] += w * bf2f_bits(va[j]);
    accB[0] += w * bf2f_bits((short)(vb & 0xffff));
    accB[1] += w * bf2f_bits((short)(vb >> 16));
  }
  float4 bA0 = *(const float4*)(bg + 8 * lane);
  float4 bA1 = *(const float4*)(bg + 8 * lane + 4);
  float2 bB  = *(const float2*)(bg + 512 + 2 * lane);
  float bAa[8] = {bA0.x, bA0.y, bA0.z, bA0.w, bA1.x, bA1.y, bA1.z, bA1.w};
  bf16x8 oA;
#pragma unroll
  for (int j = 0; j < 8; ++j) oA[j] = f2bf_bits(fmaxf(accA[j] + bAa[j], 0.f));
  bf16* hn = h3 + (size_t)n * HID;
  *(bf16x8*)(hn + 8 * lane) = oA;
  unsigned ob = (unsigned)(unsigned short)f2bf_bits(fmaxf(accB[0] + bB.x, 0.f)) |
                ((unsigned)(unsigned short)f2bf_bits(fmaxf(accB[1] + bB.y, 0.f)) << 16);
  *(unsigned*)(hn + 512 + 2 * lane) = ob;
}

// ---------------------------------------------------------------- per-graph pooling (batch is sorted)
__global__ __launch_bounds__(256) void graph_bounds(const int* __restrict__ batch,
                                                    int* __restrict__ gstart){
  int n = blockIdx.x * 256 + threadIdx.x;
  if (n >= N_NODES) return;
  int b = clampi(batch[n], N_GRAPHS);
  if (n == 0){
    for (int g = 0; g <= b; ++g) gstart[g] = 0;
  } else {
    int bp = clampi(batch[n - 1], N_GRAPHS);
    for (int g = bp + 1; g <= b; ++g) gstart[g] = n;
  }
  if (n == N_NODES - 1){
    for (int g = b + 1; g <= N_GRAPHS; ++g) gstart[g] = N_NODES;
  }
}

__global__ __launch_bounds__(640) void pool_graph(const bf16* __restrict__ h3,
                                                  const int* __restrict__ gstart,
                                                  float* __restrict__ out){
  int g = blockIdx.x;
  int c = threadIdx.x;
  int n0 = gstart[g], n1 = gstart[g + 1];
  float mx = 0.f, sm = 0.f;     // h3 >= 0 post-ReLU
  for (int n = n0; n < n1; ++n){
    float v = b2f(h3[(size_t)n * HID + c]);
    mx = fmaxf(mx, v); sm += v;
  }
  float mean = (n1 > n0) ? sm / (float)(n1 - n0) : 0.f;
  out[(size_t)g * 2 * HID + c]       = mx;
  out[(size_t)g * 2 * HID + HID + c] = mean;
}

// ---------------------------------------------------------------- launch
extern "C" void kernel_launch(void* const* d_in, const int* in_sizes, int n_in,
                              void* d_out, int out_size, void* d_ws, size_t ws_size,
                              hipStream_t stream){
  const float* x     = (const float*)d_in[0];
  const int*   ei    = (const int*)d_in[1];
  const int*   batch = (const int*)d_in[2];
  const float* Wl1 = (const float*)d_in[3];
  const float* Wr1 = (const float*)d_in[4];
  const float* a1  = (const float*)d_in[5];
  const float* b1  = (const float*)d_in[6];
  const float* Wl2 = (const float*)d_in[7];
  const float* Wr2 = (const float*)d_in[8];
  const float* a2  = (const float*)d_in[9];
  const float* b2  = (const float*)d_in[10];
  const float* Wg  = (const float*)d_in[11];
  const float* bg  = (const float*)d_in[12];
  const int* esrc = ei;
  const int* edst = ei + N_EDGES;

  // ---- workspace layout (~219 MB) ----
  char* ws = (char*)d_ws;
  size_t off = 0;
  auto take = [&](size_t bytes)->char*{
    char* p = ws + off; off = (off + bytes + 255) & ~(size_t)255; return p;
  };
  bf16*     X1   = (bf16*)    take((size_t)N_NODES * HID * 2);
  bf16*     X2   = (bf16*)    take((size_t)N_NODES * HID * 2);
  bf16*     H    = (bf16*)    take((size_t)N_NODES * HID * 2);
  bf16*     XB   = (bf16*)    take((size_t)N_NODES * K1P * 2);
  bf16*     WT1l = (bf16*)    take((size_t)HID * K1P * 2);
  bf16*     WT1r = (bf16*)    take((size_t)HID * K1P * 2);
  bf16*     WT2l = (bf16*)    take((size_t)HID * HID * 2);
  bf16*     WT2r = (bf16*)    take((size_t)HID * HID * 2);
  bf16*     WTg  = (bf16*)    take((size_t)HID * HID * 2);
  bf16*     AT1P = (bf16*)    take((size_t)(HID / 32) * 512 * 2);
  bf16*     AT2P = (bf16*)    take((size_t)(HID / 32) * 512 * 2);
  float*    LOG  = (float*)   take((size_t)E_TOT * 16 * 4);
  int*      DEGI = (int*)     take((size_t)N_NODES * 4);
  int*      ROWP = (int*)     take((size_t)(N_NODES + 1) * 4);
  int*      CURS = (int*)     take((size_t)N_NODES * 4);
  int*      SRCG = (int*)     take((size_t)N_EDGES * 4);
  int*      DSTG = (int*)     take((size_t)N_EDGES * 4);
  float*    DINV = (float*)   take((size_t)N_NODES * 4);
  int*      GST  = (int*)     take((size_t)(N_GRAPHS + 1) * 4);

  dim3 blk(256);
  auto fill = [&](void* p, unsigned v, int n){
    fill_u32<<<dim3((n + 255) / 256), blk, 0, stream>>>((unsigned*)p, v, n);
  };
  dim3 ggrid(HID / BN, (N_NODES + BM - 1) / BM);
  const int nblocks = (N_NODES * 64 + 255) / 256;
  const int lblocks = (N_TILES * 64 + 255) / 256;
  const int reblk   = (N_EDGES + 255) / 256;
  const int apn     = (HID / 32) * 512;

  // ---- prep + CSR ----
  conv_x<<<(N_NODES * K1P + 255) / 256, blk, 0, stream>>>(x, XB);
  conv_wT<<<(HID * K1P + 255) / 256, blk, 0, stream>>>(Wl1, WT1l, IN_DIM, HID, K1P);
  conv_wT<<<(HID * K1P + 255) / 256, blk, 0, stream>>>(Wr1, WT1r, IN_DIM, HID, K1P);
  conv_wT<<<(HID * HID + 255) / 256, blk, 0, stream>>>(Wl2, WT2l, HID, HID, HID);
  conv_wT<<<(HID * HID + 255) / 256, blk, 0, stream>>>(Wr2, WT2r, HID, HID, HID);
  conv_wT<<<(HID * HID + 255) / 256, blk, 0, stream>>>(Wg,  WTg,  HID, HID, HID);
  conv_attP<<<(apn + 255) / 256, blk, 0, stream>>>(a1, AT1P, HEADS);
  conv_attP<<<(apn + 255) / 256, blk, 0, stream>>>(a2, AT2P, 1);
  fill(DEGI, 0u, N_NODES);
  count_deg<<<reblk, blk, 0, stream>>>(edst, DEGI);
  scan_rowp<<<1, 1024, 0, stream>>>(DEGI, ROWP, CURS, DINV);
  bucket_edges<<<reblk, blk, 0, stream>>>(esrc, edst, CURS, SRCG, DSTG);
  graph_bounds<<<(N_NODES + 255) / 256, blk, 0, stream>>>(batch, GST);

  // ---- GATv2 layer 1 ----
  mfma_gemm<<<ggrid, blk, 0, stream>>>(XB, WT1l, X1, N_NODES, K1P, HID);
  mfma_gemm<<<ggrid, blk, 0, stream>>>(XB, WT1r, X2, N_NODES, K1P, HID);
  logits_mfma<<<lblocks, blk, 0, stream>>>(X1, X2, SRCG, DSTG, AT1P, LOG);
  gat1_agg<<<nblocks, blk, 0, stream>>>(X1, SRCG, ROWP, LOG, b1, H);

  // ---- GATv2 layer 2 ----
  mfma_gemm<<<ggrid, blk, 0, stream>>>(H, WT2l, X1, N_NODES, HID, HID);
  mfma_gemm<<<ggrid, blk, 0, stream>>>(H, WT2r, X2, N_NODES, HID, HID);
  logits_mfma<<<lblocks, blk, 0, stream>>>(X1, X2, SRCG, DSTG, AT2P, LOG);
  gat2_agg<<<nblocks, blk, 0, stream>>>(X1, SRCG, ROWP, LOG, b2, H);

  // ---- GCN + pooling ----
  mfma_gemm<<<ggrid, blk, 0, stream>>>(H, WTg, X1, N_NODES, HID, HID);
  gcn_gather<<<nblocks, blk, 0, stream>>>(X1, SRCG, ROWP, DINV, bg, X2);
  pool_graph<<<dim3(N_GRAPHS), dim3(640), 0, stream>>>(X2, GST, (float*)d_out);
}

// Round 9
// 706.667 us; speedup vs baseline: 6.7826x; 1.0750x over previous
//
#include <hip/hip_runtime.h>
#include <hip/hip_bf16.h>
#include <cstdint>
#include <cstddef>

typedef __hip_bfloat16 bf16;

#define N_NODES  50000
#define N_EDGES  150000
#define E_TOT    (N_EDGES + N_NODES)   /* CSR positions: edges (dst-sorted), then self-loops */
#define N_TILES  ((E_TOT + 15) / 16)
#define N_GRAPHS 1024
#define IN_DIM   78
#define K1P      96
#define OUT_DIM  64
#define HEADS    10
#define HID      640
#define NEG_SLOPE 0.2f

static __device__ __forceinline__ float b2f(bf16 v){ return __bfloat162float(v); }
static __device__ __forceinline__ bf16  f2b(float v){ return __float2bfloat16(v); }

__device__ __forceinline__ int clampi(int v, int hi){ return v < 0 ? 0 : (v >= hi ? hi - 1 : v); }

__device__ __forceinline__ float bf2f_bits(short s){
  return __uint_as_float(((unsigned)(unsigned short)s) << 16);
}
__device__ __forceinline__ short f2bf_bits(float v){
  unsigned u = __float_as_uint(v);
  return (short)((u + 0x7fffu + ((u >> 16) & 1u)) >> 16);   // RNE
}

// ---------------------------------------------------------------- fills
__global__ __launch_bounds__(256) void fill_u32(unsigned* __restrict__ p, unsigned v, int n){
  int i = blockIdx.x * 256 + threadIdx.x;
  if (i < n) p[i] = v;
}

// ---------------------------------------------------------------- dtype prep
__global__ __launch_bounds__(256) void conv_x(const float* __restrict__ x, bf16* __restrict__ XB){
  int i = blockIdx.x * 256 + threadIdx.x;
  if (i >= N_NODES * K1P) return;
  int n = i / K1P, k = i - n * K1P;
  XB[i] = f2b(k < IN_DIM ? x[(size_t)n * IN_DIM + k] : 0.f);
}

__global__ __launch_bounds__(256) void conv_wT(const float* __restrict__ W, bf16* __restrict__ WT,
                                               int K, int N, int Kp){
  int i = blockIdx.x * 256 + threadIdx.x;
  if (i >= N * Kp) return;
  int n = i / Kp, k = i - n * Kp;
  WT[i] = f2b(k < K ? W[(size_t)k * N + n] : 0.f);
}

// att -> B-fragment-ordered matrix for 16x16x32 MFMA
__global__ __launch_bounds__(256) void conv_attP(const float* __restrict__ a, bf16* __restrict__ P,
                                                 int heads){
  int i = blockIdx.x * 256 + threadIdx.x;
  if (i >= (HID / 32) * 512) return;
  int chunk = i >> 9;
  int lane  = (i >> 3) & 63;
  int j     = i & 7;
  int h = lane & 15;
  int k = (lane >> 4) * 8 + j;
  int c = chunk * 32 + k;
  float v = 0.f;
  if (heads == HEADS){ if (h < HEADS && (c >> 6) == h) v = a[c]; }
  else               { if (h == 0) v = a[c]; }
  P[i] = f2b(v);
}

// ---------------------------------------------------------------- MFMA GEMM
// XCD-swizzled 1-D grid; optional dual output (cols [0,HID) -> C0, [HID,2*HID) -> C1).
#define BM 128
#define BN 128
#define BK 32

typedef __attribute__((ext_vector_type(8))) short bf16x8;
typedef __attribute__((ext_vector_type(4))) float f32x4;

typedef const __attribute__((address_space(1))) unsigned gu32;
typedef __attribute__((address_space(3))) unsigned lu32;

__global__ __launch_bounds__(256) void mfma_gemm(const bf16* __restrict__ A,
                                                 const bf16* __restrict__ BT,
                                                 bf16* __restrict__ C0,
                                                 bf16* __restrict__ C1,
                                                 int M, int Kp, int NB){
  // block swizzle: all NB col-tiles of a row strip stay on one XCD (d%8 = XCD round-robin)
  int d   = blockIdx.x;
  int xcd = d & 7, j = d >> 3;
  int cb  = j % NB, ri = j / NB;
  int rb  = ri * 8 + xcd;
  const int row0 = rb * BM;
  if (row0 >= M) return;
  const int col0 = cb * BN;

  __shared__ short As[BM * BK];   // slot (r, c) holds k-chunk c ^ ((r>>1)&3)  -> 2-way banks (free)
  __shared__ short Bs[BN * BK];
  const int tid  = threadIdx.x;
  const int lane = tid & 63;
  const int wave = tid >> 6;
  const int wr   = (wave >> 1) * 64;
  const int wc   = (wave & 1) * 64;
  const int l15  = lane & 15;
  const int quad = lane >> 4;
  const int swA  = ((wr + l15) >> 1) & 3;
  const int swB  = ((wc + l15) >> 1) & 3;

  f32x4 acc[4][4];
#pragma unroll
  for (int i = 0; i < 4; ++i)
#pragma unroll
    for (int jj = 0; jj < 4; ++jj) acc[i][jj] = (f32x4){0.f, 0.f, 0.f, 0.f};

  for (int k0 = 0; k0 < Kp; k0 += BK){
#pragma unroll
    for (int t = 0; t < 2; ++t){
      int ci = (t * 4 + wave) * 64 + lane;
      int r  = ci >> 2;
      int ko = ((ci & 3) ^ ((r >> 1) & 3)) * 8;       // swizzled source k-chunk
      int gr = row0 + r; if (gr >= M) gr = M - 1;
      __builtin_amdgcn_global_load_lds((gu32*)(A + (size_t)gr * Kp + k0 + ko),
                                       (lu32*)(&As[(t * 4 + wave) * 512]), 16, 0, 0);
      __builtin_amdgcn_global_load_lds((gu32*)(BT + (size_t)(col0 + r) * Kp + k0 + ko),
                                       (lu32*)(&Bs[(t * 4 + wave) * 512]), 16, 0, 0);
    }
    __syncthreads();

    bf16x8 af[4], bfr[4];
#pragma unroll
    for (int i = 0; i < 4; ++i)
      af[i] = *(bf16x8*)(&As[(wr + i * 16 + l15) * BK + ((quad ^ swA) * 8)]);
#pragma unroll
    for (int jj = 0; jj < 4; ++jj)
      bfr[jj] = *(bf16x8*)(&Bs[(wc + jj * 16 + l15) * BK + ((quad ^ swB) * 8)]);
#pragma unroll
    for (int i = 0; i < 4; ++i)
#pragma unroll
      for (int jj = 0; jj < 4; ++jj)
        acc[i][jj] = __builtin_amdgcn_mfma_f32_16x16x32_bf16(af[i], bfr[jj], acc[i][jj], 0, 0, 0);
    __syncthreads();
  }

  // epilogue: C/D layout col=lane&15, row=quad*4+reg; column-split dual output
#pragma unroll
  for (int i = 0; i < 4; ++i){
#pragma unroll
    for (int jj = 0; jj < 4; ++jj){
      int gc = col0 + wc + jj * 16 + l15;
      bf16* Cp = (gc < HID) ? C0 : C1;
      int cc   = (gc < HID) ? gc : gc - HID;
#pragma unroll
      for (int r = 0; r < 4; ++r){
        int gr = row0 + wr + i * 16 + quad * 4 + r;
        if (gr < M) Cp[(size_t)gr * HID + cc] = f2b(acc[i][jj][r]);
      }
    }
  }
}

// ---------------------------------------------------------------- CSR build
__global__ __launch_bounds__(256) void count_deg(const int* __restrict__ edst, int* __restrict__ degi){
  int e = blockIdx.x * 256 + threadIdx.x;
  if (e >= N_EDGES) return;
  atomicAdd(&degi[clampi(edst[e], N_NODES)], 1);
}

__global__ __launch_bounds__(1024) void scan_rowp(const int* __restrict__ degi,
                                                  int* __restrict__ rowp,
                                                  int* __restrict__ curs,
                                                  float* __restrict__ dinv){
  __shared__ int wsum[16];
  __shared__ int carry_s;
  const int tid = threadIdx.x, lane = tid & 63, wv = tid >> 6;
  if (tid == 0) carry_s = 0;
  __syncthreads();
  for (int base = 0; base < N_NODES; base += 1024){
    int i = base + tid;
    int v = (i < N_NODES) ? degi[i] : 0;
    int incl = v;
#pragma unroll
    for (int ofs = 1; ofs < 64; ofs <<= 1){
      int t = __shfl_up(incl, ofs);
      if (lane >= ofs) incl += t;
    }
    if (lane == 63) wsum[wv] = incl;
    __syncthreads();
    int woff = 0;
    for (int w = 0; w < 16; ++w) if (w < wv) woff += wsum[w];
    int carry = carry_s;
    if (i < N_NODES){
      int excl = carry + woff + incl - v;
      rowp[i] = excl; curs[i] = excl;
      dinv[i] = rsqrtf((float)(v + 1));
    }
    __syncthreads();
    if (tid == 1023) carry_s = carry + woff + incl;
    __syncthreads();
  }
  if (tid == 0) rowp[N_NODES] = carry_s;
}

__global__ __launch_bounds__(256) void bucket_edges(const int* __restrict__ esrc,
                                                    const int* __restrict__ edst,
                                                    int* __restrict__ curs,
                                                    int* __restrict__ srcg,
                                                    int* __restrict__ dstg){
  int e = blockIdx.x * 256 + threadIdx.x;
  if (e >= N_EDGES) return;
  int d = clampi(edst[e], N_NODES);
  int pos = atomicAdd(&curs[d], 1);
  srcg[pos] = clampi(esrc[e], N_NODES);
  dstg[pos] = d;
}

// ---------------------------------------------------------------- MFMA logits (CSR order)
// only0: store just head-0 logit (compact, 4 B/edge) for the single-head layer.
__global__ __launch_bounds__(256) void logits_mfma(const bf16* __restrict__ xl,
                                                   const bf16* __restrict__ xr,
                                                   const int* __restrict__ srcg,
                                                   const int* __restrict__ dstg,
                                                   const bf16* __restrict__ attP,
                                                   float* __restrict__ LOG,
                                                   int only0){
  int wid  = (blockIdx.x * 256 + threadIdx.x) >> 6;
  int lane = threadIdx.x & 63;
  if (wid >= N_TILES) return;
  const int l15 = lane & 15, quad = lane >> 4;
  int p = wid * 16 + l15; if (p >= E_TOT) p = E_TOT - 1;
  int s, d;
  if (p < N_EDGES){ s = srcg[p]; d = dstg[p]; }
  else            { s = d = p - N_EDGES; }
  const bf16* ps = xl + (size_t)s * HID + quad * 8;
  const bf16* pd = xr + (size_t)d * HID + quad * 8;

  f32x4 acc = (f32x4){0.f, 0.f, 0.f, 0.f};
  for (int k0 = 0; k0 < HID; k0 += 32){
    bf16x8 va = *(const bf16x8*)(ps + k0);
    bf16x8 vb = *(const bf16x8*)(pd + k0);
    bf16x8 t;
#pragma unroll
    for (int j = 0; j < 8; ++j){
      float v = bf2f_bits(va[j]) + bf2f_bits(vb[j]);
      v = fmaxf(v, 0.f) + NEG_SLOPE * fminf(v, 0.f);
      t[j] = f2bf_bits(v);
    }
    bf16x8 wb = *(const bf16x8*)(attP + (k0 >> 5) * 512 + lane * 8);
    acc = __builtin_amdgcn_mfma_f32_16x16x32_bf16(t, wb, acc, 0, 0, 0);
  }
  int er = wid * 16 + quad * 4;
  if (only0){
    if (l15 == 0){
#pragma unroll
      for (int r = 0; r < 4; ++r){
        int ee = er + r;
        if (ee < E_TOT) LOG[ee] = acc[r];
      }
    }
  } else {
#pragma unroll
    for (int r = 0; r < 4; ++r){
      int ee = er + r;
      if (ee < E_TOT) LOG[(size_t)ee * 16 + l15] = acc[r];
    }
  }
}

// ---------------------------------------------------------------- GAT1 aggregation
// lane l owns ch [8l,8l+8) (head l>>3) and ch {512+2l,513+2l} (head 8+(l>>5)).
__global__ __launch_bounds__(256) void gat1_agg(const bf16* __restrict__ xl,
                                                const int* __restrict__ srcg,
                                                const int* __restrict__ rowp,
                                                const float* __restrict__ LOG,
                                                const float* __restrict__ bias,
                                                bf16* __restrict__ H){
  int n    = (blockIdx.x * 256 + threadIdx.x) >> 6;
  int lane = threadIdx.x & 63;
  if (n >= N_NODES) return;
  const int l15 = lane & 15;
  const int hA = lane >> 3;
  const int hB = 8 + (lane >> 5);
  int r0 = rowp[n], r1 = rowp[n + 1];

  float lself = LOG[(size_t)(N_EDGES + n) * 16 + l15];
  float m = lself;
  for (int p = r0; p < r1; ++p) m = fmaxf(m, LOG[(size_t)p * 16 + l15]);

  float p0  = __expf(lself - m);
  float den = p0;
  float accA[8], accB[2];
  {
    float pA = __shfl(p0, hA), pB = __shfl(p0, hB);
    const bf16* xn = xl + (size_t)n * HID;
    bf16x8 va = *(const bf16x8*)(xn + 8 * lane);
    unsigned vb = *(const unsigned*)(xn + 512 + 2 * lane);
#pragma unroll
    for (int j = 0; j < 8; ++j) accA[j] = pA * bf2f_bits(va[j]);
    accB[0] = pB * bf2f_bits((short)(vb & 0xffff));
    accB[1] = pB * bf2f_bits((short)(vb >> 16));
  }
  for (int p = r0; p < r1; ++p){
    int s = srcg[p];
    float pv = __expf(LOG[(size_t)p * 16 + l15] - m);
    den += pv;
    float pA = __shfl(pv, hA), pB = __shfl(pv, hB);
    const bf16* xs = xl + (size_t)s * HID;
    bf16x8 va = *(const bf16x8*)(xs + 8 * lane);
    unsigned vb = *(const unsigned*)(xs + 512 + 2 * lane);
#pragma unroll
    for (int j = 0; j < 8; ++j) accA[j] += pA * bf2f_bits(va[j]);
    accB[0] += pB * bf2f_bits((short)(vb & 0xffff));
    accB[1] += pB * bf2f_bits((short)(vb >> 16));
  }
  float dA = __shfl(den, hA), dB = __shfl(den, hB);
  float4 bA0 = *(const float4*)(bias + 8 * lane);
  float4 bA1 = *(const float4*)(bias + 8 * lane + 4);
  float2 bB  = *(const float2*)(bias + 512 + 2 * lane);
  bf16x8 oA;
  float bAa[8] = {bA0.x, bA0.y, bA0.z, bA0.w, bA1.x, bA1.y, bA1.z, bA1.w};
#pragma unroll
  for (int j = 0; j < 8; ++j){
    float v = accA[j] / dA + bAa[j];
    v = v > 0.f ? v : (__expf(v) - 1.f);              // ELU
    oA[j] = f2bf_bits(v);
  }
  float v0 = accB[0] / dB + bB.x; v0 = v0 > 0.f ? v0 : (__expf(v0) - 1.f);
  float v1 = accB[1] / dB + bB.y; v1 = v1 > 0.f ? v1 : (__expf(v1) - 1.f);
  bf16* hn = H + (size_t)n * HID;
  *(bf16x8*)(hn + 8 * lane) = oA;
  unsigned ob = (unsigned)(unsigned short)f2bf_bits(v0) |
                ((unsigned)(unsigned short)f2bf_bits(v1) << 16);
  *(unsigned*)(hn + 512 + 2 * lane) = ob;
}

// ---------------------------------------------------------------- GAT2 aggregation (1 head, compact LOG)
__global__ __launch_bounds__(256) void gat2_agg(const bf16* __restrict__ xl,
                                                const int* __restrict__ srcg,
                                                const int* __restrict__ rowp,
                                                const float* __restrict__ LOG,
                                                const float* __restrict__ bias,
                                                bf16* __restrict__ H){
  int n    = (blockIdx.x * 256 + threadIdx.x) >> 6;
  int lane = threadIdx.x & 63;
  if (n >= N_NODES) return;
  int r0 = rowp[n], r1 = rowp[n + 1];

  float lself = LOG[N_EDGES + n];
  float m = lself;
  for (int p = r0; p < r1; ++p) m = fmaxf(m, LOG[p]);

  float p0  = __expf(lself - m);
  float den = p0;
  float accA[8], accB[2];
  {
    const bf16* xn = xl + (size_t)n * HID;
    bf16x8 va = *(const bf16x8*)(xn + 8 * lane);
    unsigned vb = *(const unsigned*)(xn + 512 + 2 * lane);
#pragma unroll
    for (int j = 0; j < 8; ++j) accA[j] = p0 * bf2f_bits(va[j]);
    accB[0] = p0 * bf2f_bits((short)(vb & 0xffff));
    accB[1] = p0 * bf2f_bits((short)(vb >> 16));
  }
  for (int p = r0; p < r1; ++p){
    int s = srcg[p];
    float pv = __expf(LOG[p] - m);
    den += pv;
    const bf16* xs = xl + (size_t)s * HID;
    bf16x8 va = *(const bf16x8*)(xs + 8 * lane);
    unsigned vb = *(const unsigned*)(xs + 512 + 2 * lane);
#pragma unroll
    for (int j = 0; j < 8; ++j) accA[j] += pv * bf2f_bits(va[j]);
    accB[0] += pv * bf2f_bits((short)(vb & 0xffff));
    accB[1] += pv * bf2f_bits((short)(vb >> 16));
  }
  float inv = 1.f / den;
  float4 bA0 = *(const float4*)(bias + 8 * lane);
  float4 bA1 = *(const float4*)(bias + 8 * lane + 4);
  float2 bB  = *(const float2*)(bias + 512 + 2 * lane);
  float bAa[8] = {bA0.x, bA0.y, bA0.z, bA0.w, bA1.x, bA1.y, bA1.z, bA1.w};
  bf16x8 oA;
#pragma unroll
  for (int j = 0; j < 8; ++j) oA[j] = f2bf_bits(accA[j] * inv + bAa[j]);
  bf16* hn = H + (size_t)n * HID;
  *(bf16x8*)(hn + 8 * lane) = oA;
  unsigned ob = (unsigned)(unsigned short)f2bf_bits(accB[0] * inv + bB.x) |
                ((unsigned)(unsigned short)f2bf_bits(accB[1] * inv + bB.y) << 16);
  *(unsigned*)(hn + 512 + 2 * lane) = ob;
}

// ---------------------------------------------------------------- GCN gather: bias+ReLU -> bf16 h3
__global__ __launch_bounds__(256) void gcn_gather(const bf16* __restrict__ xw,
                                                  const int* __restrict__ srcg,
                                                  const int* __restrict__ rowp,
                                                  const float* __restrict__ dinv,
                                                  const float* __restrict__ bg,
                                                  bf16* __restrict__ h3){
  int n    = (blockIdx.x * 256 + threadIdx.x) >> 6;
  int lane = threadIdx.x & 63;
  if (n >= N_NODES) return;
  int r0 = rowp[n], r1 = rowp[n + 1];

  float dn = dinv[n];
  float accA[8], accB[2];
  {
    float w = dn * dn;
    const bf16* xn = xw + (size_t)n * HID;
    bf16x8 va = *(const bf16x8*)(xn + 8 * lane);
    unsigned vb = *(const unsigned*)(xn + 512 + 2 * lane);
#pragma unroll
    for (int j = 0; j < 8; ++j) accA[j] = w * bf2f_bits(va[j]);
    accB[0] = w * bf2f_bits((short)(vb & 0xffff));
    accB[1] = w * bf2f_bits((short)(vb >> 16));
  }
  for (int p = r0; p < r1; ++p){
    int s = srcg[p];
    float w = dinv[s] * dn;
    const bf16* xs = xw + (size_t)s * HID;
    bf16x8 va = *(const bf16x8*)(xs + 8 * lane);
    unsigned vb = *(const unsigned*)(xs + 512 + 2 * lane);
#pragma unroll
    for (int j = 0; j < 8; ++j) accA[j] += w * bf2f_bits(va[j]);
    accB[0] += w * bf2f_bits((short)(vb & 0xffff));
    accB[1] += w * bf2f_bits((short)(vb >> 16));
  }
  float4 bA0 = *(const float4*)(bg + 8 * lane);
  float4 bA1 = *(const float4*)(bg + 8 * lane + 4);
  float2 bB  = *(const float2*)(bg + 512 + 2 * lane);
  float bAa[8] = {bA0.x, bA0.y, bA0.z, bA0.w, bA1.x, bA1.y, bA1.z, bA1.w};
  bf16x8 oA;
#pragma unroll
  for (int j = 0; j < 8; ++j) oA[j] = f2bf_bits(fmaxf(accA[j] + bAa[j], 0.f));
  bf16* hn = h3 + (size_t)n * HID;
  *(bf16x8*)(hn + 8 * lane) = oA;
  unsigned ob = (unsigned)(unsigned short)f2bf_bits(fmaxf(accB[0] + bB.x, 0.f)) |
                ((unsigned)(unsigned short)f2bf_bits(fmaxf(accB[1] + bB.y, 0.f)) << 16);
  *(unsigned*)(hn + 512 + 2 * lane) = ob;
}

// ---------------------------------------------------------------- per-graph pooling (batch is sorted)
__global__ __launch_bounds__(256) void graph_bounds(const int* __restrict__ batch,
                                                    int* __restrict__ gstart){
  int n = blockIdx.x * 256 + threadIdx.x;
  if (n >= N_NODES) return;
  int b = clampi(batch[n], N_GRAPHS);
  if (n == 0){
    for (int g = 0; g <= b; ++g) gstart[g] = 0;
  } else {
    int bp = clampi(batch[n - 1], N_GRAPHS);
    for (int g = bp + 1; g <= b; ++g) gstart[g] = n;
  }
  if (n == N_NODES - 1){
    for (int g = b + 1; g <= N_GRAPHS; ++g) gstart[g] = N_NODES;
  }
}

__global__ __launch_bounds__(640) void pool_graph(const bf16* __restrict__ h3,
                                                  const int* __restrict__ gstart,
                                                  float* __restrict__ out){
  int g = blockIdx.x;
  int c = threadIdx.x;
  int n0 = gstart[g], n1 = gstart[g + 1];
  float mx = 0.f, sm = 0.f;     // h3 >= 0 post-ReLU
  for (int n = n0; n < n1; ++n){
    float v = b2f(h3[(size_t)n * HID + c]);
    mx = fmaxf(mx, v); sm += v;
  }
  float mean = (n1 > n0) ? sm / (float)(n1 - n0) : 0.f;
  out[(size_t)g * 2 * HID + c]       = mx;
  out[(size_t)g * 2 * HID + HID + c] = mean;
}

// ---------------------------------------------------------------- launch
extern "C" void kernel_launch(void* const* d_in, const int* in_sizes, int n_in,
                              void* d_out, int out_size, void* d_ws, size_t ws_size,
                              hipStream_t stream){
  const float* x     = (const float*)d_in[0];
  const int*   ei    = (const int*)d_in[1];
  const int*   batch = (const int*)d_in[2];
  const float* Wl1 = (const float*)d_in[3];
  const float* Wr1 = (const float*)d_in[4];
  const float* a1  = (const float*)d_in[5];
  const float* b1  = (const float*)d_in[6];
  const float* Wl2 = (const float*)d_in[7];
  const float* Wr2 = (const float*)d_in[8];
  const float* a2  = (const float*)d_in[9];
  const float* b2  = (const float*)d_in[10];
  const float* Wg  = (const float*)d_in[11];
  const float* bg  = (const float*)d_in[12];
  const int* esrc = ei;
  const int* edst = ei + N_EDGES;

  // ---- workspace layout (~219 MB) ----
  char* ws = (char*)d_ws;
  size_t off = 0;
  auto take = [&](size_t bytes)->char*{
    char* p = ws + off; off = (off + bytes + 255) & ~(size_t)255; return p;
  };
  bf16*     X1   = (bf16*)    take((size_t)N_NODES * HID * 2);
  bf16*     X2   = (bf16*)    take((size_t)N_NODES * HID * 2);
  bf16*     H    = (bf16*)    take((size_t)N_NODES * HID * 2);
  bf16*     XB   = (bf16*)    take((size_t)N_NODES * K1P * 2);
  // NB: WT1l/WT1r contiguous (size multiple of 256) -> treated as one 1280xK1P matrix; same for WT2l/WT2r.
  bf16*     WT1l = (bf16*)    take((size_t)HID * K1P * 2);
  bf16*     WT1r = (bf16*)    take((size_t)HID * K1P * 2);
  bf16*     WT2l = (bf16*)    take((size_t)HID * HID * 2);
  bf16*     WT2r = (bf16*)    take((size_t)HID * HID * 2);
  bf16*     WTg  = (bf16*)    take((size_t)HID * HID * 2);
  bf16*     AT1P = (bf16*)    take((size_t)(HID / 32) * 512 * 2);
  bf16*     AT2P = (bf16*)    take((size_t)(HID / 32) * 512 * 2);
  float*    LOG  = (float*)   take((size_t)E_TOT * 16 * 4);
  int*      DEGI = (int*)     take((size_t)N_NODES * 4);
  int*      ROWP = (int*)     take((size_t)(N_NODES + 1) * 4);
  int*      CURS = (int*)     take((size_t)N_NODES * 4);
  int*      SRCG = (int*)     take((size_t)N_EDGES * 4);
  int*      DSTG = (int*)     take((size_t)N_EDGES * 4);
  float*    DINV = (float*)   take((size_t)N_NODES * 4);
  int*      GST  = (int*)     take((size_t)(N_GRAPHS + 1) * 4);

  dim3 blk(256);
  auto fill = [&](void* p, unsigned v, int n){
    fill_u32<<<dim3((n + 255) / 256), blk, 0, stream>>>((unsigned*)p, v, n);
  };
  const int MB8     = ((N_NODES + BM - 1) / BM + 7) / 8;   // row strips per XCD (49)
  const int nblocks = (N_NODES * 64 + 255) / 256;
  const int lblocks = (N_TILES * 64 + 255) / 256;
  const int reblk   = (N_EDGES + 255) / 256;
  const int apn     = (HID / 32) * 512;

  // ---- prep + CSR ----
  conv_x<<<(N_NODES * K1P + 255) / 256, blk, 0, stream>>>(x, XB);
  conv_wT<<<(HID * K1P + 255) / 256, blk, 0, stream>>>(Wl1, WT1l, IN_DIM, HID, K1P);
  conv_wT<<<(HID * K1P + 255) / 256, blk, 0, stream>>>(Wr1, WT1r, IN_DIM, HID, K1P);
  conv_wT<<<(HID * HID + 255) / 256, blk, 0, stream>>>(Wl2, WT2l, HID, HID, HID);
  conv_wT<<<(HID * HID + 255) / 256, blk, 0, stream>>>(Wr2, WT2r, HID, HID, HID);
  conv_wT<<<(HID * HID + 255) / 256, blk, 0, stream>>>(Wg,  WTg,  HID, HID, HID);
  conv_attP<<<(apn + 255) / 256, blk, 0, stream>>>(a1, AT1P, HEADS);
  conv_attP<<<(apn + 255) / 256, blk, 0, stream>>>(a2, AT2P, 1);
  fill(DEGI, 0u, N_NODES);
  count_deg<<<reblk, blk, 0, stream>>>(edst, DEGI);
  scan_rowp<<<1, 1024, 0, stream>>>(DEGI, ROWP, CURS, DINV);
  bucket_edges<<<reblk, blk, 0, stream>>>(esrc, edst, CURS, SRCG, DSTG);
  graph_bounds<<<(N_NODES + 255) / 256, blk, 0, stream>>>(batch, GST);

  // ---- GATv2 layer 1 (merged Wl|Wr GEMM, N=1280) ----
  mfma_gemm<<<dim3(8 * MB8 * 10), blk, 0, stream>>>(XB, WT1l, X1, X2, N_NODES, K1P, 10);
  logits_mfma<<<lblocks, blk, 0, stream>>>(X1, X2, SRCG, DSTG, AT1P, LOG, 0);
  gat1_agg<<<nblocks, blk, 0, stream>>>(X1, SRCG, ROWP, LOG, b1, H);

  // ---- GATv2 layer 2 (merged Wl|Wr GEMM, N=1280; compact logits) ----
  mfma_gemm<<<dim3(8 * MB8 * 10), blk, 0, stream>>>(H, WT2l, X1, X2, N_NODES, HID, 10);
  logits_mfma<<<lblocks, blk, 0, stream>>>(X1, X2, SRCG, DSTG, AT2P, LOG, 1);
  gat2_agg<<<nblocks, blk, 0, stream>>>(X1, SRCG, ROWP, LOG, b2, H);

  // ---- GCN + pooling ----
  mfma_gemm<<<dim3(8 * MB8 * 5), blk, 0, stream>>>(H, WTg, X1, X1, N_NODES, HID, 5);
  gcn_gather<<<nblocks, blk, 0, stream>>>(X1, SRCG, ROWP, DINV, bg, X2);
  pool_graph<<<dim3(N_GRAPHS), dim3(640), 0, stream>>>(X2, GST, (float*)d_out);
}

// Round 10
// 678.415 us; speedup vs baseline: 7.0650x; 1.0416x over previous
//
#include <hip/hip_runtime.h>
#include <hip/hip_bf16.h>
#include <cstdint>
#include <cstddef>

typedef __hip_bfloat16 bf16;

#define N_NODES  50000
#define N_EDGES  150000
#define E_TOT    (N_EDGES + N_NODES)   /* CSR positions: edges (dst-sorted), then self-loops */
#define N_TILES  ((E_TOT + 15) / 16)
#define N_GRAPHS 1024
#define IN_DIM   78
#define K1P      96
#define OUT_DIM  64
#define HEADS    10
#define HID      640
#define NEG_SLOPE 0.2f

static __device__ __forceinline__ float b2f(bf16 v){ return __bfloat162float(v); }
static __device__ __forceinline__ bf16  f2b(float v){ return __float2bfloat16(v); }

__device__ __forceinline__ int clampi(int v, int hi){ return v < 0 ? 0 : (v >= hi ? hi - 1 : v); }

__device__ __forceinline__ float bf2f_bits(short s){
  return __uint_as_float(((unsigned)(unsigned short)s) << 16);
}
__device__ __forceinline__ short f2bf_bits(float v){      // RNE (used where accuracy matters)
  unsigned u = __float_as_uint(v);
  return (short)((u + 0x7fffu + ((u >> 16) & 1u)) >> 16);
}
__device__ __forceinline__ short f2bf_trunc(float v){     // cheap truncation (logits path)
  return (short)(__float_as_uint(v) >> 16);
}

// ---------------------------------------------------------------- fills
__global__ __launch_bounds__(256) void fill_u32(unsigned* __restrict__ p, unsigned v, int n){
  int i = blockIdx.x * 256 + threadIdx.x;
  if (i < n) p[i] = v;
}

// ---------------------------------------------------------------- dtype prep
__global__ __launch_bounds__(256) void conv_x(const float* __restrict__ x, bf16* __restrict__ XB){
  int i = blockIdx.x * 256 + threadIdx.x;
  if (i >= N_NODES * K1P) return;
  int n = i / K1P, k = i - n * K1P;
  XB[i] = f2b(k < IN_DIM ? x[(size_t)n * IN_DIM + k] : 0.f);
}

// 2 weight matrices -> contiguous transposed bf16 (layer-1 pair, K padded)
__global__ __launch_bounds__(256) void conv_wT2(const float* __restrict__ W0,
                                                const float* __restrict__ W1,
                                                bf16* __restrict__ WT,
                                                int K, int N, int Kp){
  int i = blockIdx.x * 256 + threadIdx.x;
  const int per = N * Kp;
  if (i >= 2 * per) return;
  int m = i / per, r = i - m * per;
  const float* W = m == 0 ? W0 : W1;
  int n = r / Kp, k = r - n * Kp;
  WT[i] = f2b(k < K ? W[(size_t)k * N + n] : 0.f);
}

// 3 weight matrices -> contiguous transposed bf16 (Wl2|Wr2|Wg)
__global__ __launch_bounds__(256) void conv_wT3(const float* __restrict__ W0,
                                                const float* __restrict__ W1,
                                                const float* __restrict__ W2,
                                                bf16* __restrict__ WT,
                                                int K, int N, int Kp){
  int i = blockIdx.x * 256 + threadIdx.x;
  const int per = N * Kp;
  if (i >= 3 * per) return;
  int m = i / per, r = i - m * per;
  const float* W = m == 0 ? W0 : (m == 1 ? W1 : W2);
  int n = r / Kp, k = r - n * Kp;
  WT[i] = f2b(k < K ? W[(size_t)k * N + n] : 0.f);
}

// att -> B-fragment-ordered matrix for 16x16x32 MFMA
__global__ __launch_bounds__(256) void conv_attP(const float* __restrict__ a, bf16* __restrict__ P,
                                                 int heads){
  int i = blockIdx.x * 256 + threadIdx.x;
  if (i >= (HID / 32) * 512) return;
  int chunk = i >> 9;
  int lane  = (i >> 3) & 63;
  int j     = i & 7;
  int h = lane & 15;
  int k = (lane >> 4) * 8 + j;
  int c = chunk * 32 + k;
  float v = 0.f;
  if (heads == HEADS){ if (h < HEADS && (c >> 6) == h) v = a[c]; }
  else               { if (h == 0) v = a[c]; }
  P[i] = f2b(v);
}

// ---------------------------------------------------------------- MFMA GEMM
#define BM 128
#define BN 128
#define BK 32

typedef __attribute__((ext_vector_type(8))) short bf16x8;
typedef __attribute__((ext_vector_type(4))) float f32x4;

typedef const __attribute__((address_space(1))) unsigned gu32;
typedef __attribute__((address_space(3))) unsigned lu32;

__global__ __launch_bounds__(256) void mfma_gemm(const bf16* __restrict__ A,
                                                 const bf16* __restrict__ BT,
                                                 bf16* __restrict__ C0,
                                                 bf16* __restrict__ C1,
                                                 int M, int Kp, int NB){
  // block swizzle: all NB col-tiles of a row strip stay on one XCD (d%8 = XCD round-robin)
  int d   = blockIdx.x;
  int xcd = d & 7, j = d >> 3;
  int cb  = j % NB, ri = j / NB;
  int rb  = ri * 8 + xcd;
  const int row0 = rb * BM;
  if (row0 >= M) return;
  const int col0 = cb * BN;

  __shared__ short As[BM * BK];   // slot (r, c) holds k-chunk c ^ ((r>>1)&3)  -> 2-way banks (free)
  __shared__ short Bs[BN * BK];
  const int tid  = threadIdx.x;
  const int lane = tid & 63;
  const int wave = tid >> 6;
  const int wr   = (wave >> 1) * 64;
  const int wc   = (wave & 1) * 64;
  const int l15  = lane & 15;
  const int quad = lane >> 4;
  const int swA  = ((wr + l15) >> 1) & 3;
  const int swB  = ((wc + l15) >> 1) & 3;

  // hoisted staging addresses (row clamp done once, K-loop is pointer + k0)
  const bf16* aptr[2];
  const bf16* bptr[2];
  lu32* lda[2];
  lu32* ldb[2];
#pragma unroll
  for (int t = 0; t < 2; ++t){
    int ci = (t * 4 + wave) * 64 + lane;
    int r  = ci >> 2;
    int ko = ((ci & 3) ^ ((r >> 1) & 3)) * 8;
    int gr = row0 + r; if (gr >= M) gr = M - 1;
    aptr[t] = A  + (size_t)gr * Kp + ko;
    bptr[t] = BT + (size_t)(col0 + r) * Kp + ko;
    lda[t]  = (lu32*)(&As[(t * 4 + wave) * 512]);
    ldb[t]  = (lu32*)(&Bs[(t * 4 + wave) * 512]);
  }

  f32x4 acc[4][4];
#pragma unroll
  for (int i = 0; i < 4; ++i)
#pragma unroll
    for (int jj = 0; jj < 4; ++jj) acc[i][jj] = (f32x4){0.f, 0.f, 0.f, 0.f};

  for (int k0 = 0; k0 < Kp; k0 += BK){
#pragma unroll
    for (int t = 0; t < 2; ++t){
      __builtin_amdgcn_global_load_lds((gu32*)(aptr[t] + k0), lda[t], 16, 0, 0);
      __builtin_amdgcn_global_load_lds((gu32*)(bptr[t] + k0), ldb[t], 16, 0, 0);
    }
    __syncthreads();

    bf16x8 af[4], bfr[4];
#pragma unroll
    for (int i = 0; i < 4; ++i)
      af[i] = *(bf16x8*)(&As[(wr + i * 16 + l15) * BK + ((quad ^ swA) * 8)]);
#pragma unroll
    for (int jj = 0; jj < 4; ++jj)
      bfr[jj] = *(bf16x8*)(&Bs[(wc + jj * 16 + l15) * BK + ((quad ^ swB) * 8)]);
#pragma unroll
    for (int i = 0; i < 4; ++i)
#pragma unroll
      for (int jj = 0; jj < 4; ++jj)
        acc[i][jj] = __builtin_amdgcn_mfma_f32_16x16x32_bf16(af[i], bfr[jj], acc[i][jj], 0, 0, 0);
    __syncthreads();
  }

  // epilogue: C/D layout col=lane&15, row=quad*4+reg; column-split dual output
  if (row0 + BM <= M){          // full strip: no row guards (391/392 tiles)
#pragma unroll
    for (int i = 0; i < 4; ++i){
#pragma unroll
      for (int jj = 0; jj < 4; ++jj){
        int gc = col0 + wc + jj * 16 + l15;
        bf16* Cp = (gc < HID) ? C0 : C1;
        size_t cc = (gc < HID) ? gc : gc - HID;
        size_t base = (size_t)(row0 + wr + i * 16 + quad * 4) * HID + cc;
#pragma unroll
        for (int r = 0; r < 4; ++r)
          Cp[base + (size_t)r * HID] = f2b(acc[i][jj][r]);
      }
    }
  } else {
#pragma unroll
    for (int i = 0; i < 4; ++i){
#pragma unroll
      for (int jj = 0; jj < 4; ++jj){
        int gc = col0 + wc + jj * 16 + l15;
        bf16* Cp = (gc < HID) ? C0 : C1;
        int cc   = (gc < HID) ? gc : gc - HID;
#pragma unroll
        for (int r = 0; r < 4; ++r){
          int gr = row0 + wr + i * 16 + quad * 4 + r;
          if (gr < M) Cp[(size_t)gr * HID + cc] = f2b(acc[i][jj][r]);
        }
      }
    }
  }
}

// ---------------------------------------------------------------- CSR build
__global__ __launch_bounds__(256) void count_deg(const int* __restrict__ edst, int* __restrict__ degi){
  int e = blockIdx.x * 256 + threadIdx.x;
  if (e >= N_EDGES) return;
  atomicAdd(&degi[clampi(edst[e], N_NODES)], 1);
}

__global__ __launch_bounds__(1024) void scan_rowp(const int* __restrict__ degi,
                                                  int* __restrict__ rowp,
                                                  int* __restrict__ curs,
                                                  float* __restrict__ dinv){
  __shared__ int wsum[16];
  __shared__ int carry_s;
  const int tid = threadIdx.x, lane = tid & 63, wv = tid >> 6;
  if (tid == 0) carry_s = 0;
  __syncthreads();
  for (int base = 0; base < N_NODES; base += 1024){
    int i = base + tid;
    int v = (i < N_NODES) ? degi[i] : 0;
    int incl = v;
#pragma unroll
    for (int ofs = 1; ofs < 64; ofs <<= 1){
      int t = __shfl_up(incl, ofs);
      if (lane >= ofs) incl += t;
    }
    if (lane == 63) wsum[wv] = incl;
    __syncthreads();
    int woff = 0;
    for (int w = 0; w < 16; ++w) if (w < wv) woff += wsum[w];
    int carry = carry_s;
    if (i < N_NODES){
      int excl = carry + woff + incl - v;
      rowp[i] = excl; curs[i] = excl;
      dinv[i] = rsqrtf((float)(v + 1));
    }
    __syncthreads();
    if (tid == 1023) carry_s = carry + woff + incl;
    __syncthreads();
  }
  if (tid == 0) rowp[N_NODES] = carry_s;
}

__global__ __launch_bounds__(256) void bucket_edges(const int* __restrict__ esrc,
                                                    const int* __restrict__ edst,
                                                    int* __restrict__ curs,
                                                    int* __restrict__ srcg,
                                                    int* __restrict__ dstg){
  int e = blockIdx.x * 256 + threadIdx.x;
  if (e >= N_EDGES) return;
  int d = clampi(edst[e], N_NODES);
  int pos = atomicAdd(&curs[d], 1);
  srcg[pos] = clampi(esrc[e], N_NODES);
  dstg[pos] = d;
}

// ---------------------------------------------------------------- MFMA logits (CSR order)
// only0: store just head-0 logit (compact) for the single-head layer.
__global__ __launch_bounds__(256) void logits_mfma(const bf16* __restrict__ xl,
                                                   const bf16* __restrict__ xr,
                                                   const int* __restrict__ srcg,
                                                   const int* __restrict__ dstg,
                                                   const bf16* __restrict__ attP,
                                                   float* __restrict__ LOG,
                                                   int only0){
  int wid  = (blockIdx.x * 256 + threadIdx.x) >> 6;
  int lane = threadIdx.x & 63;
  if (wid >= N_TILES) return;
  const int l15 = lane & 15, quad = lane >> 4;
  int p = wid * 16 + l15; if (p >= E_TOT) p = E_TOT - 1;
  int s, d;
  if (p < N_EDGES){ s = srcg[p]; d = dstg[p]; }
  else            { s = d = p - N_EDGES; }
  const bf16* ps = xl + (size_t)s * HID + quad * 8;
  const bf16* pd = xr + (size_t)d * HID + quad * 8;

  f32x4 acc = (f32x4){0.f, 0.f, 0.f, 0.f};
  for (int k0 = 0; k0 < HID; k0 += 32){
    bf16x8 va = *(const bf16x8*)(ps + k0);
    bf16x8 vb = *(const bf16x8*)(pd + k0);
    bf16x8 t;
#pragma unroll
    for (int j = 0; j < 8; ++j){
      float v = bf2f_bits(va[j]) + bf2f_bits(vb[j]);
      v *= (v > 0.f) ? 1.f : NEG_SLOPE;            // cndmask + mul
      t[j] = f2bf_trunc(v);                        // 1-op repack
    }
    bf16x8 wb = *(const bf16x8*)(attP + (k0 >> 5) * 512 + lane * 8);
    acc = __builtin_amdgcn_mfma_f32_16x16x32_bf16(t, wb, acc, 0, 0, 0);
  }
  int er = wid * 16 + quad * 4;
  if (only0){
    if (l15 == 0){
#pragma unroll
      for (int r = 0; r < 4; ++r){
        int ee = er + r;
        if (ee < E_TOT) LOG[ee] = acc[r];
      }
    }
  } else {
#pragma unroll
    for (int r = 0; r < 4; ++r){
      int ee = er + r;
      if (ee < E_TOT) LOG[(size_t)ee * 16 + l15] = acc[r];
    }
  }
}

// ---------------------------------------------------------------- GAT1 aggregation (2-way unrolled)
// lane l owns ch [8l,8l+8) (head l>>3) and ch {512+2l,513+2l} (head 8+(l>>5)).
__global__ __launch_bounds__(256) void gat1_agg(const bf16* __restrict__ xl,
                                                const int* __restrict__ srcg,
                                                const int* __restrict__ rowp,
                                                const float* __restrict__ LOG,
                                                const float* __restrict__ bias,
                                                bf16* __restrict__ H){
  int n    = (blockIdx.x * 256 + threadIdx.x) >> 6;
  int lane = threadIdx.x & 63;
  if (n >= N_NODES) return;
  const int l15 = lane & 15;
  const int hA = lane >> 3;
  const int hB = 8 + (lane >> 5);
  int r0 = rowp[n], r1 = rowp[n + 1];

  float lself = LOG[(size_t)(N_EDGES + n) * 16 + l15];
  float m = lself;
  for (int p = r0; p < r1; ++p) m = fmaxf(m, LOG[(size_t)p * 16 + l15]);

  float p0  = __expf(lself - m);
  float den = p0;
  float accA[8], accB[2];
  {
    float pA = __shfl(p0, hA), pB = __shfl(p0, hB);
    const bf16* xn = xl + (size_t)n * HID;
    bf16x8 va = *(const bf16x8*)(xn + 8 * lane);
    unsigned vb = *(const unsigned*)(xn + 512 + 2 * lane);
#pragma unroll
    for (int j = 0; j < 8; ++j) accA[j] = pA * bf2f_bits(va[j]);
    accB[0] = pB * bf2f_bits((short)(vb & 0xffff));
    accB[1] = pB * bf2f_bits((short)(vb >> 16));
  }
  int p = r0;
  for (; p + 1 < r1; p += 2){
    int s0 = srcg[p], s1 = srcg[p + 1];
    float l0 = LOG[(size_t)p * 16 + l15];
    float l1 = LOG[(size_t)(p + 1) * 16 + l15];
    const bf16* xs0 = xl + (size_t)s0 * HID;
    const bf16* xs1 = xl + (size_t)s1 * HID;
    bf16x8 va0 = *(const bf16x8*)(xs0 + 8 * lane);
    bf16x8 va1 = *(const bf16x8*)(xs1 + 8 * lane);
    unsigned vb0 = *(const unsigned*)(xs0 + 512 + 2 * lane);
    unsigned vb1 = *(const unsigned*)(xs1 + 512 + 2 * lane);
    float pv0 = __expf(l0 - m), pv1 = __expf(l1 - m);
    den += pv0 + pv1;
    float pA0 = __shfl(pv0, hA), pB0 = __shfl(pv0, hB);
    float pA1 = __shfl(pv1, hA), pB1 = __shfl(pv1, hB);
#pragma unroll
    for (int j = 0; j < 8; ++j) accA[j] += pA0 * bf2f_bits(va0[j]) + pA1 * bf2f_bits(va1[j]);
    accB[0] += pB0 * bf2f_bits((short)(vb0 & 0xffff)) + pB1 * bf2f_bits((short)(vb1 & 0xffff));
    accB[1] += pB0 * bf2f_bits((short)(vb0 >> 16))    + pB1 * bf2f_bits((short)(vb1 >> 16));
  }
  if (p < r1){
    int s = srcg[p];
    float pv = __expf(LOG[(size_t)p * 16 + l15] - m);
    den += pv;
    float pA = __shfl(pv, hA), pB = __shfl(pv, hB);
    const bf16* xs = xl + (size_t)s * HID;
    bf16x8 va = *(const bf16x8*)(xs + 8 * lane);
    unsigned vb = *(const unsigned*)(xs + 512 + 2 * lane);
#pragma unroll
    for (int j = 0; j < 8; ++j) accA[j] += pA * bf2f_bits(va[j]);
    accB[0] += pB * bf2f_bits((short)(vb & 0xffff));
    accB[1] += pB * bf2f_bits((short)(vb >> 16));
  }
  float dA = __shfl(den, hA), dB = __shfl(den, hB);
  float4 bA0 = *(const float4*)(bias + 8 * lane);
  float4 bA1 = *(const float4*)(bias + 8 * lane + 4);
  float2 bB  = *(const float2*)(bias + 512 + 2 * lane);
  bf16x8 oA;
  float bAa[8] = {bA0.x, bA0.y, bA0.z, bA0.w, bA1.x, bA1.y, bA1.z, bA1.w};
#pragma unroll
  for (int j = 0; j < 8; ++j){
    float v = accA[j] / dA + bAa[j];
    v = v > 0.f ? v : (__expf(v) - 1.f);              // ELU
    oA[j] = f2bf_bits(v);
  }
  float v0 = accB[0] / dB + bB.x; v0 = v0 > 0.f ? v0 : (__expf(v0) - 1.f);
  float v1 = accB[1] / dB + bB.y; v1 = v1 > 0.f ? v1 : (__expf(v1) - 1.f);
  bf16* hn = H + (size_t)n * HID;
  *(bf16x8*)(hn + 8 * lane) = oA;
  unsigned ob = (unsigned)(unsigned short)f2bf_bits(v0) |
                ((unsigned)(unsigned short)f2bf_bits(v1) << 16);
  *(unsigned*)(hn + 512 + 2 * lane) = ob;
}

// ---------------------------------------------------------------- GAT2 aggregation (1 head, compact LOG, unrolled)
__global__ __launch_bounds__(256) void gat2_agg(const bf16* __restrict__ xl,
                                                const int* __restrict__ srcg,
                                                const int* __restrict__ rowp,
                                                const float* __restrict__ LOG,
                                                const float* __restrict__ bias,
                                                bf16* __restrict__ H){
  int n    = (blockIdx.x * 256 + threadIdx.x) >> 6;
  int lane = threadIdx.x & 63;
  if (n >= N_NODES) return;
  int r0 = rowp[n], r1 = rowp[n + 1];

  float lself = LOG[N_EDGES + n];
  float m = lself;
  for (int p = r0; p < r1; ++p) m = fmaxf(m, LOG[p]);

  float p0  = __expf(lself - m);
  float den = p0;
  float accA[8], accB[2];
  {
    const bf16* xn = xl + (size_t)n * HID;
    bf16x8 va = *(const bf16x8*)(xn + 8 * lane);
    unsigned vb = *(const unsigned*)(xn + 512 + 2 * lane);
#pragma unroll
    for (int j = 0; j < 8; ++j) accA[j] = p0 * bf2f_bits(va[j]);
    accB[0] = p0 * bf2f_bits((short)(vb & 0xffff));
    accB[1] = p0 * bf2f_bits((short)(vb >> 16));
  }
  int p = r0;
  for (; p + 1 < r1; p += 2){
    int s0 = srcg[p], s1 = srcg[p + 1];
    float pv0 = __expf(LOG[p] - m), pv1 = __expf(LOG[p + 1] - m);
    const bf16* xs0 = xl + (size_t)s0 * HID;
    const bf16* xs1 = xl + (size_t)s1 * HID;
    bf16x8 va0 = *(const bf16x8*)(xs0 + 8 * lane);
    bf16x8 va1 = *(const bf16x8*)(xs1 + 8 * lane);
    unsigned vb0 = *(const unsigned*)(xs0 + 512 + 2 * lane);
    unsigned vb1 = *(const unsigned*)(xs1 + 512 + 2 * lane);
    den += pv0 + pv1;
#pragma unroll
    for (int j = 0; j < 8; ++j) accA[j] += pv0 * bf2f_bits(va0[j]) + pv1 * bf2f_bits(va1[j]);
    accB[0] += pv0 * bf2f_bits((short)(vb0 & 0xffff)) + pv1 * bf2f_bits((short)(vb1 & 0xffff));
    accB[1] += pv0 * bf2f_bits((short)(vb0 >> 16))    + pv1 * bf2f_bits((short)(vb1 >> 16));
  }
  if (p < r1){
    int s = srcg[p];
    float pv = __expf(LOG[p] - m);
    den += pv;
    const bf16* xs = xl + (size_t)s * HID;
    bf16x8 va = *(const bf16x8*)(xs + 8 * lane);
    unsigned vb = *(const unsigned*)(xs + 512 + 2 * lane);
#pragma unroll
    for (int j = 0; j < 8; ++j) accA[j] += pv * bf2f_bits(va[j]);
    accB[0] += pv * bf2f_bits((short)(vb & 0xffff));
    accB[1] += pv * bf2f_bits((short)(vb >> 16));
  }
  float inv = 1.f / den;
  float4 bA0 = *(const float4*)(bias + 8 * lane);
  float4 bA1 = *(const float4*)(bias + 8 * lane + 4);
  float2 bB  = *(const float2*)(bias + 512 + 2 * lane);
  float bAa[8] = {bA0.x, bA0.y, bA0.z, bA0.w, bA1.x, bA1.y, bA1.z, bA1.w};
  bf16x8 oA;
#pragma unroll
  for (int j = 0; j < 8; ++j) oA[j] = f2bf_bits(accA[j] * inv + bAa[j]);
  bf16* hn = H + (size_t)n * HID;
  *(bf16x8*)(hn + 8 * lane) = oA;
  unsigned ob = (unsigned)(unsigned short)f2bf_bits(accB[0] * inv + bB.x) |
                ((unsigned)(unsigned short)f2bf_bits(accB[1] * inv + bB.y) << 16);
  *(unsigned*)(hn + 512 + 2 * lane) = ob;
}

// ---------------------------------------------------------------- GCN gather: bias+ReLU -> bf16 h3 (unrolled)
__global__ __launch_bounds__(256) void gcn_gather(const bf16* __restrict__ xw,
                                                  const int* __restrict__ srcg,
                                                  const int* __restrict__ rowp,
                                                  const float* __restrict__ dinv,
                                                  const float* __restrict__ bg,
                                                  bf16* __restrict__ h3){
  int n    = (blockIdx.x * 256 + threadIdx.x) >> 6;
  int lane = threadIdx.x & 63;
  if (n >= N_NODES) return;
  int r0 = rowp[n], r1 = rowp[n + 1];

  float dn = dinv[n];
  float accA[8], accB[2];
  {
    float w = dn * dn;
    const bf16* xn = xw + (size_t)n * HID;
    bf16x8 va = *(const bf16x8*)(xn + 8 * lane);
    unsigned vb = *(const unsigned*)(xn + 512 + 2 * lane);
#pragma unroll
    for (int j = 0; j < 8; ++j) accA[j] = w * bf2f_bits(va[j]);
    accB[0] = w * bf2f_bits((short)(vb & 0xffff));
    accB[1] = w * bf2f_bits((short)(vb >> 16));
  }
  int p = r0;
  for (; p + 1 < r1; p += 2){
    int s0 = srcg[p], s1 = srcg[p + 1];
    float w0 = dinv[s0] * dn, w1 = dinv[s1] * dn;
    const bf16* xs0 = xw + (size_t)s0 * HID;
    const bf16* xs1 = xw + (size_t)s1 * HID;
    bf16x8 va0 = *(const bf16x8*)(xs0 + 8 * lane);
    bf16x8 va1 = *(const bf16x8*)(xs1 + 8 * lane);
    unsigned vb0 = *(const unsigned*)(xs0 + 512 + 2 * lane);
    unsigned vb1 = *(const unsigned*)(xs1 + 512 + 2 * lane);
#pragma unroll
    for (int j = 0; j < 8; ++j) accA[j] += w0 * bf2f_bits(va0[j]) + w1 * bf2f_bits(va1[j]);
    accB[0] += w0 * bf2f_bits((short)(vb0 & 0xffff)) + w1 * bf2f_bits((short)(vb1 & 0xffff));
    accB[1] += w0 * bf2f_bits((short)(vb0 >> 16))    + w1 * bf2f_bits((short)(vb1 >> 16));
  }
  if (p < r1){
    int s = srcg[p];
    float w = dinv[s] * dn;
    const bf16* xs = xw + (size_t)s * HID;
    bf16x8 va = *(const bf16x8*)(xs + 8 * lane);
    unsigned vb = *(const unsigned*)(xs + 512 + 2 * lane);
#pragma unroll
    for (int j = 0; j < 8; ++j) accA[j] += w * bf2f_bits(va[j]);
    accB[0] += w * bf2f_bits((short)(vb & 0xffff));
    accB[1] += w * bf2f_bits((short)(vb >> 16));
  }
  float4 bA0 = *(const float4*)(bg + 8 * lane);
  float4 bA1 = *(const float4*)(bg + 8 * lane + 4);
  float2 bB  = *(const float2*)(bg + 512 + 2 * lane);
  float bAa[8] = {bA0.x, bA0.y, bA0.z, bA0.w, bA1.x, bA1.y, bA1.z, bA1.w};
  bf16x8 oA;
#pragma unroll
  for (int j = 0; j < 8; ++j) oA[j] = f2bf_bits(fmaxf(accA[j] + bAa[j], 0.f));
  bf16* hn = h3 + (size_t)n * HID;
  *(bf16x8*)(hn + 8 * lane) = oA;
  unsigned ob = (unsigned)(unsigned short)f2bf_bits(fmaxf(accB[0] + bB.x, 0.f)) |
                ((unsigned)(unsigned short)f2bf_bits(fmaxf(accB[1] + bB.y, 0.f)) << 16);
  *(unsigned*)(hn + 512 + 2 * lane) = ob;
}

// ---------------------------------------------------------------- per-graph pooling (batch is sorted)
__global__ __launch_bounds__(256) void graph_bounds(const int* __restrict__ batch,
                                                    int* __restrict__ gstart){
  int n = blockIdx.x * 256 + threadIdx.x;
  if (n >= N_NODES) return;
  int b = clampi(batch[n], N_GRAPHS);
  if (n == 0){
    for (int g = 0; g <= b; ++g) gstart[g] = 0;
  } else {
    int bp = clampi(batch[n - 1], N_GRAPHS);
    for (int g = bp + 1; g <= b; ++g) gstart[g] = n;
  }
  if (n == N_NODES - 1){
    for (int g = b + 1; g <= N_GRAPHS; ++g) gstart[g] = N_NODES;
  }
}

__global__ __launch_bounds__(640) void pool_graph(const bf16* __restrict__ h3,
                                                  const int* __restrict__ gstart,
                                                  float* __restrict__ out){
  int g = blockIdx.x;
  int c = threadIdx.x;
  int n0 = gstart[g], n1 = gstart[g + 1];
  float mx = 0.f, sm = 0.f;     // h3 >= 0 post-ReLU
  for (int n = n0; n < n1; ++n){
    float v = b2f(h3[(size_t)n * HID + c]);
    mx = fmaxf(mx, v); sm += v;
  }
  float mean = (n1 > n0) ? sm / (float)(n1 - n0) : 0.f;
  out[(size_t)g * 2 * HID + c]       = mx;
  out[(size_t)g * 2 * HID + HID + c] = mean;
}

// ---------------------------------------------------------------- launch
extern "C" void kernel_launch(void* const* d_in, const int* in_sizes, int n_in,
                              void* d_out, int out_size, void* d_ws, size_t ws_size,
                              hipStream_t stream){
  const float* x     = (const float*)d_in[0];
  const int*   ei    = (const int*)d_in[1];
  const int*   batch = (const int*)d_in[2];
  const float* Wl1 = (const float*)d_in[3];
  const float* Wr1 = (const float*)d_in[4];
  const float* a1  = (const float*)d_in[5];
  const float* b1  = (const float*)d_in[6];
  const float* Wl2 = (const float*)d_in[7];
  const float* Wr2 = (const float*)d_in[8];
  const float* a2  = (const float*)d_in[9];
  const float* b2  = (const float*)d_in[10];
  const float* Wg  = (const float*)d_in[11];
  const float* bg  = (const float*)d_in[12];
  const int* esrc = ei;
  const int* edst = ei + N_EDGES;

  // ---- workspace layout (~219 MB) ----
  char* ws = (char*)d_ws;
  size_t off = 0;
  auto take = [&](size_t bytes)->char*{
    char* p = ws + off; off = (off + bytes + 255) & ~(size_t)255; return p;
  };
  bf16*     X1   = (bf16*)    take((size_t)N_NODES * HID * 2);
  bf16*     X2   = (bf16*)    take((size_t)N_NODES * HID * 2);
  bf16*     H    = (bf16*)    take((size_t)N_NODES * HID * 2);
  bf16*     XB   = (bf16*)    take((size_t)N_NODES * K1P * 2);
  // WT1l|WT1r contiguous (one 1280xK1P matrix); WT2l|WT2r contiguous; WTg follows WT2r.
  bf16*     WT1l = (bf16*)    take((size_t)HID * K1P * 2);
  bf16*     WT1r = (bf16*)    take((size_t)HID * K1P * 2);
  bf16*     WT2l = (bf16*)    take((size_t)HID * HID * 2);
  bf16*     WT2r = (bf16*)    take((size_t)HID * HID * 2);
  bf16*     WTg  = (bf16*)    take((size_t)HID * HID * 2);
  bf16*     AT1P = (bf16*)    take((size_t)(HID / 32) * 512 * 2);
  bf16*     AT2P = (bf16*)    take((size_t)(HID / 32) * 512 * 2);
  float*    LOG  = (float*)   take((size_t)E_TOT * 16 * 4);
  int*      DEGI = (int*)     take((size_t)N_NODES * 4);
  int*      ROWP = (int*)     take((size_t)(N_NODES + 1) * 4);
  int*      CURS = (int*)     take((size_t)N_NODES * 4);
  int*      SRCG = (int*)     take((size_t)N_EDGES * 4);
  int*      DSTG = (int*)     take((size_t)N_EDGES * 4);
  float*    DINV = (float*)   take((size_t)N_NODES * 4);
  int*      GST  = (int*)     take((size_t)(N_GRAPHS + 1) * 4);

  dim3 blk(256);
  auto fill = [&](void* p, unsigned v, int n){
    fill_u32<<<dim3((n + 255) / 256), blk, 0, stream>>>((unsigned*)p, v, n);
  };
  const int MB8     = ((N_NODES + BM - 1) / BM + 7) / 8;   // row strips per XCD (49)
  const int nblocks = (N_NODES * 64 + 255) / 256;
  const int lblocks = (N_TILES * 64 + 255) / 256;
  const int reblk   = (N_EDGES + 255) / 256;
  const int apn     = (HID / 32) * 512;

  // ---- prep + CSR ----
  conv_x<<<(N_NODES * K1P + 255) / 256, blk, 0, stream>>>(x, XB);
  conv_wT2<<<(2 * HID * K1P + 255) / 256, blk, 0, stream>>>(Wl1, Wr1, WT1l, IN_DIM, HID, K1P);
  conv_wT3<<<(3 * HID * HID + 255) / 256, blk, 0, stream>>>(Wl2, Wr2, Wg, WT2l, HID, HID, HID);
  conv_attP<<<(apn + 255) / 256, blk, 0, stream>>>(a1, AT1P, HEADS);
  conv_attP<<<(apn + 255) / 256, blk, 0, stream>>>(a2, AT2P, 1);
  fill(DEGI, 0u, N_NODES);
  count_deg<<<reblk, blk, 0, stream>>>(edst, DEGI);
  scan_rowp<<<1, 1024, 0, stream>>>(DEGI, ROWP, CURS, DINV);
  bucket_edges<<<reblk, blk, 0, stream>>>(esrc, edst, CURS, SRCG, DSTG);
  graph_bounds<<<(N_NODES + 255) / 256, blk, 0, stream>>>(batch, GST);

  // ---- GATv2 layer 1 (merged Wl|Wr GEMM, N=1280) ----
  mfma_gemm<<<dim3(8 * MB8 * 10), blk, 0, stream>>>(XB, WT1l, X1, X2, N_NODES, K1P, 10);
  logits_mfma<<<lblocks, blk, 0, stream>>>(X1, X2, SRCG, DSTG, AT1P, LOG, 0);
  gat1_agg<<<nblocks, blk, 0, stream>>>(X1, SRCG, ROWP, LOG, b1, H);

  // ---- GATv2 layer 2 (merged Wl|Wr GEMM, N=1280; compact logits) ----
  mfma_gemm<<<dim3(8 * MB8 * 10), blk, 0, stream>>>(H, WT2l, X1, X2, N_NODES, HID, 10);
  logits_mfma<<<lblocks, blk, 0, stream>>>(X1, X2, SRCG, DSTG, AT2P, LOG, 1);
  gat2_agg<<<nblocks, blk, 0, stream>>>(X1, SRCG, ROWP, LOG, b2, H);

  // ---- GCN + pooling ----
  mfma_gemm<<<dim3(8 * MB8 * 5), blk, 0, stream>>>(H, WTg, X1, X1, N_NODES, HID, 5);
  gcn_gather<<<nblocks, blk, 0, stream>>>(X1, SRCG, ROWP, DINV, bg, X2);
  pool_graph<<<dim3(N_GRAPHS), dim3(640), 0, stream>>>(X2, GST, (float*)d_out);
}

// Round 11
// 649.271 us; speedup vs baseline: 7.3822x; 1.0449x over previous
//
#include <hip/hip_runtime.h>
#include <hip/hip_bf16.h>
#include <cstdint>
#include <cstddef>

typedef __hip_bfloat16 bf16;

#define N_NODES  50000
#define N_EDGES  150000
#define E_TOT    (N_EDGES + N_NODES)   /* CSR positions: edges (dst-sorted), then self-loops */
#define N_TILES  ((E_TOT + 15) / 16)
#define N_GRAPHS 1024
#define IN_DIM   78
#define K1P      128                   /* IN_DIM padded to mult of 64 (BK) */
#define OUT_DIM  64
#define HEADS    10
#define HID      640
#define NEG_SLOPE 0.2f

static __device__ __forceinline__ float b2f(bf16 v){ return __bfloat162float(v); }
static __device__ __forceinline__ bf16  f2b(float v){ return __float2bfloat16(v); }

__device__ __forceinline__ int clampi(int v, int hi){ return v < 0 ? 0 : (v >= hi ? hi - 1 : v); }

__device__ __forceinline__ float bf2f_bits(short s){
  return __uint_as_float(((unsigned)(unsigned short)s) << 16);
}
__device__ __forceinline__ short f2bf_bits(float v){      // RNE (used where accuracy matters)
  unsigned u = __float_as_uint(v);
  return (short)((u + 0x7fffu + ((u >> 16) & 1u)) >> 16);
}
__device__ __forceinline__ short f2bf_trunc(float v){     // cheap truncation (logits path)
  return (short)(__float_as_uint(v) >> 16);
}

// ---------------------------------------------------------------- fills
__global__ __launch_bounds__(256) void fill_u32(unsigned* __restrict__ p, unsigned v, int n){
  int i = blockIdx.x * 256 + threadIdx.x;
  if (i < n) p[i] = v;
}

// ---------------------------------------------------------------- dtype prep
__global__ __launch_bounds__(256) void conv_x(const float* __restrict__ x, bf16* __restrict__ XB){
  int i = blockIdx.x * 256 + threadIdx.x;
  if (i >= N_NODES * K1P) return;
  int n = i / K1P, k = i - n * K1P;
  XB[i] = f2b(k < IN_DIM ? x[(size_t)n * IN_DIM + k] : 0.f);
}

// 2 weight matrices -> contiguous transposed bf16 (layer-1 pair, K padded)
__global__ __launch_bounds__(256) void conv_wT2(const float* __restrict__ W0,
                                                const float* __restrict__ W1,
                                                bf16* __restrict__ WT,
                                                int K, int N, int Kp){
  int i = blockIdx.x * 256 + threadIdx.x;
  const int per = N * Kp;
  if (i >= 2 * per) return;
  int m = i / per, r = i - m * per;
  const float* W = m == 0 ? W0 : W1;
  int n = r / Kp, k = r - n * Kp;
  WT[i] = f2b(k < K ? W[(size_t)k * N + n] : 0.f);
}

// 3 weight matrices -> contiguous transposed bf16 (Wl2|Wr2|Wg)
__global__ __launch_bounds__(256) void conv_wT3(const float* __restrict__ W0,
                                                const float* __restrict__ W1,
                                                const float* __restrict__ W2,
                                                bf16* __restrict__ WT,
                                                int K, int N, int Kp){
  int i = blockIdx.x * 256 + threadIdx.x;
  const int per = N * Kp;
  if (i >= 3 * per) return;
  int m = i / per, r = i - m * per;
  const float* W = m == 0 ? W0 : (m == 1 ? W1 : W2);
  int n = r / Kp, k = r - n * Kp;
  WT[i] = f2b(k < K ? W[(size_t)k * N + n] : 0.f);
}

// att -> B-fragment-ordered matrix for 16x16x32 MFMA
__global__ __launch_bounds__(256) void conv_attP(const float* __restrict__ a, bf16* __restrict__ P,
                                                 int heads){
  int i = blockIdx.x * 256 + threadIdx.x;
  if (i >= (HID / 32) * 512) return;
  int chunk = i >> 9;
  int lane  = (i >> 3) & 63;
  int j     = i & 7;
  int h = lane & 15;
  int k = (lane >> 4) * 8 + j;
  int c = chunk * 32 + k;
  float v = 0.f;
  if (heads == HEADS){ if (h < HEADS && (c >> 6) == h) v = a[c]; }
  else               { if (h == 0) v = a[c]; }
  P[i] = f2b(v);
}

// ---------------------------------------------------------------- MFMA GEMM (BK=64, halved barriers)
#define BM 128
#define BN 128
#define BK 64

typedef __attribute__((ext_vector_type(8))) short bf16x8;
typedef __attribute__((ext_vector_type(4))) float f32x4;

typedef const __attribute__((address_space(1))) unsigned gu32;
typedef __attribute__((address_space(3))) unsigned lu32;

__global__ __launch_bounds__(256) void mfma_gemm(const bf16* __restrict__ A,
                                                 const bf16* __restrict__ BT,
                                                 bf16* __restrict__ C0,
                                                 bf16* __restrict__ C1,
                                                 int M, int Kp, int NB){
  // block swizzle: all NB col-tiles of a row strip stay on one XCD (d%8 = XCD round-robin)
  int d   = blockIdx.x;
  int xcd = d & 7, j = d >> 3;
  int cb  = j % NB, ri = j / NB;
  int rb  = ri * 8 + xcd;
  const int row0 = rb * BM;
  if (row0 >= M) return;
  const int col0 = cb * BN;

  // LDS slot (r, kc) holds source k-chunk kc ^ (r&7): full 32-bank coverage, 2-way (free)
  __shared__ short As[BM * BK];   // 16 KB
  __shared__ short Bs[BN * BK];   // 16 KB
  const int tid  = threadIdx.x;
  const int lane = tid & 63;
  const int wave = tid >> 6;
  const int wr   = (wave >> 1) * 64;
  const int wc   = (wave & 1) * 64;
  const int l15  = lane & 15;
  const int quad = lane >> 4;
  const int sw   = l15 & 7;       // row-XOR term (wr, i*16 are multiples of 8)

  // hoisted staging addresses: 16 wave-loads per matrix, group g = t*4+wave, chunk ci = g*64+lane
  const bf16* aptr[4];
  const bf16* bptr[4];
  lu32* lda[4];
  lu32* ldb[4];
#pragma unroll
  for (int t = 0; t < 4; ++t){
    int ci = (t * 4 + wave) * 64 + lane;
    int r  = ci >> 3;                         // 0..127
    int sc = (ci & 7) ^ (r & 7);              // swizzled source chunk
    int gr = row0 + r; if (gr >= M) gr = M - 1;
    aptr[t] = A  + (size_t)gr * Kp + sc * 8;
    bptr[t] = BT + (size_t)(col0 + r) * Kp + sc * 8;
    lda[t]  = (lu32*)(&As[(t * 4 + wave) * 512]);
    ldb[t]  = (lu32*)(&Bs[(t * 4 + wave) * 512]);
  }

  f32x4 acc[4][4];
#pragma unroll
  for (int i = 0; i < 4; ++i)
#pragma unroll
    for (int jj = 0; jj < 4; ++jj) acc[i][jj] = (f32x4){0.f, 0.f, 0.f, 0.f};

  for (int k0 = 0; k0 < Kp; k0 += BK){
#pragma unroll
    for (int t = 0; t < 4; ++t){
      __builtin_amdgcn_global_load_lds((gu32*)(aptr[t] + k0), lda[t], 16, 0, 0);
      __builtin_amdgcn_global_load_lds((gu32*)(bptr[t] + k0), ldb[t], 16, 0, 0);
    }
    __syncthreads();

#pragma unroll
    for (int ks = 0; ks < 2; ++ks){
      const int slotA = ((ks * 4 + quad) ^ sw) * 8;
      bf16x8 af[4], bfr[4];
#pragma unroll
      for (int i = 0; i < 4; ++i)
        af[i] = *(bf16x8*)(&As[(wr + i * 16 + l15) * BK + slotA]);
#pragma unroll
      for (int jj = 0; jj < 4; ++jj)
        bfr[jj] = *(bf16x8*)(&Bs[(wc + jj * 16 + l15) * BK + slotA]);
#pragma unroll
      for (int i = 0; i < 4; ++i)
#pragma unroll
        for (int jj = 0; jj < 4; ++jj)
          acc[i][jj] = __builtin_amdgcn_mfma_f32_16x16x32_bf16(af[i], bfr[jj], acc[i][jj], 0, 0, 0);
    }
    __syncthreads();
  }

  // epilogue: C/D layout col=lane&15, row=quad*4+reg; column-split dual output
  if (row0 + BM <= M){          // full strip: no row guards (391/392 tiles)
#pragma unroll
    for (int i = 0; i < 4; ++i){
#pragma unroll
      for (int jj = 0; jj < 4; ++jj){
        int gc = col0 + wc + jj * 16 + l15;
        bf16* Cp = (gc < HID) ? C0 : C1;
        size_t cc = (gc < HID) ? gc : gc - HID;
        size_t base = (size_t)(row0 + wr + i * 16 + quad * 4) * HID + cc;
#pragma unroll
        for (int r = 0; r < 4; ++r)
          Cp[base + (size_t)r * HID] = f2b(acc[i][jj][r]);
      }
    }
  } else {
#pragma unroll
    for (int i = 0; i < 4; ++i){
#pragma unroll
      for (int jj = 0; jj < 4; ++jj){
        int gc = col0 + wc + jj * 16 + l15;
        bf16* Cp = (gc < HID) ? C0 : C1;
        int cc   = (gc < HID) ? gc : gc - HID;
#pragma unroll
        for (int r = 0; r < 4; ++r){
          int gr = row0 + wr + i * 16 + quad * 4 + r;
          if (gr < M) Cp[(size_t)gr * HID + cc] = f2b(acc[i][jj][r]);
        }
      }
    }
  }
}

// ---------------------------------------------------------------- CSR build
__global__ __launch_bounds__(256) void count_deg(const int* __restrict__ edst, int* __restrict__ degi){
  int e = blockIdx.x * 256 + threadIdx.x;
  if (e >= N_EDGES) return;
  atomicAdd(&degi[clampi(edst[e], N_NODES)], 1);
}

__global__ __launch_bounds__(1024) void scan_rowp(const int* __restrict__ degi,
                                                  int* __restrict__ rowp,
                                                  int* __restrict__ curs,
                                                  float* __restrict__ dinv){
  __shared__ int wsum[16];
  __shared__ int carry_s;
  const int tid = threadIdx.x, lane = tid & 63, wv = tid >> 6;
  if (tid == 0) carry_s = 0;
  __syncthreads();
  for (int base = 0; base < N_NODES; base += 1024){
    int i = base + tid;
    int v = (i < N_NODES) ? degi[i] : 0;
    int incl = v;
#pragma unroll
    for (int ofs = 1; ofs < 64; ofs <<= 1){
      int t = __shfl_up(incl, ofs);
      if (lane >= ofs) incl += t;
    }
    if (lane == 63) wsum[wv] = incl;
    __syncthreads();
    int woff = 0;
    for (int w = 0; w < 16; ++w) if (w < wv) woff += wsum[w];
    int carry = carry_s;
    if (i < N_NODES){
      int excl = carry + woff + incl - v;
      rowp[i] = excl; curs[i] = excl;
      dinv[i] = rsqrtf((float)(v + 1));
    }
    __syncthreads();
    if (tid == 1023) carry_s = carry + woff + incl;
    __syncthreads();
  }
  if (tid == 0) rowp[N_NODES] = carry_s;
}

__global__ __launch_bounds__(256) void bucket_edges(const int* __restrict__ esrc,
                                                    const int* __restrict__ edst,
                                                    int* __restrict__ curs,
                                                    int* __restrict__ srcg,
                                                    int* __restrict__ dstg){
  int e = blockIdx.x * 256 + threadIdx.x;
  if (e >= N_EDGES) return;
  int d = clampi(edst[e], N_NODES);
  int pos = atomicAdd(&curs[d], 1);
  srcg[pos] = clampi(esrc[e], N_NODES);
  dstg[pos] = d;
}

// ---------------------------------------------------------------- MFMA logits (CSR order)
// only0: store just head-0 logit (compact) for the single-head layer.
__global__ __launch_bounds__(256) void logits_mfma(const bf16* __restrict__ xl,
                                                   const bf16* __restrict__ xr,
                                                   const int* __restrict__ srcg,
                                                   const int* __restrict__ dstg,
                                                   const bf16* __restrict__ attP,
                                                   float* __restrict__ LOG,
                                                   int only0){
  int wid  = (blockIdx.x * 256 + threadIdx.x) >> 6;
  int lane = threadIdx.x & 63;
  if (wid >= N_TILES) return;
  const int l15 = lane & 15, quad = lane >> 4;
  int p = wid * 16 + l15; if (p >= E_TOT) p = E_TOT - 1;
  int s, d;
  if (p < N_EDGES){ s = srcg[p]; d = dstg[p]; }
  else            { s = d = p - N_EDGES; }
  const bf16* ps = xl + (size_t)s * HID + quad * 8;
  const bf16* pd = xr + (size_t)d * HID + quad * 8;

  f32x4 acc = (f32x4){0.f, 0.f, 0.f, 0.f};
  for (int k0 = 0; k0 < HID; k0 += 32){
    bf16x8 va = *(const bf16x8*)(ps + k0);
    bf16x8 vb = *(const bf16x8*)(pd + k0);
    bf16x8 t;
#pragma unroll
    for (int j = 0; j < 8; ++j){
      float v = bf2f_bits(va[j]) + bf2f_bits(vb[j]);
      v *= (v > 0.f) ? 1.f : NEG_SLOPE;            // cndmask + mul
      t[j] = f2bf_trunc(v);                        // 1-op repack
    }
    bf16x8 wb = *(const bf16x8*)(attP + (k0 >> 5) * 512 + lane * 8);
    acc = __builtin_amdgcn_mfma_f32_16x16x32_bf16(t, wb, acc, 0, 0, 0);
  }
  int er = wid * 16 + quad * 4;
  if (only0){
    if (l15 == 0){
#pragma unroll
      for (int r = 0; r < 4; ++r){
        int ee = er + r;
        if (ee < E_TOT) LOG[ee] = acc[r];
      }
    }
  } else {
#pragma unroll
    for (int r = 0; r < 4; ++r){
      int ee = er + r;
      if (ee < E_TOT) LOG[(size_t)ee * 16 + l15] = acc[r];
    }
  }
}

// ---------------------------------------------------------------- GAT1 aggregation (2-way unrolled)
// lane l owns ch [8l,8l+8) (head l>>3) and ch {512+2l,513+2l} (head 8+(l>>5)).
__global__ __launch_bounds__(256) void gat1_agg(const bf16* __restrict__ xl,
                                                const int* __restrict__ srcg,
                                                const int* __restrict__ rowp,
                                                const float* __restrict__ LOG,
                                                const float* __restrict__ bias,
                                                bf16* __restrict__ H){
  int n    = (blockIdx.x * 256 + threadIdx.x) >> 6;
  int lane = threadIdx.x & 63;
  if (n >= N_NODES) return;
  const int l15 = lane & 15;
  const int hA = lane >> 3;
  const int hB = 8 + (lane >> 5);
  int r0 = rowp[n], r1 = rowp[n + 1];

  float lself = LOG[(size_t)(N_EDGES + n) * 16 + l15];
  float m = lself;
  for (int p = r0; p < r1; ++p) m = fmaxf(m, LOG[(size_t)p * 16 + l15]);

  float p0  = __expf(lself - m);
  float den = p0;
  float accA[8], accB[2];
  {
    float pA = __shfl(p0, hA), pB = __shfl(p0, hB);
    const bf16* xn = xl + (size_t)n * HID;
    bf16x8 va = *(const bf16x8*)(xn + 8 * lane);
    unsigned vb = *(const unsigned*)(xn + 512 + 2 * lane);
#pragma unroll
    for (int j = 0; j < 8; ++j) accA[j] = pA * bf2f_bits(va[j]);
    accB[0] = pB * bf2f_bits((short)(vb & 0xffff));
    accB[1] = pB * bf2f_bits((short)(vb >> 16));
  }
  int p = r0;
  for (; p + 1 < r1; p += 2){
    int s0 = srcg[p], s1 = srcg[p + 1];
    float l0 = LOG[(size_t)p * 16 + l15];
    float l1 = LOG[(size_t)(p + 1) * 16 + l15];
    const bf16* xs0 = xl + (size_t)s0 * HID;
    const bf16* xs1 = xl + (size_t)s1 * HID;
    bf16x8 va0 = *(const bf16x8*)(xs0 + 8 * lane);
    bf16x8 va1 = *(const bf16x8*)(xs1 + 8 * lane);
    unsigned vb0 = *(const unsigned*)(xs0 + 512 + 2 * lane);
    unsigned vb1 = *(const unsigned*)(xs1 + 512 + 2 * lane);
    float pv0 = __expf(l0 - m), pv1 = __expf(l1 - m);
    den += pv0 + pv1;
    float pA0 = __shfl(pv0, hA), pB0 = __shfl(pv0, hB);
    float pA1 = __shfl(pv1, hA), pB1 = __shfl(pv1, hB);
#pragma unroll
    for (int j = 0; j < 8; ++j) accA[j] += pA0 * bf2f_bits(va0[j]) + pA1 * bf2f_bits(va1[j]);
    accB[0] += pB0 * bf2f_bits((short)(vb0 & 0xffff)) + pB1 * bf2f_bits((short)(vb1 & 0xffff));
    accB[1] += pB0 * bf2f_bits((short)(vb0 >> 16))    + pB1 * bf2f_bits((short)(vb1 >> 16));
  }
  if (p < r1){
    int s = srcg[p];
    float pv = __expf(LOG[(size_t)p * 16 + l15] - m);
    den += pv;
    float pA = __shfl(pv, hA), pB = __shfl(pv, hB);
    const bf16* xs = xl + (size_t)s * HID;
    bf16x8 va = *(const bf16x8*)(xs + 8 * lane);
    unsigned vb = *(const unsigned*)(xs + 512 + 2 * lane);
#pragma unroll
    for (int j = 0; j < 8; ++j) accA[j] += pA * bf2f_bits(va[j]);
    accB[0] += pB * bf2f_bits((short)(vb & 0xffff));
    accB[1] += pB * bf2f_bits((short)(vb >> 16));
  }
  float dA = __shfl(den, hA), dB = __shfl(den, hB);
  float4 bA0 = *(const float4*)(bias + 8 * lane);
  float4 bA1 = *(const float4*)(bias + 8 * lane + 4);
  float2 bB  = *(const float2*)(bias + 512 + 2 * lane);
  bf16x8 oA;
  float bAa[8] = {bA0.x, bA0.y, bA0.z, bA0.w, bA1.x, bA1.y, bA1.z, bA1.w};
#pragma unroll
  for (int j = 0; j < 8; ++j){
    float v = accA[j] / dA + bAa[j];
    v = v > 0.f ? v : (__expf(v) - 1.f);              // ELU
    oA[j] = f2bf_bits(v);
  }
  float v0 = accB[0] / dB + bB.x; v0 = v0 > 0.f ? v0 : (__expf(v0) - 1.f);
  float v1 = accB[1] / dB + bB.y; v1 = v1 > 0.f ? v1 : (__expf(v1) - 1.f);
  bf16* hn = H + (size_t)n * HID;
  *(bf16x8*)(hn + 8 * lane) = oA;
  unsigned ob = (unsigned)(unsigned short)f2bf_bits(v0) |
                ((unsigned)(unsigned short)f2bf_bits(v1) << 16);
  *(unsigned*)(hn + 512 + 2 * lane) = ob;
}

// ---------------------------------------------------------------- GAT2 aggregation (1 head, compact LOG, unrolled)
__global__ __launch_bounds__(256) void gat2_agg(const bf16* __restrict__ xl,
                                                const int* __restrict__ srcg,
                                                const int* __restrict__ rowp,
                                                const float* __restrict__ LOG,
                                                const float* __restrict__ bias,
                                                bf16* __restrict__ H){
  int n    = (blockIdx.x * 256 + threadIdx.x) >> 6;
  int lane = threadIdx.x & 63;
  if (n >= N_NODES) return;
  int r0 = rowp[n], r1 = rowp[n + 1];

  float lself = LOG[N_EDGES + n];
  float m = lself;
  for (int p = r0; p < r1; ++p) m = fmaxf(m, LOG[p]);

  float p0  = __expf(lself - m);
  float den = p0;
  float accA[8], accB[2];
  {
    const bf16* xn = xl + (size_t)n * HID;
    bf16x8 va = *(const bf16x8*)(xn + 8 * lane);
    unsigned vb = *(const unsigned*)(xn + 512 + 2 * lane);
#pragma unroll
    for (int j = 0; j < 8; ++j) accA[j] = p0 * bf2f_bits(va[j]);
    accB[0] = p0 * bf2f_bits((short)(vb & 0xffff));
    accB[1] = p0 * bf2f_bits((short)(vb >> 16));
  }
  int p = r0;
  for (; p + 1 < r1; p += 2){
    int s0 = srcg[p], s1 = srcg[p + 1];
    float pv0 = __expf(LOG[p] - m), pv1 = __expf(LOG[p + 1] - m);
    const bf16* xs0 = xl + (size_t)s0 * HID;
    const bf16* xs1 = xl + (size_t)s1 * HID;
    bf16x8 va0 = *(const bf16x8*)(xs0 + 8 * lane);
    bf16x8 va1 = *(const bf16x8*)(xs1 + 8 * lane);
    unsigned vb0 = *(const unsigned*)(xs0 + 512 + 2 * lane);
    unsigned vb1 = *(const unsigned*)(xs1 + 512 + 2 * lane);
    den += pv0 + pv1;
#pragma unroll
    for (int j = 0; j < 8; ++j) accA[j] += pv0 * bf2f_bits(va0[j]) + pv1 * bf2f_bits(va1[j]);
    accB[0] += pv0 * bf2f_bits((short)(vb0 & 0xffff)) + pv1 * bf2f_bits((short)(vb1 & 0xffff));
    accB[1] += pv0 * bf2f_bits((short)(vb0 >> 16))    + pv1 * bf2f_bits((short)(vb1 >> 16));
  }
  if (p < r1){
    int s = srcg[p];
    float pv = __expf(LOG[p] - m);
    den += pv;
    const bf16* xs = xl + (size_t)s * HID;
    bf16x8 va = *(const bf16x8*)(xs + 8 * lane);
    unsigned vb = *(const unsigned*)(xs + 512 + 2 * lane);
#pragma unroll
    for (int j = 0; j < 8; ++j) accA[j] += pv * bf2f_bits(va[j]);
    accB[0] += pv * bf2f_bits((short)(vb & 0xffff));
    accB[1] += pv * bf2f_bits((short)(vb >> 16));
  }
  float inv = 1.f / den;
  float4 bA0 = *(const float4*)(bias + 8 * lane);
  float4 bA1 = *(const float4*)(bias + 8 * lane + 4);
  float2 bB  = *(const float2*)(bias + 512 + 2 * lane);
  float bAa[8] = {bA0.x, bA0.y, bA0.z, bA0.w, bA1.x, bA1.y, bA1.z, bA1.w};
  bf16x8 oA;
#pragma unroll
  for (int j = 0; j < 8; ++j) oA[j] = f2bf_bits(accA[j] * inv + bAa[j]);
  bf16* hn = H + (size_t)n * HID;
  *(bf16x8*)(hn + 8 * lane) = oA;
  unsigned ob = (unsigned)(unsigned short)f2bf_bits(accB[0] * inv + bB.x) |
                ((unsigned)(unsigned short)f2bf_bits(accB[1] * inv + bB.y) << 16);
  *(unsigned*)(hn + 512 + 2 * lane) = ob;
}

// ---------------------------------------------------------------- GCN gather: bias+ReLU -> bf16 h3 (unrolled)
__global__ __launch_bounds__(256) void gcn_gather(const bf16* __restrict__ xw,
                                                  const int* __restrict__ srcg,
                                                  const int* __restrict__ rowp,
                                                  const float* __restrict__ dinv,
                                                  const float* __restrict__ bg,
                                                  bf16* __restrict__ h3){
  int n    = (blockIdx.x * 256 + threadIdx.x) >> 6;
  int lane = threadIdx.x & 63;
  if (n >= N_NODES) return;
  int r0 = rowp[n], r1 = rowp[n + 1];

  float dn = dinv[n];
  float accA[8], accB[2];
  {
    float w = dn * dn;
    const bf16* xn = xw + (size_t)n * HID;
    bf16x8 va = *(const bf16x8*)(xn + 8 * lane);
    unsigned vb = *(const unsigned*)(xn + 512 + 2 * lane);
#pragma unroll
    for (int j = 0; j < 8; ++j) accA[j] = w * bf2f_bits(va[j]);
    accB[0] = w * bf2f_bits((short)(vb & 0xffff));
    accB[1] = w * bf2f_bits((short)(vb >> 16));
  }
  int p = r0;
  for (; p + 1 < r1; p += 2){
    int s0 = srcg[p], s1 = srcg[p + 1];
    float w0 = dinv[s0] * dn, w1 = dinv[s1] * dn;
    const bf16* xs0 = xw + (size_t)s0 * HID;
    const bf16* xs1 = xw + (size_t)s1 * HID;
    bf16x8 va0 = *(const bf16x8*)(xs0 + 8 * lane);
    bf16x8 va1 = *(const bf16x8*)(xs1 + 8 * lane);
    unsigned vb0 = *(const unsigned*)(xs0 + 512 + 2 * lane);
    unsigned vb1 = *(const unsigned*)(xs1 + 512 + 2 * lane);
#pragma unroll
    for (int j = 0; j < 8; ++j) accA[j] += w0 * bf2f_bits(va0[j]) + w1 * bf2f_bits(va1[j]);
    accB[0] += w0 * bf2f_bits((short)(vb0 & 0xffff)) + w1 * bf2f_bits((short)(vb1 & 0xffff));
    accB[1] += w0 * bf2f_bits((short)(vb0 >> 16))    + w1 * bf2f_bits((short)(vb1 >> 16));
  }
  if (p < r1){
    int s = srcg[p];
    float w = dinv[s] * dn;
    const bf16* xs = xw + (size_t)s * HID;
    bf16x8 va = *(const bf16x8*)(xs + 8 * lane);
    unsigned vb = *(const unsigned*)(xs + 512 + 2 * lane);
#pragma unroll
    for (int j = 0; j < 8; ++j) accA[j] += w * bf2f_bits(va[j]);
    accB[0] += w * bf2f_bits((short)(vb & 0xffff));
    accB[1] += w * bf2f_bits((short)(vb >> 16));
  }
  float4 bA0 = *(const float4*)(bg + 8 * lane);
  float4 bA1 = *(const float4*)(bg + 8 * lane + 4);
  float2 bB  = *(const float2*)(bg + 512 + 2 * lane);
  float bAa[8] = {bA0.x, bA0.y, bA0.z, bA0.w, bA1.x, bA1.y, bA1.z, bA1.w};
  bf16x8 oA;
#pragma unroll
  for (int j = 0; j < 8; ++j) oA[j] = f2bf_bits(fmaxf(accA[j] + bAa[j], 0.f));
  bf16* hn = h3 + (size_t)n * HID;
  *(bf16x8*)(hn + 8 * lane) = oA;
  unsigned ob = (unsigned)(unsigned short)f2bf_bits(fmaxf(accB[0] + bB.x, 0.f)) |
                ((unsigned)(unsigned short)f2bf_bits(fmaxf(accB[1] + bB.y, 0.f)) << 16);
  *(unsigned*)(hn + 512 + 2 * lane) = ob;
}

// ---------------------------------------------------------------- per-graph pooling (batch is sorted)
__global__ __launch_bounds__(256) void graph_bounds(const int* __restrict__ batch,
                                                    int* __restrict__ gstart){
  int n = blockIdx.x * 256 + threadIdx.x;
  if (n >= N_NODES) return;
  int b = clampi(batch[n], N_GRAPHS);
  if (n == 0){
    for (int g = 0; g <= b; ++g) gstart[g] = 0;
  } else {
    int bp = clampi(batch[n - 1], N_GRAPHS);
    for (int g = bp + 1; g <= b; ++g) gstart[g] = n;
  }
  if (n == N_NODES - 1){
    for (int g = b + 1; g <= N_GRAPHS; ++g) gstart[g] = N_NODES;
  }
}

__global__ __launch_bounds__(640) void pool_graph(const bf16* __restrict__ h3,
                                                  const int* __restrict__ gstart,
                                                  float* __restrict__ out){
  int g = blockIdx.x;
  int c = threadIdx.x;
  int n0 = gstart[g], n1 = gstart[g + 1];
  float mx = 0.f, sm = 0.f;     // h3 >= 0 post-ReLU
  for (int n = n0; n < n1; ++n){
    float v = b2f(h3[(size_t)n * HID + c]);
    mx = fmaxf(mx, v); sm += v;
  }
  float mean = (n1 > n0) ? sm / (float)(n1 - n0) : 0.f;
  out[(size_t)g * 2 * HID + c]       = mx;
  out[(size_t)g * 2 * HID + HID + c] = mean;
}

// ---------------------------------------------------------------- launch
extern "C" void kernel_launch(void* const* d_in, const int* in_sizes, int n_in,
                              void* d_out, int out_size, void* d_ws, size_t ws_size,
                              hipStream_t stream){
  const float* x     = (const float*)d_in[0];
  const int*   ei    = (const int*)d_in[1];
  const int*   batch = (const int*)d_in[2];
  const float* Wl1 = (const float*)d_in[3];
  const float* Wr1 = (const float*)d_in[4];
  const float* a1  = (const float*)d_in[5];
  const float* b1  = (const float*)d_in[6];
  const float* Wl2 = (const float*)d_in[7];
  const float* Wr2 = (const float*)d_in[8];
  const float* a2  = (const float*)d_in[9];
  const float* b2  = (const float*)d_in[10];
  const float* Wg  = (const float*)d_in[11];
  const float* bg  = (const float*)d_in[12];
  const int* esrc = ei;
  const int* edst = ei + N_EDGES;

  // ---- workspace layout (~222 MB) ----
  char* ws = (char*)d_ws;
  size_t off = 0;
  auto take = [&](size_t bytes)->char*{
    char* p = ws + off; off = (off + bytes + 255) & ~(size_t)255; return p;
  };
  bf16*     X1   = (bf16*)    take((size_t)N_NODES * HID * 2);
  bf16*     X2   = (bf16*)    take((size_t)N_NODES * HID * 2);
  bf16*     H    = (bf16*)    take((size_t)N_NODES * HID * 2);
  bf16*     XB   = (bf16*)    take((size_t)N_NODES * K1P * 2);
  // WT1l|WT1r contiguous (one 1280xK1P matrix); WT2l|WT2r contiguous; WTg follows WT2r.
  bf16*     WT1l = (bf16*)    take((size_t)HID * K1P * 2);
  bf16*     WT1r = (bf16*)    take((size_t)HID * K1P * 2);
  bf16*     WT2l = (bf16*)    take((size_t)HID * HID * 2);
  bf16*     WT2r = (bf16*)    take((size_t)HID * HID * 2);
  bf16*     WTg  = (bf16*)    take((size_t)HID * HID * 2);
  bf16*     AT1P = (bf16*)    take((size_t)(HID / 32) * 512 * 2);
  bf16*     AT2P = (bf16*)    take((size_t)(HID / 32) * 512 * 2);
  float*    LOG  = (float*)   take((size_t)E_TOT * 16 * 4);
  int*      DEGI = (int*)     take((size_t)N_NODES * 4);
  int*      ROWP = (int*)     take((size_t)(N_NODES + 1) * 4);
  int*      CURS = (int*)     take((size_t)N_NODES * 4);
  int*      SRCG = (int*)     take((size_t)N_EDGES * 4);
  int*      DSTG = (int*)     take((size_t)N_EDGES * 4);
  float*    DINV = (float*)   take((size_t)N_NODES * 4);
  int*      GST  = (int*)     take((size_t)(N_GRAPHS + 1) * 4);

  dim3 blk(256);
  auto fill = [&](void* p, unsigned v, int n){
    fill_u32<<<dim3((n + 255) / 256), blk, 0, stream>>>((unsigned*)p, v, n);
  };
  const int MB8     = ((N_NODES + BM - 1) / BM + 7) / 8;   // row strips per XCD (49)
  const int nblocks = (N_NODES * 64 + 255) / 256;
  const int lblocks = (N_TILES * 64 + 255) / 256;
  const int reblk   = (N_EDGES + 255) / 256;
  const int apn     = (HID / 32) * 512;

  // ---- prep + CSR ----
  conv_x<<<(N_NODES * K1P + 255) / 256, blk, 0, stream>>>(x, XB);
  conv_wT2<<<(2 * HID * K1P + 255) / 256, blk, 0, stream>>>(Wl1, Wr1, WT1l, IN_DIM, HID, K1P);
  conv_wT3<<<(3 * HID * HID + 255) / 256, blk, 0, stream>>>(Wl2, Wr2, Wg, WT2l, HID, HID, HID);
  conv_attP<<<(apn + 255) / 256, blk, 0, stream>>>(a1, AT1P, HEADS);
  conv_attP<<<(apn + 255) / 256, blk, 0, stream>>>(a2, AT2P, 1);
  fill(DEGI, 0u, N_NODES);
  count_deg<<<reblk, blk, 0, stream>>>(edst, DEGI);
  scan_rowp<<<1, 1024, 0, stream>>>(DEGI, ROWP, CURS, DINV);
  bucket_edges<<<reblk, blk, 0, stream>>>(esrc, edst, CURS, SRCG, DSTG);
  graph_bounds<<<(N_NODES + 255) / 256, blk, 0, stream>>>(batch, GST);

  // ---- GATv2 layer 1 (merged Wl|Wr GEMM, N=1280) ----
  mfma_gemm<<<dim3(8 * MB8 * 10), blk, 0, stream>>>(XB, WT1l, X1, X2, N_NODES, K1P, 10);
  logits_mfma<<<lblocks, blk, 0, stream>>>(X1, X2, SRCG, DSTG, AT1P, LOG, 0);
  gat1_agg<<<nblocks, blk, 0, stream>>>(X1, SRCG, ROWP, LOG, b1, H);

  // ---- GATv2 layer 2 (merged Wl|Wr GEMM, N=1280; compact logits) ----
  mfma_gemm<<<dim3(8 * MB8 * 10), blk, 0, stream>>>(H, WT2l, X1, X2, N_NODES, HID, 10);
  logits_mfma<<<lblocks, blk, 0, stream>>>(X1, X2, SRCG, DSTG, AT2P, LOG, 1);
  gat2_agg<<<nblocks, blk, 0, stream>>>(X1, SRCG, ROWP, LOG, b2, H);

  // ---- GCN + pooling ----
  mfma_gemm<<<dim3(8 * MB8 * 5), blk, 0, stream>>>(H, WTg, X1, X1, N_NODES, HID, 5);
  gcn_gather<<<nblocks, blk, 0, stream>>>(X1, SRCG, ROWP, DINV, bg, X2);
  pool_graph<<<dim3(N_GRAPHS), dim3(640), 0, stream>>>(X2, GST, (float*)d_out);
}

// Round 12
// 608.411 us; speedup vs baseline: 7.8779x; 1.0672x over previous
//
#include <hip/hip_runtime.h>
#include <hip/hip_bf16.h>
#include <cstdint>
#include <cstddef>

typedef __hip_bfloat16 bf16;

#define N_NODES  50000
#define N_EDGES  150000
#define E_TOT    (N_EDGES + N_NODES)   /* CSR positions: edges (dst-sorted), then self-loops */
#define N_TILES  ((E_TOT + 15) / 16)
#define N_GRAPHS 1024
#define IN_DIM   78
#define K1P      128                   /* IN_DIM padded to mult of 64 (BK) */
#define OUT_DIM  64
#define HEADS    10
#define HID      640
#define NEG_SLOPE 0.2f
#define SCB      ((N_NODES + 255) / 256)   /* 196 scan blocks */

static __device__ __forceinline__ float b2f(bf16 v){ return __bfloat162float(v); }
static __device__ __forceinline__ bf16  f2b(float v){ return __float2bfloat16(v); }

__device__ __forceinline__ int clampi(int v, int hi){ return v < 0 ? 0 : (v >= hi ? hi - 1 : v); }

__device__ __forceinline__ float bf2f_bits(short s){
  return __uint_as_float(((unsigned)(unsigned short)s) << 16);
}
__device__ __forceinline__ short f2bf_bits(float v){      // RNE (used where accuracy matters)
  unsigned u = __float_as_uint(v);
  return (short)((u + 0x7fffu + ((u >> 16) & 1u)) >> 16);
}
__device__ __forceinline__ short f2bf_trunc(float v){     // cheap truncation (logits path)
  return (short)(__float_as_uint(v) >> 16);
}

// ---------------------------------------------------------------- fills
__global__ __launch_bounds__(256) void fill_u32(unsigned* __restrict__ p, unsigned v, int n){
  int i = blockIdx.x * 256 + threadIdx.x;
  if (i < n) p[i] = v;
}

// ---------------------------------------------------------------- dtype prep
__global__ __launch_bounds__(256) void conv_x(const float* __restrict__ x, bf16* __restrict__ XB){
  int i = blockIdx.x * 256 + threadIdx.x;
  if (i >= N_NODES * K1P) return;
  int n = i / K1P, k = i - n * K1P;
  XB[i] = f2b(k < IN_DIM ? x[(size_t)n * IN_DIM + k] : 0.f);
}

// 2 weight matrices -> contiguous transposed bf16 (layer-1 pair, K padded; small)
__global__ __launch_bounds__(256) void conv_wT2(const float* __restrict__ W0,
                                                const float* __restrict__ W1,
                                                bf16* __restrict__ WT,
                                                int K, int N, int Kp){
  int i = blockIdx.x * 256 + threadIdx.x;
  const int per = N * Kp;
  if (i >= 2 * per) return;
  int m = i / per, r = i - m * per;
  const float* W = m == 0 ? W0 : W1;
  int n = r / Kp, k = r - n * Kp;
  WT[i] = f2b(k < K ? W[(size_t)k * N + n] : 0.f);
}

// tiled transpose: 3x (640x640 f32, row-major k x n) -> bf16 WT[m][n][k]
__global__ __launch_bounds__(256) void conv_wT3t(const float* __restrict__ W0,
                                                 const float* __restrict__ W1,
                                                 const float* __restrict__ W2,
                                                 bf16* __restrict__ WT){
  __shared__ float t[32][33];
  int m = blockIdx.z;
  const float* W = m == 0 ? W0 : (m == 1 ? W1 : W2);
  int n0 = blockIdx.x * 32, k0 = blockIdx.y * 32;
  int tx = threadIdx.x & 31, ty = threadIdx.x >> 5;   // 32 x 8
#pragma unroll
  for (int r = 0; r < 32; r += 8)
    t[ty + r][tx] = W[(size_t)(k0 + ty + r) * HID + n0 + tx];   // coalesced in n
  __syncthreads();
  bf16* O = WT + (size_t)m * HID * HID;
#pragma unroll
  for (int r = 0; r < 32; r += 8)
    O[(size_t)(n0 + ty + r) * HID + k0 + tx] = f2b(t[tx][ty + r]);  // coalesced in k
}

// att -> B-fragment-ordered matrix for 16x16x32 MFMA
__global__ __launch_bounds__(256) void conv_attP(const float* __restrict__ a, bf16* __restrict__ P,
                                                 int heads){
  int i = blockIdx.x * 256 + threadIdx.x;
  if (i >= (HID / 32) * 512) return;
  int chunk = i >> 9;
  int lane  = (i >> 3) & 63;
  int j     = i & 7;
  int h = lane & 15;
  int k = (lane >> 4) * 8 + j;
  int c = chunk * 32 + k;
  float v = 0.f;
  if (heads == HEADS){ if (h < HEADS && (c >> 6) == h) v = a[c]; }
  else               { if (h == 0) v = a[c]; }
  P[i] = f2b(v);
}

// ---------------------------------------------------------------- MFMA GEMM (BK=64)
#define BM 128
#define BN 128
#define BK 64

typedef __attribute__((ext_vector_type(8))) short bf16x8;
typedef __attribute__((ext_vector_type(4))) float f32x4;

typedef const __attribute__((address_space(1))) unsigned gu32;
typedef __attribute__((address_space(3))) unsigned lu32;

__global__ __launch_bounds__(256) void mfma_gemm(const bf16* __restrict__ A,
                                                 const bf16* __restrict__ BT,
                                                 bf16* __restrict__ C0,
                                                 bf16* __restrict__ C1,
                                                 int M, int Kp, int NB){
  // block swizzle: all NB col-tiles of a row strip stay on one XCD (d%8 = XCD round-robin)
  int d   = blockIdx.x;
  int xcd = d & 7, j = d >> 3;
  int cb  = j % NB, ri = j / NB;
  int rb  = ri * 8 + xcd;
  const int row0 = rb * BM;
  if (row0 >= M) return;
  const int col0 = cb * BN;

  // LDS slot (r, kc) holds source k-chunk kc ^ (r&7): full 32-bank coverage, 2-way (free)
  __shared__ short As[BM * BK];   // 16 KB
  __shared__ short Bs[BN * BK];   // 16 KB
  const int tid  = threadIdx.x;
  const int lane = tid & 63;
  const int wave = tid >> 6;
  const int wr   = (wave >> 1) * 64;
  const int wc   = (wave & 1) * 64;
  const int l15  = lane & 15;
  const int quad = lane >> 4;
  const int sw   = l15 & 7;       // row-XOR term (wr, i*16 are multiples of 8)

  const bf16* aptr[4];
  const bf16* bptr[4];
  lu32* lda[4];
  lu32* ldb[4];
#pragma unroll
  for (int t = 0; t < 4; ++t){
    int ci = (t * 4 + wave) * 64 + lane;
    int r  = ci >> 3;
    int sc = (ci & 7) ^ (r & 7);
    int gr = row0 + r; if (gr >= M) gr = M - 1;
    aptr[t] = A  + (size_t)gr * Kp + sc * 8;
    bptr[t] = BT + (size_t)(col0 + r) * Kp + sc * 8;
    lda[t]  = (lu32*)(&As[(t * 4 + wave) * 512]);
    ldb[t]  = (lu32*)(&Bs[(t * 4 + wave) * 512]);
  }

  f32x4 acc[4][4];
#pragma unroll
  for (int i = 0; i < 4; ++i)
#pragma unroll
    for (int jj = 0; jj < 4; ++jj) acc[i][jj] = (f32x4){0.f, 0.f, 0.f, 0.f};

  for (int k0 = 0; k0 < Kp; k0 += BK){
#pragma unroll
    for (int t = 0; t < 4; ++t){
      __builtin_amdgcn_global_load_lds((gu32*)(aptr[t] + k0), lda[t], 16, 0, 0);
      __builtin_amdgcn_global_load_lds((gu32*)(bptr[t] + k0), ldb[t], 16, 0, 0);
    }
    __syncthreads();

#pragma unroll
    for (int ks = 0; ks < 2; ++ks){
      const int slotA = ((ks * 4 + quad) ^ sw) * 8;
      bf16x8 af[4], bfr[4];
#pragma unroll
      for (int i = 0; i < 4; ++i)
        af[i] = *(bf16x8*)(&As[(wr + i * 16 + l15) * BK + slotA]);
#pragma unroll
      for (int jj = 0; jj < 4; ++jj)
        bfr[jj] = *(bf16x8*)(&Bs[(wc + jj * 16 + l15) * BK + slotA]);
#pragma unroll
      for (int i = 0; i < 4; ++i)
#pragma unroll
        for (int jj = 0; jj < 4; ++jj)
          acc[i][jj] = __builtin_amdgcn_mfma_f32_16x16x32_bf16(af[i], bfr[jj], acc[i][jj], 0, 0, 0);
    }
    __syncthreads();
  }

  // epilogue: C/D layout col=lane&15, row=quad*4+reg; column-split dual output
  if (row0 + BM <= M){
#pragma unroll
    for (int i = 0; i < 4; ++i){
#pragma unroll
      for (int jj = 0; jj < 4; ++jj){
        int gc = col0 + wc + jj * 16 + l15;
        bf16* Cp = (gc < HID) ? C0 : C1;
        size_t cc = (gc < HID) ? gc : gc - HID;
        size_t base = (size_t)(row0 + wr + i * 16 + quad * 4) * HID + cc;
#pragma unroll
        for (int r = 0; r < 4; ++r)
          Cp[base + (size_t)r * HID] = f2b(acc[i][jj][r]);
      }
    }
  } else {
#pragma unroll
    for (int i = 0; i < 4; ++i){
#pragma unroll
      for (int jj = 0; jj < 4; ++jj){
        int gc = col0 + wc + jj * 16 + l15;
        bf16* Cp = (gc < HID) ? C0 : C1;
        int cc   = (gc < HID) ? gc : gc - HID;
#pragma unroll
        for (int r = 0; r < 4; ++r){
          int gr = row0 + wr + i * 16 + quad * 4 + r;
          if (gr < M) Cp[(size_t)gr * HID + cc] = f2b(acc[i][jj][r]);
        }
      }
    }
  }
}

// ---------------------------------------------------------------- CSR build
__global__ __launch_bounds__(256) void count_deg(const int* __restrict__ edst, int* __restrict__ degi){
  int e = blockIdx.x * 256 + threadIdx.x;
  if (e >= N_EDGES) return;
  atomicAdd(&degi[clampi(edst[e], N_NODES)], 1);
}

// phase 1: per-block exclusive scan; block sums to bsum; dinv computed here
__global__ __launch_bounds__(256) void scan_blk(const int* __restrict__ degi,
                                                int* __restrict__ rowp,
                                                float* __restrict__ dinv,
                                                int* __restrict__ bsum){
  __shared__ int wsum[4];
  int b = blockIdx.x, tid = threadIdx.x;
  int i = b * 256 + tid;
  int lane = tid & 63, wv = tid >> 6;
  int v = (i < N_NODES) ? degi[i] : 0;
  int incl = v;
#pragma unroll
  for (int ofs = 1; ofs < 64; ofs <<= 1){
    int t = __shfl_up(incl, ofs);
    if (lane >= ofs) incl += t;
  }
  if (lane == 63) wsum[wv] = incl;
  __syncthreads();
  int woff = 0;
#pragma unroll
  for (int w = 0; w < 4; ++w) if (w < wv) woff += wsum[w];
  if (i < N_NODES){
    rowp[i] = woff + incl - v;            // block-local exclusive
    dinv[i] = rsqrtf((float)(v + 1));
  }
  if (tid == 0) bsum[b] = wsum[0] + wsum[1] + wsum[2] + wsum[3];
}

// phase 2: single block scans bsum[SCB] exclusive in place; total -> rowp[N_NODES]
__global__ __launch_bounds__(256) void scan_top(int* __restrict__ bsum, int* __restrict__ rowp){
  __shared__ int wsum[4];
  int tid = threadIdx.x, lane = tid & 63, wv = tid >> 6;
  int v = (tid < SCB) ? bsum[tid] : 0;
  int incl = v;
#pragma unroll
  for (int ofs = 1; ofs < 64; ofs <<= 1){
    int t = __shfl_up(incl, ofs);
    if (lane >= ofs) incl += t;
  }
  if (lane == 63) wsum[wv] = incl;
  __syncthreads();
  int woff = 0;
#pragma unroll
  for (int w = 0; w < 4; ++w) if (w < wv) woff += wsum[w];
  if (tid < SCB) bsum[tid] = woff + incl - v;
  if (tid == 255) rowp[N_NODES] = woff + incl;   // grand total (v=0 past SCB)
}

// phase 3: add block offsets; curs = rowp
__global__ __launch_bounds__(256) void scan_add(const int* __restrict__ bsum,
                                                int* __restrict__ rowp,
                                                int* __restrict__ curs){
  int i = blockIdx.x * 256 + threadIdx.x;
  if (i >= N_NODES) return;
  int r = rowp[i] + bsum[blockIdx.x];
  rowp[i] = r; curs[i] = r;
}

__global__ __launch_bounds__(256) void bucket_edges(const int* __restrict__ esrc,
                                                    const int* __restrict__ edst,
                                                    int* __restrict__ curs,
                                                    int* __restrict__ srcg,
                                                    int* __restrict__ dstg){
  int e = blockIdx.x * 256 + threadIdx.x;
  if (e >= N_EDGES) return;
  int d = clampi(edst[e], N_NODES);
  int pos = atomicAdd(&curs[d], 1);
  srcg[pos] = clampi(esrc[e], N_NODES);
  dstg[pos] = d;
}

// ---------------------------------------------------------------- MFMA logits (CSR order, k-unrolled x2)
__global__ __launch_bounds__(256) void logits_mfma(const bf16* __restrict__ xl,
                                                   const bf16* __restrict__ xr,
                                                   const int* __restrict__ srcg,
                                                   const int* __restrict__ dstg,
                                                   const bf16* __restrict__ attP,
                                                   float* __restrict__ LOG,
                                                   int only0){
  int wid  = (blockIdx.x * 256 + threadIdx.x) >> 6;
  int lane = threadIdx.x & 63;
  if (wid >= N_TILES) return;
  const int l15 = lane & 15, quad = lane >> 4;
  int p = wid * 16 + l15; if (p >= E_TOT) p = E_TOT - 1;
  int s, d;
  if (p < N_EDGES){ s = srcg[p]; d = dstg[p]; }
  else            { s = d = p - N_EDGES; }
  const bf16* ps = xl + (size_t)s * HID + quad * 8;
  const bf16* pd = xr + (size_t)d * HID + quad * 8;
  const bf16* pw = attP + lane * 8;

  f32x4 acc = (f32x4){0.f, 0.f, 0.f, 0.f};
  for (int k0 = 0; k0 < HID; k0 += 64){       // 10 iterations, 4 gathers in flight
    bf16x8 va0 = *(const bf16x8*)(ps + k0);
    bf16x8 vb0 = *(const bf16x8*)(pd + k0);
    bf16x8 va1 = *(const bf16x8*)(ps + k0 + 32);
    bf16x8 vb1 = *(const bf16x8*)(pd + k0 + 32);
    bf16x8 t0, t1;
#pragma unroll
    for (int j = 0; j < 8; ++j){
      float v0 = bf2f_bits(va0[j]) + bf2f_bits(vb0[j]);
      v0 *= (v0 > 0.f) ? 1.f : NEG_SLOPE;
      t0[j] = f2bf_trunc(v0);
      float v1 = bf2f_bits(va1[j]) + bf2f_bits(vb1[j]);
      v1 *= (v1 > 0.f) ? 1.f : NEG_SLOPE;
      t1[j] = f2bf_trunc(v1);
    }
    bf16x8 wb0 = *(const bf16x8*)(pw + (k0 >> 5) * 512);
    bf16x8 wb1 = *(const bf16x8*)(pw + ((k0 >> 5) + 1) * 512);
    acc = __builtin_amdgcn_mfma_f32_16x16x32_bf16(t0, wb0, acc, 0, 0, 0);
    acc = __builtin_amdgcn_mfma_f32_16x16x32_bf16(t1, wb1, acc, 0, 0, 0);
  }
  int er = wid * 16 + quad * 4;
  if (only0){
    if (l15 == 0){
#pragma unroll
      for (int r = 0; r < 4; ++r){
        int ee = er + r;
        if (ee < E_TOT) LOG[ee] = acc[r];
      }
    }
  } else {
#pragma unroll
    for (int r = 0; r < 4; ++r){
      int ee = er + r;
      if (ee < E_TOT) LOG[(size_t)ee * 16 + l15] = acc[r];
    }
  }
}

// ---------------------------------------------------------------- GAT1 aggregation (2-way unrolled)
// lane l owns ch [8l,8l+8) (head l>>3) and ch {512+2l,513+2l} (head 8+(l>>5)).
__global__ __launch_bounds__(256) void gat1_agg(const bf16* __restrict__ xl,
                                                const int* __restrict__ srcg,
                                                const int* __restrict__ rowp,
                                                const float* __restrict__ LOG,
                                                const float* __restrict__ bias,
                                                bf16* __restrict__ H){
  int n    = (blockIdx.x * 256 + threadIdx.x) >> 6;
  int lane = threadIdx.x & 63;
  if (n >= N_NODES) return;
  const int l15 = lane & 15;
  const int hA = lane >> 3;
  const int hB = 8 + (lane >> 5);
  int r0 = rowp[n], r1 = rowp[n + 1];

  float lself = LOG[(size_t)(N_EDGES + n) * 16 + l15];
  float m = lself;
  for (int p = r0; p < r1; ++p) m = fmaxf(m, LOG[(size_t)p * 16 + l15]);

  float p0  = __expf(lself - m);
  float den = p0;
  float accA[8], accB[2];
  {
    float pA = __shfl(p0, hA), pB = __shfl(p0, hB);
    const bf16* xn = xl + (size_t)n * HID;
    bf16x8 va = *(const bf16x8*)(xn + 8 * lane);
    unsigned vb = *(const unsigned*)(xn + 512 + 2 * lane);
#pragma unroll
    for (int j = 0; j < 8; ++j) accA[j] = pA * bf2f_bits(va[j]);
    accB[0] = pB * bf2f_bits((short)(vb & 0xffff));
    accB[1] = pB * bf2f_bits((short)(vb >> 16));
  }
  int p = r0;
  for (; p + 1 < r1; p += 2){
    int s0 = srcg[p], s1 = srcg[p + 1];
    float l0 = LOG[(size_t)p * 16 + l15];
    float l1 = LOG[(size_t)(p + 1) * 16 + l15];
    const bf16* xs0 = xl + (size_t)s0 * HID;
    const bf16* xs1 = xl + (size_t)s1 * HID;
    bf16x8 va0 = *(const bf16x8*)(xs0 + 8 * lane);
    bf16x8 va1 = *(const bf16x8*)(xs1 + 8 * lane);
    unsigned vb0 = *(const unsigned*)(xs0 + 512 + 2 * lane);
    unsigned vb1 = *(const unsigned*)(xs1 + 512 + 2 * lane);
    float pv0 = __expf(l0 - m), pv1 = __expf(l1 - m);
    den += pv0 + pv1;
    float pA0 = __shfl(pv0, hA), pB0 = __shfl(pv0, hB);
    float pA1 = __shfl(pv1, hA), pB1 = __shfl(pv1, hB);
#pragma unroll
    for (int j = 0; j < 8; ++j) accA[j] += pA0 * bf2f_bits(va0[j]) + pA1 * bf2f_bits(va1[j]);
    accB[0] += pB0 * bf2f_bits((short)(vb0 & 0xffff)) + pB1 * bf2f_bits((short)(vb1 & 0xffff));
    accB[1] += pB0 * bf2f_bits((short)(vb0 >> 16))    + pB1 * bf2f_bits((short)(vb1 >> 16));
  }
  if (p < r1){
    int s = srcg[p];
    float pv = __expf(LOG[(size_t)p * 16 + l15] - m);
    den += pv;
    float pA = __shfl(pv, hA), pB = __shfl(pv, hB);
    const bf16* xs = xl + (size_t)s * HID;
    bf16x8 va = *(const bf16x8*)(xs + 8 * lane);
    unsigned vb = *(const unsigned*)(xs + 512 + 2 * lane);
#pragma unroll
    for (int j = 0; j < 8; ++j) accA[j] += pA * bf2f_bits(va[j]);
    accB[0] += pB * bf2f_bits((short)(vb & 0xffff));
    accB[1] += pB * bf2f_bits((short)(vb >> 16));
  }
  float dA = __shfl(den, hA), dB = __shfl(den, hB);
  float4 bA0 = *(const float4*)(bias + 8 * lane);
  float4 bA1 = *(const float4*)(bias + 8 * lane + 4);
  float2 bB  = *(const float2*)(bias + 512 + 2 * lane);
  bf16x8 oA;
  float bAa[8] = {bA0.x, bA0.y, bA0.z, bA0.w, bA1.x, bA1.y, bA1.z, bA1.w};
#pragma unroll
  for (int j = 0; j < 8; ++j){
    float v = accA[j] / dA + bAa[j];
    v = v > 0.f ? v : (__expf(v) - 1.f);              // ELU
    oA[j] = f2bf_bits(v);
  }
  float v0 = accB[0] / dB + bB.x; v0 = v0 > 0.f ? v0 : (__expf(v0) - 1.f);
  float v1 = accB[1] / dB + bB.y; v1 = v1 > 0.f ? v1 : (__expf(v1) - 1.f);
  bf16* hn = H + (size_t)n * HID;
  *(bf16x8*)(hn + 8 * lane) = oA;
  unsigned ob = (unsigned)(unsigned short)f2bf_bits(v0) |
                ((unsigned)(unsigned short)f2bf_bits(v1) << 16);
  *(unsigned*)(hn + 512 + 2 * lane) = ob;
}

// ---------------------------------------------------------------- GAT2 aggregation (1 head, compact LOG, unrolled)
__global__ __launch_bounds__(256) void gat2_agg(const bf16* __restrict__ xl,
                                                const int* __restrict__ srcg,
                                                const int* __restrict__ rowp,
                                                const float* __restrict__ LOG,
                                                const float* __restrict__ bias,
                                                bf16* __restrict__ H){
  int n    = (blockIdx.x * 256 + threadIdx.x) >> 6;
  int lane = threadIdx.x & 63;
  if (n >= N_NODES) return;
  int r0 = rowp[n], r1 = rowp[n + 1];

  float lself = LOG[N_EDGES + n];
  float m = lself;
  for (int p = r0; p < r1; ++p) m = fmaxf(m, LOG[p]);

  float p0  = __expf(lself - m);
  float den = p0;
  float accA[8], accB[2];
  {
    const bf16* xn = xl + (size_t)n * HID;
    bf16x8 va = *(const bf16x8*)(xn + 8 * lane);
    unsigned vb = *(const unsigned*)(xn + 512 + 2 * lane);
#pragma unroll
    for (int j = 0; j < 8; ++j) accA[j] = p0 * bf2f_bits(va[j]);
    accB[0] = p0 * bf2f_bits((short)(vb & 0xffff));
    accB[1] = p0 * bf2f_bits((short)(vb >> 16));
  }
  int p = r0;
  for (; p + 1 < r1; p += 2){
    int s0 = srcg[p], s1 = srcg[p + 1];
    float pv0 = __expf(LOG[p] - m), pv1 = __expf(LOG[p + 1] - m);
    const bf16* xs0 = xl + (size_t)s0 * HID;
    const bf16* xs1 = xl + (size_t)s1 * HID;
    bf16x8 va0 = *(const bf16x8*)(xs0 + 8 * lane);
    bf16x8 va1 = *(const bf16x8*)(xs1 + 8 * lane);
    unsigned vb0 = *(const unsigned*)(xs0 + 512 + 2 * lane);
    unsigned vb1 = *(const unsigned*)(xs1 + 512 + 2 * lane);
    den += pv0 + pv1;
#pragma unroll
    for (int j = 0; j < 8; ++j) accA[j] += pv0 * bf2f_bits(va0[j]) + pv1 * bf2f_bits(va1[j]);
    accB[0] += pv0 * bf2f_bits((short)(vb0 & 0xffff)) + pv1 * bf2f_bits((short)(vb1 & 0xffff));
    accB[1] += pv0 * bf2f_bits((short)(vb0 >> 16))    + pv1 * bf2f_bits((short)(vb1 >> 16));
  }
  if (p < r1){
    int s = srcg[p];
    float pv = __expf(LOG[p] - m);
    den += pv;
    const bf16* xs = xl + (size_t)s * HID;
    bf16x8 va = *(const bf16x8*)(xs + 8 * lane);
    unsigned vb = *(const unsigned*)(xs + 512 + 2 * lane);
#pragma unroll
    for (int j = 0; j < 8; ++j) accA[j] += pv * bf2f_bits(va[j]);
    accB[0] += pv * bf2f_bits((short)(vb & 0xffff));
    accB[1] += pv * bf2f_bits((short)(vb >> 16));
  }
  float inv = 1.f / den;
  float4 bA0 = *(const float4*)(bias + 8 * lane);
  float4 bA1 = *(const float4*)(bias + 8 * lane + 4);
  float2 bB  = *(const float2*)(bias + 512 + 2 * lane);
  float bAa[8] = {bA0.x, bA0.y, bA0.z, bA0.w, bA1.x, bA1.y, bA1.z, bA1.w};
  bf16x8 oA;
#pragma unroll
  for (int j = 0; j < 8; ++j) oA[j] = f2bf_bits(accA[j] * inv + bAa[j]);
  bf16* hn = H + (size_t)n * HID;
  *(bf16x8*)(hn + 8 * lane) = oA;
  unsigned ob = (unsigned)(unsigned short)f2bf_bits(accB[0] * inv + bB.x) |
                ((unsigned)(unsigned short)f2bf_bits(accB[1] * inv + bB.y) << 16);
  *(unsigned*)(hn + 512 + 2 * lane) = ob;
}

// ---------------------------------------------------------------- GCN gather: bias+ReLU -> bf16 h3 (unrolled)
__global__ __launch_bounds__(256) void gcn_gather(const bf16* __restrict__ xw,
                                                  const int* __restrict__ srcg,
                                                  const int* __restrict__ rowp,
                                                  const float* __restrict__ dinv,
                                                  const float* __restrict__ bg,
                                                  bf16* __restrict__ h3){
  int n    = (blockIdx.x * 256 + threadIdx.x) >> 6;
  int lane = threadIdx.x & 63;
  if (n >= N_NODES) return;
  int r0 = rowp[n], r1 = rowp[n + 1];

  float dn = dinv[n];
  float accA[8], accB[2];
  {
    float w = dn * dn;
    const bf16* xn = xw + (size_t)n * HID;
    bf16x8 va = *(const bf16x8*)(xn + 8 * lane);
    unsigned vb = *(const unsigned*)(xn + 512 + 2 * lane);
#pragma unroll
    for (int j = 0; j < 8; ++j) accA[j] = w * bf2f_bits(va[j]);
    accB[0] = w * bf2f_bits((short)(vb & 0xffff));
    accB[1] = w * bf2f_bits((short)(vb >> 16));
  }
  int p = r0;
  for (; p + 1 < r1; p += 2){
    int s0 = srcg[p], s1 = srcg[p + 1];
    float w0 = dinv[s0] * dn, w1 = dinv[s1] * dn;
    const bf16* xs0 = xw + (size_t)s0 * HID;
    const bf16* xs1 = xw + (size_t)s1 * HID;
    bf16x8 va0 = *(const bf16x8*)(xs0 + 8 * lane);
    bf16x8 va1 = *(const bf16x8*)(xs1 + 8 * lane);
    unsigned vb0 = *(const unsigned*)(xs0 + 512 + 2 * lane);
    unsigned vb1 = *(const unsigned*)(xs1 + 512 + 2 * lane);
#pragma unroll
    for (int j = 0; j < 8; ++j) accA[j] += w0 * bf2f_bits(va0[j]) + w1 * bf2f_bits(va1[j]);
    accB[0] += w0 * bf2f_bits((short)(vb0 & 0xffff)) + w1 * bf2f_bits((short)(vb1 & 0xffff));
    accB[1] += w0 * bf2f_bits((short)(vb0 >> 16))    + w1 * bf2f_bits((short)(vb1 >> 16));
  }
  if (p < r1){
    int s = srcg[p];
    float w = dinv[s] * dn;
    const bf16* xs = xw + (size_t)s * HID;
    bf16x8 va = *(const bf16x8*)(xs + 8 * lane);
    unsigned vb = *(const unsigned*)(xs + 512 + 2 * lane);
#pragma unroll
    for (int j = 0; j < 8; ++j) accA[j] += w * bf2f_bits(va[j]);
    accB[0] += w * bf2f_bits((short)(vb & 0xffff));
    accB[1] += w * bf2f_bits((short)(vb >> 16));
  }
  float4 bA0 = *(const float4*)(bg + 8 * lane);
  float4 bA1 = *(const float4*)(bg + 8 * lane + 4);
  float2 bB  = *(const float2*)(bg + 512 + 2 * lane);
  float bAa[8] = {bA0.x, bA0.y, bA0.z, bA0.w, bA1.x, bA1.y, bA1.z, bA1.w};
  bf16x8 oA;
#pragma unroll
  for (int j = 0; j < 8; ++j) oA[j] = f2bf_bits(fmaxf(accA[j] + bAa[j], 0.f));
  bf16* hn = h3 + (size_t)n * HID;
  *(bf16x8*)(hn + 8 * lane) = oA;
  unsigned ob = (unsigned)(unsigned short)f2bf_bits(fmaxf(accB[0] + bB.x, 0.f)) |
                ((unsigned)(unsigned short)f2bf_bits(fmaxf(accB[1] + bB.y, 0.f)) << 16);
  *(unsigned*)(hn + 512 + 2 * lane) = ob;
}

// ---------------------------------------------------------------- per-graph pooling (batch is sorted)
__global__ __launch_bounds__(256) void graph_bounds(const int* __restrict__ batch,
                                                    int* __restrict__ gstart){
  int n = blockIdx.x * 256 + threadIdx.x;
  if (n >= N_NODES) return;
  int b = clampi(batch[n], N_GRAPHS);
  if (n == 0){
    for (int g = 0; g <= b; ++g) gstart[g] = 0;
  } else {
    int bp = clampi(batch[n - 1], N_GRAPHS);
    for (int g = bp + 1; g <= b; ++g) gstart[g] = n;
  }
  if (n == N_NODES - 1){
    for (int g = b + 1; g <= N_GRAPHS; ++g) gstart[g] = N_NODES;
  }
}

__global__ __launch_bounds__(640) void pool_graph(const bf16* __restrict__ h3,
                                                  const int* __restrict__ gstart,
                                                  float* __restrict__ out){
  int g = blockIdx.x;
  int c = threadIdx.x;
  int n0 = gstart[g], n1 = gstart[g + 1];
  float mx = 0.f, sm = 0.f;     // h3 >= 0 post-ReLU
  for (int n = n0; n < n1; ++n){
    float v = b2f(h3[(size_t)n * HID + c]);
    mx = fmaxf(mx, v); sm += v;
  }
  float mean = (n1 > n0) ? sm / (float)(n1 - n0) : 0.f;
  out[(size_t)g * 2 * HID + c]       = mx;
  out[(size_t)g * 2 * HID + HID + c] = mean;
}

// ---------------------------------------------------------------- launch
extern "C" void kernel_launch(void* const* d_in, const int* in_sizes, int n_in,
                              void* d_out, int out_size, void* d_ws, size_t ws_size,
                              hipStream_t stream){
  const float* x     = (const float*)d_in[0];
  const int*   ei    = (const int*)d_in[1];
  const int*   batch = (const int*)d_in[2];
  const float* Wl1 = (const float*)d_in[3];
  const float* Wr1 = (const float*)d_in[4];
  const float* a1  = (const float*)d_in[5];
  const float* b1  = (const float*)d_in[6];
  const float* Wl2 = (const float*)d_in[7];
  const float* Wr2 = (const float*)d_in[8];
  const float* a2  = (const float*)d_in[9];
  const float* b2  = (const float*)d_in[10];
  const float* Wg  = (const float*)d_in[11];
  const float* bg  = (const float*)d_in[12];
  const int* esrc = ei;
  const int* edst = ei + N_EDGES;

  // ---- workspace layout (~222 MB) ----
  char* ws = (char*)d_ws;
  size_t off = 0;
  auto take = [&](size_t bytes)->char*{
    char* p = ws + off; off = (off + bytes + 255) & ~(size_t)255; return p;
  };
  bf16*     X1   = (bf16*)    take((size_t)N_NODES * HID * 2);
  bf16*     X2   = (bf16*)    take((size_t)N_NODES * HID * 2);
  bf16*     H    = (bf16*)    take((size_t)N_NODES * HID * 2);
  bf16*     XB   = (bf16*)    take((size_t)N_NODES * K1P * 2);
  // WT1l|WT1r contiguous (one 1280xK1P matrix); WT2l|WT2r|WTg contiguous.
  bf16*     WT1l = (bf16*)    take((size_t)HID * K1P * 2);
  bf16*     WT1r = (bf16*)    take((size_t)HID * K1P * 2);
  bf16*     WT2l = (bf16*)    take((size_t)HID * HID * 2);
  bf16*     WT2r = (bf16*)    take((size_t)HID * HID * 2);
  bf16*     WTg  = (bf16*)    take((size_t)HID * HID * 2);
  bf16*     AT1P = (bf16*)    take((size_t)(HID / 32) * 512 * 2);
  bf16*     AT2P = (bf16*)    take((size_t)(HID / 32) * 512 * 2);
  float*    LOG  = (float*)   take((size_t)E_TOT * 16 * 4);
  int*      DEGI = (int*)     take((size_t)N_NODES * 4);
  int*      ROWP = (int*)     take((size_t)(N_NODES + 1) * 4);
  int*      CURS = (int*)     take((size_t)N_NODES * 4);
  int*      SRCG = (int*)     take((size_t)N_EDGES * 4);
  int*      DSTG = (int*)     take((size_t)N_EDGES * 4);
  float*    DINV = (float*)   take((size_t)N_NODES * 4);
  int*      GST  = (int*)     take((size_t)(N_GRAPHS + 1) * 4);
  int*      BSUM = (int*)     take((size_t)SCB * 4);

  dim3 blk(256);
  auto fill = [&](void* p, unsigned v, int n){
    fill_u32<<<dim3((n + 255) / 256), blk, 0, stream>>>((unsigned*)p, v, n);
  };
  const int MB8     = ((N_NODES + BM - 1) / BM + 7) / 8;   // row strips per XCD (49)
  const int nblocks = (N_NODES * 64 + 255) / 256;
  const int lblocks = (N_TILES * 64 + 255) / 256;
  const int reblk   = (N_EDGES + 255) / 256;
  const int apn     = (HID / 32) * 512;

  // ---- prep + CSR ----
  conv_x<<<(N_NODES * K1P + 255) / 256, blk, 0, stream>>>(x, XB);
  conv_wT2<<<(2 * HID * K1P + 255) / 256, blk, 0, stream>>>(Wl1, Wr1, WT1l, IN_DIM, HID, K1P);
  conv_wT3t<<<dim3(HID / 32, HID / 32, 3), blk, 0, stream>>>(Wl2, Wr2, Wg, WT2l);
  conv_attP<<<(apn + 255) / 256, blk, 0, stream>>>(a1, AT1P, HEADS);
  conv_attP<<<(apn + 255) / 256, blk, 0, stream>>>(a2, AT2P, 1);
  fill(DEGI, 0u, N_NODES);
  count_deg<<<reblk, blk, 0, stream>>>(edst, DEGI);
  scan_blk<<<dim3(SCB), blk, 0, stream>>>(DEGI, ROWP, DINV, BSUM);
  scan_top<<<dim3(1), blk, 0, stream>>>(BSUM, ROWP);
  scan_add<<<dim3(SCB), blk, 0, stream>>>(BSUM, ROWP, CURS);
  bucket_edges<<<reblk, blk, 0, stream>>>(esrc, edst, CURS, SRCG, DSTG);
  graph_bounds<<<(N_NODES + 255) / 256, blk, 0, stream>>>(batch, GST);

  // ---- GATv2 layer 1 (merged Wl|Wr GEMM, N=1280) ----
  mfma_gemm<<<dim3(8 * MB8 * 10), blk, 0, stream>>>(XB, WT1l, X1, X2, N_NODES, K1P, 10);
  logits_mfma<<<lblocks, blk, 0, stream>>>(X1, X2, SRCG, DSTG, AT1P, LOG, 0);
  gat1_agg<<<nblocks, blk, 0, stream>>>(X1, SRCG, ROWP, LOG, b1, H);

  // ---- GATv2 layer 2 (merged Wl|Wr GEMM, N=1280; compact logits) ----
  mfma_gemm<<<dim3(8 * MB8 * 10), blk, 0, stream>>>(H, WT2l, X1, X2, N_NODES, HID, 10);
  logits_mfma<<<lblocks, blk, 0, stream>>>(X1, X2, SRCG, DSTG, AT2P, LOG, 1);
  gat2_agg<<<nblocks, blk, 0, stream>>>(X1, SRCG, ROWP, LOG, b2, H);

  // ---- GCN + pooling ----
  mfma_gemm<<<dim3(8 * MB8 * 5), blk, 0, stream>>>(H, WTg, X1, X1, N_NODES, HID, 5);
  gcn_gather<<<nblocks, blk, 0, stream>>>(X1, SRCG, ROWP, DINV, bg, X2);
  pool_graph<<<dim3(N_GRAPHS), dim3(640), 0, stream>>>(X2, GST, (float*)d_out);
}